// Round 1
// baseline (9222.897 us; speedup 1.0000x reference)
//
#include <hip/hip_runtime.h>
#include <math.h>

// ---------------------------------------------------------------------------
// ParallelTransformerAEP forward, fp32 baseline.
// Structure per layer: LN -> qkv GEMM -> RoPE -> dual(ff) GEMM w/ silu fuse
//                      -> attention -> (ctx@Wa + h@Wff + x) GEMM
// ---------------------------------------------------------------------------

namespace {
constexpr int SEQ    = 512;
constexpr int NBATCH = 32;
constexpr int DIMM   = 512;
constexpr int NHEAD  = 8;
constexpr int DHEAD  = 64;
constexpr int FFIN   = 2048;
constexpr int NFUSED = 4736;
constexpr int NROWS  = NBATCH * SEQ;   // 16384
constexpr int QKVC   = 640;            // 512 q + 64 k + 64 v
}

// ------------------------- build x = page * item ---------------------------
__global__ __launch_bounds__(512) void build_x_k(
    const int* __restrict__ page_in, const int* __restrict__ item_in,
    const int* __restrict__ item_meta_in, const int* __restrict__ page_meta_in,
    const float* __restrict__ pwide, const float* __restrict__ iwide,
    const float* __restrict__ page_emb, const float* __restrict__ page_meta_emb,
    const float* __restrict__ item_emb, const float* __restrict__ item_meta_emb,
    const float* __restrict__ item_pre_emb,
    const float* __restrict__ pW, const float* __restrict__ pb,
    const float* __restrict__ pg, const float* __restrict__ pbeta,
    const float* __restrict__ iW, const float* __restrict__ ib,
    const float* __restrict__ ig, const float* __restrict__ ibeta,
    float* __restrict__ x)
{
    const int row = blockIdx.x;
    const int b = row >> 9;
    const int s = row & 511;
    const int d = threadIdx.x;
    const float BNS = 0.9999950000374997f;   // 1/sqrt(1+1e-5)

    float pv, iv;
    if (d < 384) {
        pv = page_emb[(size_t)page_in[row] * 384 + d];
    } else if (d < 448) {
        pv = page_meta_emb[(size_t)page_meta_in[row] * 64 + (d - 384)];
    } else {
        const int dd = d - 448;
        float acc = pb[dd];
        #pragma unroll
        for (int c = 0; c < 8; ++c) {
            float w  = pwide[((size_t)b * 8 + c) * SEQ + s];
            float wn = w * BNS * pg[c] + pbeta[c];
            acc += wn * pW[c * 64 + dd];
        }
        pv = acc > 0.f ? acc : 0.2f * acc;
    }
    if (d < 320) {
        iv = item_emb[(size_t)item_in[row] * 320 + d];
    } else if (d < 384) {
        iv = item_meta_emb[(size_t)item_meta_in[row] * 64 + (d - 320)];
    } else if (d < 448) {
        iv = item_pre_emb[(size_t)item_in[row] * 64 + (d - 384)];
    } else {
        const int dd = d - 448;
        float acc = ib[dd];
        #pragma unroll
        for (int c = 0; c < 8; ++c) {
            float w  = iwide[((size_t)b * 8 + c) * SEQ + s];
            float wn = w * BNS * ig[c] + ibeta[c];
            acc += wn * iW[c * 64 + dd];
        }
        iv = acc > 0.f ? acc : 0.2f * acc;
    }
    x[(size_t)row * DIMM + d] = pv * iv;
}

// ------------------------------ LayerNorm ----------------------------------
__global__ __launch_bounds__(256) void ln_k(const float* __restrict__ x,
                                            float* __restrict__ xn,
                                            const float* __restrict__ g)
{
    const int row = blockIdx.x;
    const int t = threadIdx.x;
    const float* xr = x + (size_t)row * DIMM;
    __shared__ float red[4];

    float v0 = xr[t], v1 = xr[t + 256];
    float s = v0 + v1;
    #pragma unroll
    for (int o = 32; o; o >>= 1) s += __shfl_xor(s, o);
    if ((t & 63) == 0) red[t >> 6] = s;
    __syncthreads();
    float mu = (red[0] + red[1] + red[2] + red[3]) * (1.0f / 512.0f);
    __syncthreads();

    float d0 = v0 - mu, d1 = v1 - mu;
    float vs = d0 * d0 + d1 * d1;
    #pragma unroll
    for (int o = 32; o; o >>= 1) vs += __shfl_xor(vs, o);
    if ((t & 63) == 0) red[t >> 6] = vs;
    __syncthreads();
    float var = (red[0] + red[1] + red[2] + red[3]) * (1.0f / 512.0f);
    float r = 1.0f / sqrtf(var + 1e-5f);

    float* out = xn + (size_t)row * DIMM;
    out[t]       = d0 * r * g[t];
    out[t + 256] = d1 * r * g[t + 256];
}

// ------------------------------ RoPE (q,k in-place) ------------------------
__global__ __launch_bounds__(64) void rope_k(float* __restrict__ qkv)
{
    const int row = blockIdx.x;
    const int s = row & 511;
    const int d = threadIdx.x;
    const int j = d & 31;

    float invf = powf(10000.0f, -(float)j * (1.0f / 32.0f));
    float ang = (float)s * invf;
    float sn, cs;
    sincosf(ang, &sn, &cs);

    float* rowp = qkv + (size_t)row * QKVC;
    const int pair = (d < 32) ? d + 32 : d - 32;
    const float sgn = (d < 32) ? -1.f : 1.f;

    float kv = rowp[512 + d];
    float kp = rowp[512 + pair];
    float qv[NHEAD], qp[NHEAD];
    #pragma unroll
    for (int h = 0; h < NHEAD; ++h) {
        qv[h] = rowp[h * 64 + d];
        qp[h] = rowp[h * 64 + pair];
    }
    __syncthreads();
    rowp[512 + d] = kv * cs + sgn * kp * sn;
    #pragma unroll
    for (int h = 0; h < NHEAD; ++h)
        rowp[h * 64 + d] = (qv[h] * cs + sgn * qp[h] * sn) * 0.125f;
}

// --------------------- GEMM 128x128 (single or two-pass+residual) ----------
// C[m,n] = sum_k A[m,k]B[k,n]  (+ A2@B2 and + C_old when TWOPASS)
template <bool TWOPASS>
__global__ __launch_bounds__(256) void gemm128x128_k(
    const float* __restrict__ A, int lda,
    const float* __restrict__ B, int ldb, int K,
    const float* __restrict__ A2, int lda2,
    const float* __restrict__ B2, int ldb2, int K2,
    float* __restrict__ C, int ldc)
{
    __shared__ float As[16][132];
    __shared__ float Bs[16][128];
    const int m0 = blockIdx.y << 7;
    const int n0 = blockIdx.x << 7;
    const int t  = threadIdx.x;
    const int tx = t & 15, ty = t >> 4;
    const int ar = t >> 2, aq = (t & 3) << 2;
    const int br = t >> 5, bq = (t & 31) << 2;

    float acc[8][8];
    #pragma unroll
    for (int i = 0; i < 8; ++i)
        #pragma unroll
        for (int jj = 0; jj < 8; ++jj) acc[i][jj] = 0.f;

    for (int pass = 0; pass < (TWOPASS ? 2 : 1); ++pass) {
        const float* Ap = pass ? A2 : A;
        const float* Bp = pass ? B2 : B;
        const int la = pass ? lda2 : lda;
        const int lb = pass ? ldb2 : ldb;
        const int KK = pass ? K2 : K;
        for (int k0 = 0; k0 < KK; k0 += 16) {
            __syncthreads();
            float4 av0 = *(const float4*)(Ap + (size_t)(m0 + ar) * la + k0 + aq);
            float4 av1 = *(const float4*)(Ap + (size_t)(m0 + ar + 64) * la + k0 + aq);
            As[aq + 0][ar] = av0.x; As[aq + 1][ar] = av0.y;
            As[aq + 2][ar] = av0.z; As[aq + 3][ar] = av0.w;
            As[aq + 0][ar + 64] = av1.x; As[aq + 1][ar + 64] = av1.y;
            As[aq + 2][ar + 64] = av1.z; As[aq + 3][ar + 64] = av1.w;
            *(float4*)&Bs[br][bq]     = *(const float4*)(Bp + (size_t)(k0 + br) * lb + n0 + bq);
            *(float4*)&Bs[br + 8][bq] = *(const float4*)(Bp + (size_t)(k0 + br + 8) * lb + n0 + bq);
            __syncthreads();
            #pragma unroll
            for (int k = 0; k < 16; ++k) {
                float a[8], bb[8];
                *(float4*)&a[0]  = *(const float4*)&As[k][ty << 2];
                *(float4*)&a[4]  = *(const float4*)&As[k][64 + (ty << 2)];
                *(float4*)&bb[0] = *(const float4*)&Bs[k][tx << 2];
                *(float4*)&bb[4] = *(const float4*)&Bs[k][64 + (tx << 2)];
                #pragma unroll
                for (int i = 0; i < 8; ++i)
                    #pragma unroll
                    for (int jj = 0; jj < 8; ++jj)
                        acc[i][jj] = fmaf(a[i], bb[jj], acc[i][jj]);
            }
        }
    }

    #pragma unroll
    for (int i = 0; i < 8; ++i) {
        const int r = m0 + ((i < 4) ? (ty << 2) + i : 64 + (ty << 2) + (i - 4));
        float* dst0 = C + (size_t)r * ldc + n0 + (tx << 2);
        float* dst1 = dst0 + 64;
        float4 o0 = make_float4(acc[i][0], acc[i][1], acc[i][2], acc[i][3]);
        float4 o1 = make_float4(acc[i][4], acc[i][5], acc[i][6], acc[i][7]);
        if (TWOPASS) {
            float4 c0 = *(const float4*)dst0;
            float4 c1 = *(const float4*)dst1;
            o0.x += c0.x; o0.y += c0.y; o0.z += c0.z; o0.w += c0.w;
            o1.x += c1.x; o1.y += c1.y; o1.z += c1.z; o1.w += c1.w;
        }
        *(float4*)dst0 = o0;
        *(float4*)dst1 = o1;
    }
}

// -------------- dual GEMM 128x64: h = silu(A@Bg) * (A@Bx) ------------------
__global__ __launch_bounds__(256) void gemm_dual_silu_k(
    const float* __restrict__ A, int lda,
    const float* __restrict__ Bx, const float* __restrict__ Bg, int ldb, int K,
    float* __restrict__ C, int ldc)
{
    __shared__ float As[16][132];
    __shared__ float Bs[2][16][64];
    const int m0 = blockIdx.y << 7;
    const int n0 = blockIdx.x << 6;
    const int t  = threadIdx.x;
    const int tx = t & 15, ty = t >> 4;
    const int ar = t >> 2, aq = (t & 3) << 2;
    const int br = t >> 4, bq = (t & 15) << 2;

    float accX[8][4], accG[8][4];
    #pragma unroll
    for (int i = 0; i < 8; ++i)
        #pragma unroll
        for (int jj = 0; jj < 4; ++jj) { accX[i][jj] = 0.f; accG[i][jj] = 0.f; }

    for (int k0 = 0; k0 < K; k0 += 16) {
        __syncthreads();
        float4 av0 = *(const float4*)(A + (size_t)(m0 + ar) * lda + k0 + aq);
        float4 av1 = *(const float4*)(A + (size_t)(m0 + ar + 64) * lda + k0 + aq);
        As[aq + 0][ar] = av0.x; As[aq + 1][ar] = av0.y;
        As[aq + 2][ar] = av0.z; As[aq + 3][ar] = av0.w;
        As[aq + 0][ar + 64] = av1.x; As[aq + 1][ar + 64] = av1.y;
        As[aq + 2][ar + 64] = av1.z; As[aq + 3][ar + 64] = av1.w;
        *(float4*)&Bs[0][br][bq] = *(const float4*)(Bx + (size_t)(k0 + br) * ldb + n0 + bq);
        *(float4*)&Bs[1][br][bq] = *(const float4*)(Bg + (size_t)(k0 + br) * ldb + n0 + bq);
        __syncthreads();
        #pragma unroll
        for (int k = 0; k < 16; ++k) {
            float a[8], bx[4], bg[4];
            *(float4*)&a[0] = *(const float4*)&As[k][ty << 2];
            *(float4*)&a[4] = *(const float4*)&As[k][64 + (ty << 2)];
            *(float4*)&bx[0] = *(const float4*)&Bs[0][k][tx << 2];
            *(float4*)&bg[0] = *(const float4*)&Bs[1][k][tx << 2];
            #pragma unroll
            for (int i = 0; i < 8; ++i)
                #pragma unroll
                for (int jj = 0; jj < 4; ++jj) {
                    accX[i][jj] = fmaf(a[i], bx[jj], accX[i][jj]);
                    accG[i][jj] = fmaf(a[i], bg[jj], accG[i][jj]);
                }
        }
    }

    #pragma unroll
    for (int i = 0; i < 8; ++i) {
        const int r = m0 + ((i < 4) ? (ty << 2) + i : 64 + (ty << 2) + (i - 4));
        float o[4];
        #pragma unroll
        for (int jj = 0; jj < 4; ++jj) {
            float gv = accG[i][jj];
            float sig = 1.0f / (1.0f + expf(-gv));
            o[jj] = gv * sig * accX[i][jj];
        }
        *(float4*)(C + (size_t)r * ldc + n0 + (tx << 2)) =
            make_float4(o[0], o[1], o[2], o[3]);
    }
}

// ------------------------------ attention ----------------------------------
// grid: (SEQ/16, NHEAD, NBATCH), block 256.
__global__ __launch_bounds__(256) void attn_k(const float* __restrict__ qkv,
                                              float* __restrict__ ctx,
                                              const int* __restrict__ vl)
{
    const int it = blockIdx.x;
    const int h  = blockIdx.y;
    const int b  = blockIdx.z;
    const int i0 = it << 4;
    const int t  = threadIdx.x;

    __shared__ float qs[16][64];
    __shared__ float kst[64][65];   // transposed k tile: kst[d][j]
    __shared__ float vs[64][68];    // v tile row-major
    __shared__ float sc[16][512];
    __shared__ float inv_s[16];

    // load q tile (post-RoPE, pre-scaled)
    {
        const int r = t >> 4, c4 = (t & 15) << 2;
        *(float4*)&qs[r][c4] =
            *(const float4*)&qkv[((size_t)((b << 9) + i0 + r)) * QKVC + (h << 6) + c4];
    }
    const int VL = vl[b];

    // scores
    for (int j0 = 0; j0 < 512; j0 += 64) {
        __syncthreads();
        for (int idx = t; idx < 1024; idx += 256) {
            const int r = idx >> 4, c4 = (idx & 15) << 2;
            float4 kv4 = *(const float4*)&qkv[((size_t)((b << 9) + j0 + r)) * QKVC + 512 + c4];
            kst[c4 + 0][r] = kv4.x; kst[c4 + 1][r] = kv4.y;
            kst[c4 + 2][r] = kv4.z; kst[c4 + 3][r] = kv4.w;
        }
        __syncthreads();
        #pragma unroll
        for (int rep = 0; rep < 4; ++rep) {
            const int idx = t + (rep << 8);
            const int i = idx >> 6, jj = idx & 63;
            float s = 0.f;
            #pragma unroll
            for (int d = 0; d < 64; ++d) s = fmaf(qs[i][d], kst[d][jj], s);
            sc[i][j0 + jj] = (j0 + jj < VL) ? s : -3.0e38f;
        }
    }
    __syncthreads();

    // softmax: 16 threads per row
    {
        const int row = t >> 4, tx = t & 15;
        float m = -3.0e38f;
        for (int jj = tx; jj < 512; jj += 16) m = fmaxf(m, sc[row][jj]);
        #pragma unroll
        for (int o = 8; o; o >>= 1) m = fmaxf(m, __shfl_xor(m, o));
        float sum = 0.f;
        for (int jj = tx; jj < 512; jj += 16) {
            float e = expf(sc[row][jj] - m);
            sc[row][jj] = e;
            sum += e;
        }
        #pragma unroll
        for (int o = 8; o; o >>= 1) sum += __shfl_xor(sum, o);
        if (tx == 0) inv_s[row] = 1.0f / sum;
    }
    __syncthreads();

    // PV
    float acc0 = 0.f, acc1 = 0.f, acc2 = 0.f, acc3 = 0.f;
    const int i = t >> 4, d4 = (t & 15) << 2;
    for (int j0 = 0; j0 < 512; j0 += 64) {
        for (int idx = t; idx < 1024; idx += 256) {
            const int r = idx >> 4, c4 = (idx & 15) << 2;
            *(float4*)&vs[r][c4] =
                *(const float4*)&qkv[((size_t)((b << 9) + j0 + r)) * QKVC + 576 + c4];
        }
        __syncthreads();
        #pragma unroll 8
        for (int jj = 0; jj < 64; ++jj) {
            float p = sc[i][j0 + jj];
            acc0 = fmaf(p, vs[jj][d4 + 0], acc0);
            acc1 = fmaf(p, vs[jj][d4 + 1], acc1);
            acc2 = fmaf(p, vs[jj][d4 + 2], acc2);
            acc3 = fmaf(p, vs[jj][d4 + 3], acc3);
        }
        __syncthreads();
    }
    const float iv = inv_s[i];
    *(float4*)&ctx[((size_t)((b << 9) + i0 + i)) * DIMM + (h << 6) + d4] =
        make_float4(acc0 * iv, acc1 * iv, acc2 * iv, acc3 * iv);
}

// ------------------------------ pool ---------------------------------------
__global__ __launch_bounds__(512) void pool_k(const float* __restrict__ x,
                                              float* __restrict__ out)
{
    const int b = blockIdx.x;
    const int d = threadIdx.x;
    const float* xb = x + (size_t)b * SEQ * DIMM;
    float s = 0.f, m = -3.0e38f;
    for (int i = 0; i < SEQ; ++i) {
        float v = xb[(size_t)i * DIMM + d];
        s += v;
        m = fmaxf(m, v);
    }
    out[b * 1024 + d] = s * (1.0f / 512.0f);
    out[b * 1024 + 512 + d] = m;
}

// ---------------------------------------------------------------------------
extern "C" void kernel_launch(void* const* d_in, const int* in_sizes, int n_in,
                              void* d_out, int out_size, void* d_ws, size_t ws_size,
                              hipStream_t stream)
{
    const int*   page_in        = (const int*)d_in[0];
    const int*   item_in        = (const int*)d_in[1];
    const int*   item_meta_in   = (const int*)d_in[2];
    const int*   vl_in          = (const int*)d_in[3];
    const int*   page_meta_in   = (const int*)d_in[4];
    const float* pwide          = (const float*)d_in[5];
    const float* iwide          = (const float*)d_in[6];
    const float* page_emb       = (const float*)d_in[7];
    const float* page_meta_emb  = (const float*)d_in[8];
    const float* item_emb       = (const float*)d_in[9];
    const float* item_meta_emb  = (const float*)d_in[10];
    const float* item_pre_emb   = (const float*)d_in[11];
    const float* pW             = (const float*)d_in[12];
    const float* pb             = (const float*)d_in[13];
    const float* pg             = (const float*)d_in[14];
    const float* pbeta          = (const float*)d_in[15];
    const float* iW             = (const float*)d_in[16];
    const float* ib             = (const float*)d_in[17];
    const float* ig             = (const float*)d_in[18];
    const float* ibeta          = (const float*)d_in[19];
    const float* norm_g         = (const float*)d_in[20];
    const float* fused_W        = (const float*)d_in[21];
    const float* attn_out_W     = (const float*)d_in[22];
    const float* ff_out_W       = (const float*)d_in[23];
    float* out = (float*)d_out;

    float* ws  = (float*)d_ws;
    float* x   = ws;                               // 16384*512
    float* xn  = x   + (size_t)NROWS * DIMM;       // 16384*512
    float* qkv = xn  + (size_t)NROWS * DIMM;       // 16384*640
    float* h   = qkv + (size_t)NROWS * QKVC;       // 16384*2048
    float* ctx = h   + (size_t)NROWS * FFIN;       // 16384*512

    build_x_k<<<NROWS, 512, 0, stream>>>(
        page_in, item_in, item_meta_in, page_meta_in, pwide, iwide,
        page_emb, page_meta_emb, item_emb, item_meta_emb, item_pre_emb,
        pW, pb, pg, pbeta, iW, ib, ig, ibeta, x);

    for (int l = 0; l < 4; ++l) {
        const float* Wf  = fused_W    + (size_t)l * DIMM * NFUSED;
        const float* Wa  = attn_out_W + (size_t)l * DIMM * DIMM;
        const float* Wff = ff_out_W   + (size_t)l * FFIN * DIMM;
        const float* g   = norm_g     + (size_t)l * DIMM;

        ln_k<<<NROWS, 256, 0, stream>>>(x, xn, g);

        gemm128x128_k<false><<<dim3(QKVC / 128, NROWS / 128), 256, 0, stream>>>(
            xn, DIMM, Wf, NFUSED, DIMM,
            nullptr, 0, nullptr, 0, 0,
            qkv, QKVC);

        rope_k<<<NROWS, 64, 0, stream>>>(qkv);

        gemm_dual_silu_k<<<dim3(FFIN / 64, NROWS / 128), 256, 0, stream>>>(
            xn, DIMM, Wf + 640, Wf + 2688, NFUSED, DIMM, h, FFIN);

        attn_k<<<dim3(SEQ / 16, NHEAD, NBATCH), 256, 0, stream>>>(qkv, ctx, vl_in);

        gemm128x128_k<true><<<dim3(DIMM / 128, NROWS / 128), 256, 0, stream>>>(
            ctx, DIMM, Wa, DIMM, DIMM,
            h, FFIN, Wff, DIMM, FFIN,
            x, DIMM);
    }

    pool_k<<<NBATCH, 512, 0, stream>>>(x, out);
}

// Round 2
// 6826.857 us; speedup vs baseline: 1.3510x; 1.3510x over previous
//
#include <hip/hip_runtime.h>
#include <math.h>

// ---------------------------------------------------------------------------
// ParallelTransformerAEP forward, fp32.
// R1: flash-style register-microtiled attention; pool/rope grid fixes.
// ---------------------------------------------------------------------------

namespace {
constexpr int SEQ    = 512;
constexpr int NBATCH = 32;
constexpr int DIMM   = 512;
constexpr int NHEAD  = 8;
constexpr int FFIN   = 2048;
constexpr int NFUSED = 4736;
constexpr int NROWS  = NBATCH * SEQ;   // 16384
constexpr int QKVC   = 640;            // 512 q + 64 k + 64 v
}

// ------------------------- build x = page * item ---------------------------
__global__ __launch_bounds__(512) void build_x_k(
    const int* __restrict__ page_in, const int* __restrict__ item_in,
    const int* __restrict__ item_meta_in, const int* __restrict__ page_meta_in,
    const float* __restrict__ pwide, const float* __restrict__ iwide,
    const float* __restrict__ page_emb, const float* __restrict__ page_meta_emb,
    const float* __restrict__ item_emb, const float* __restrict__ item_meta_emb,
    const float* __restrict__ item_pre_emb,
    const float* __restrict__ pW, const float* __restrict__ pb,
    const float* __restrict__ pg, const float* __restrict__ pbeta,
    const float* __restrict__ iW, const float* __restrict__ ib,
    const float* __restrict__ ig, const float* __restrict__ ibeta,
    float* __restrict__ x)
{
    const int row = blockIdx.x;
    const int b = row >> 9;
    const int s = row & 511;
    const int d = threadIdx.x;
    const float BNS = 0.9999950000374997f;   // 1/sqrt(1+1e-5)

    float pv, iv;
    if (d < 384) {
        pv = page_emb[(size_t)page_in[row] * 384 + d];
    } else if (d < 448) {
        pv = page_meta_emb[(size_t)page_meta_in[row] * 64 + (d - 384)];
    } else {
        const int dd = d - 448;
        float acc = pb[dd];
        #pragma unroll
        for (int c = 0; c < 8; ++c) {
            float w  = pwide[((size_t)b * 8 + c) * SEQ + s];
            float wn = w * BNS * pg[c] + pbeta[c];
            acc += wn * pW[c * 64 + dd];
        }
        pv = acc > 0.f ? acc : 0.2f * acc;
    }
    if (d < 320) {
        iv = item_emb[(size_t)item_in[row] * 320 + d];
    } else if (d < 384) {
        iv = item_meta_emb[(size_t)item_meta_in[row] * 64 + (d - 320)];
    } else if (d < 448) {
        iv = item_pre_emb[(size_t)item_in[row] * 64 + (d - 384)];
    } else {
        const int dd = d - 448;
        float acc = ib[dd];
        #pragma unroll
        for (int c = 0; c < 8; ++c) {
            float w  = iwide[((size_t)b * 8 + c) * SEQ + s];
            float wn = w * BNS * ig[c] + ibeta[c];
            acc += wn * iW[c * 64 + dd];
        }
        iv = acc > 0.f ? acc : 0.2f * acc;
    }
    x[(size_t)row * DIMM + d] = pv * iv;
}

// ------------------------------ LayerNorm ----------------------------------
__global__ __launch_bounds__(256) void ln_k(const float* __restrict__ x,
                                            float* __restrict__ xn,
                                            const float* __restrict__ g)
{
    const int row = blockIdx.x;
    const int t = threadIdx.x;
    const float* xr = x + (size_t)row * DIMM;
    __shared__ float red[4];

    float v0 = xr[t], v1 = xr[t + 256];
    float s = v0 + v1;
    #pragma unroll
    for (int o = 32; o; o >>= 1) s += __shfl_xor(s, o);
    if ((t & 63) == 0) red[t >> 6] = s;
    __syncthreads();
    float mu = (red[0] + red[1] + red[2] + red[3]) * (1.0f / 512.0f);
    __syncthreads();

    float d0 = v0 - mu, d1 = v1 - mu;
    float vs = d0 * d0 + d1 * d1;
    #pragma unroll
    for (int o = 32; o; o >>= 1) vs += __shfl_xor(vs, o);
    if ((t & 63) == 0) red[t >> 6] = vs;
    __syncthreads();
    float var = (red[0] + red[1] + red[2] + red[3]) * (1.0f / 512.0f);
    float r = 1.0f / sqrtf(var + 1e-5f);

    float* out = xn + (size_t)row * DIMM;
    out[t]       = d0 * r * g[t];
    out[t + 256] = d1 * r * g[t + 256];
}

// ------------------------------ RoPE (q,k in-place) ------------------------
// 256 threads = 4 rows per block
__global__ __launch_bounds__(256) void rope_k(float* __restrict__ qkv)
{
    const int row = (blockIdx.x << 2) + (threadIdx.x >> 6);
    const int s = row & 511;
    const int d = threadIdx.x & 63;
    const int j = d & 31;

    float invf = powf(10000.0f, -(float)j * (1.0f / 32.0f));
    float ang = (float)s * invf;
    float sn, cs;
    sincosf(ang, &sn, &cs);

    float* rowp = qkv + (size_t)row * QKVC;
    const int pair = (d < 32) ? d + 32 : d - 32;
    const float sgn = (d < 32) ? -1.f : 1.f;

    float kv = rowp[512 + d];
    float kp = rowp[512 + pair];
    float qv[NHEAD], qp[NHEAD];
    #pragma unroll
    for (int h = 0; h < NHEAD; ++h) {
        qv[h] = rowp[h * 64 + d];
        qp[h] = rowp[h * 64 + pair];
    }
    rowp[512 + d] = kv * cs + sgn * kp * sn;
    #pragma unroll
    for (int h = 0; h < NHEAD; ++h)
        rowp[h * 64 + d] = (qv[h] * cs + sgn * qp[h] * sn) * 0.125f;
}

// --------------------- GEMM 128x128 (single or two-pass+residual) ----------
template <bool TWOPASS>
__global__ __launch_bounds__(256) void gemm128x128_k(
    const float* __restrict__ A, int lda,
    const float* __restrict__ B, int ldb, int K,
    const float* __restrict__ A2, int lda2,
    const float* __restrict__ B2, int ldb2, int K2,
    float* __restrict__ C, int ldc)
{
    __shared__ float As[16][132];
    __shared__ float Bs[16][128];
    const int m0 = blockIdx.y << 7;
    const int n0 = blockIdx.x << 7;
    const int t  = threadIdx.x;
    const int tx = t & 15, ty = t >> 4;
    const int ar = t >> 2, aq = (t & 3) << 2;
    const int br = t >> 5, bq = (t & 31) << 2;

    float acc[8][8];
    #pragma unroll
    for (int i = 0; i < 8; ++i)
        #pragma unroll
        for (int jj = 0; jj < 8; ++jj) acc[i][jj] = 0.f;

    for (int pass = 0; pass < (TWOPASS ? 2 : 1); ++pass) {
        const float* Ap = pass ? A2 : A;
        const float* Bp = pass ? B2 : B;
        const int la = pass ? lda2 : lda;
        const int lb = pass ? ldb2 : ldb;
        const int KK = pass ? K2 : K;
        for (int k0 = 0; k0 < KK; k0 += 16) {
            __syncthreads();
            float4 av0 = *(const float4*)(Ap + (size_t)(m0 + ar) * la + k0 + aq);
            float4 av1 = *(const float4*)(Ap + (size_t)(m0 + ar + 64) * la + k0 + aq);
            As[aq + 0][ar] = av0.x; As[aq + 1][ar] = av0.y;
            As[aq + 2][ar] = av0.z; As[aq + 3][ar] = av0.w;
            As[aq + 0][ar + 64] = av1.x; As[aq + 1][ar + 64] = av1.y;
            As[aq + 2][ar + 64] = av1.z; As[aq + 3][ar + 64] = av1.w;
            *(float4*)&Bs[br][bq]     = *(const float4*)(Bp + (size_t)(k0 + br) * lb + n0 + bq);
            *(float4*)&Bs[br + 8][bq] = *(const float4*)(Bp + (size_t)(k0 + br + 8) * lb + n0 + bq);
            __syncthreads();
            #pragma unroll
            for (int k = 0; k < 16; ++k) {
                float a[8], bb[8];
                *(float4*)&a[0]  = *(const float4*)&As[k][ty << 2];
                *(float4*)&a[4]  = *(const float4*)&As[k][64 + (ty << 2)];
                *(float4*)&bb[0] = *(const float4*)&Bs[k][tx << 2];
                *(float4*)&bb[4] = *(const float4*)&Bs[k][64 + (tx << 2)];
                #pragma unroll
                for (int i = 0; i < 8; ++i)
                    #pragma unroll
                    for (int jj = 0; jj < 8; ++jj)
                        acc[i][jj] = fmaf(a[i], bb[jj], acc[i][jj]);
            }
        }
    }

    #pragma unroll
    for (int i = 0; i < 8; ++i) {
        const int r = m0 + ((i < 4) ? (ty << 2) + i : 64 + (ty << 2) + (i - 4));
        float* dst0 = C + (size_t)r * ldc + n0 + (tx << 2);
        float* dst1 = dst0 + 64;
        float4 o0 = make_float4(acc[i][0], acc[i][1], acc[i][2], acc[i][3]);
        float4 o1 = make_float4(acc[i][4], acc[i][5], acc[i][6], acc[i][7]);
        if (TWOPASS) {
            float4 c0 = *(const float4*)dst0;
            float4 c1 = *(const float4*)dst1;
            o0.x += c0.x; o0.y += c0.y; o0.z += c0.z; o0.w += c0.w;
            o1.x += c1.x; o1.y += c1.y; o1.z += c1.z; o1.w += c1.w;
        }
        *(float4*)dst0 = o0;
        *(float4*)dst1 = o1;
    }
}

// -------------- dual GEMM 128x64: h = silu(A@Bg) * (A@Bx) ------------------
__global__ __launch_bounds__(256) void gemm_dual_silu_k(
    const float* __restrict__ A, int lda,
    const float* __restrict__ Bx, const float* __restrict__ Bg, int ldb, int K,
    float* __restrict__ C, int ldc)
{
    __shared__ float As[16][132];
    __shared__ float Bs[2][16][64];
    const int m0 = blockIdx.y << 7;
    const int n0 = blockIdx.x << 6;
    const int t  = threadIdx.x;
    const int tx = t & 15, ty = t >> 4;
    const int ar = t >> 2, aq = (t & 3) << 2;
    const int br = t >> 4, bq = (t & 15) << 2;

    float accX[8][4], accG[8][4];
    #pragma unroll
    for (int i = 0; i < 8; ++i)
        #pragma unroll
        for (int jj = 0; jj < 4; ++jj) { accX[i][jj] = 0.f; accG[i][jj] = 0.f; }

    for (int k0 = 0; k0 < K; k0 += 16) {
        __syncthreads();
        float4 av0 = *(const float4*)(A + (size_t)(m0 + ar) * lda + k0 + aq);
        float4 av1 = *(const float4*)(A + (size_t)(m0 + ar + 64) * lda + k0 + aq);
        As[aq + 0][ar] = av0.x; As[aq + 1][ar] = av0.y;
        As[aq + 2][ar] = av0.z; As[aq + 3][ar] = av0.w;
        As[aq + 0][ar + 64] = av1.x; As[aq + 1][ar + 64] = av1.y;
        As[aq + 2][ar + 64] = av1.z; As[aq + 3][ar + 64] = av1.w;
        *(float4*)&Bs[0][br][bq] = *(const float4*)(Bx + (size_t)(k0 + br) * ldb + n0 + bq);
        *(float4*)&Bs[1][br][bq] = *(const float4*)(Bg + (size_t)(k0 + br) * ldb + n0 + bq);
        __syncthreads();
        #pragma unroll
        for (int k = 0; k < 16; ++k) {
            float a[8], bx[4], bg[4];
            *(float4*)&a[0] = *(const float4*)&As[k][ty << 2];
            *(float4*)&a[4] = *(const float4*)&As[k][64 + (ty << 2)];
            *(float4*)&bx[0] = *(const float4*)&Bs[0][k][tx << 2];
            *(float4*)&bg[0] = *(const float4*)&Bs[1][k][tx << 2];
            #pragma unroll
            for (int i = 0; i < 8; ++i)
                #pragma unroll
                for (int jj = 0; jj < 4; ++jj) {
                    accX[i][jj] = fmaf(a[i], bx[jj], accX[i][jj]);
                    accG[i][jj] = fmaf(a[i], bg[jj], accG[i][jj]);
                }
        }
    }

    #pragma unroll
    for (int i = 0; i < 8; ++i) {
        const int r = m0 + ((i < 4) ? (ty << 2) + i : 64 + (ty << 2) + (i - 4));
        float o[4];
        #pragma unroll
        for (int jj = 0; jj < 4; ++jj) {
            float gv = accG[i][jj];
            float sig = 1.0f / (1.0f + expf(-gv));
            o[jj] = gv * sig * accX[i][jj];
        }
        *(float4*)(C + (size_t)r * ldc + n0 + (tx << 2)) =
            make_float4(o[0], o[1], o[2], o[3]);
    }
}

// ------------------------------ attention (flash, microtiled) --------------
// grid: (SEQ/64, NHEAD, NBATCH), block 256. Each thread: 4 rows x 4 cols.
__global__ __launch_bounds__(256) void attn_k(const float* __restrict__ qkv,
                                              float* __restrict__ ctx,
                                              const int* __restrict__ vl)
{
    const int rc = blockIdx.x;
    const int h  = blockIdx.y;
    const int b  = blockIdx.z;
    const int i0 = rc << 6;
    const int t  = threadIdx.x;
    const int tx = t & 15, ty = t >> 4;

    __shared__ float QT[64][68];   // QT[d][i]
    __shared__ float KT[64][68];   // KT[d][j]
    __shared__ float Vs[64][68];   // Vs[j][d]
    __shared__ float PT[64][68];   // PT[j][i]

    const int VL = vl[b];

    // stage Q transposed (post-RoPE, pre-scaled)
    for (int idx = t; idx < 1024; idx += 256) {
        const int r = idx >> 4, c4 = (idx & 15) << 2;
        float4 qv = *(const float4*)&qkv[((size_t)((b << 9) + i0 + r)) * QKVC + (h << 6) + c4];
        QT[c4 + 0][r] = qv.x; QT[c4 + 1][r] = qv.y;
        QT[c4 + 2][r] = qv.z; QT[c4 + 3][r] = qv.w;
    }

    float m[4], l[4], o[4][4];
    #pragma unroll
    for (int r = 0; r < 4; ++r) {
        m[r] = -3.0e38f; l[r] = 0.f;
        #pragma unroll
        for (int c = 0; c < 4; ++c) o[r][c] = 0.f;
    }

    for (int j0 = 0; j0 < SEQ; j0 += 64) {
        __syncthreads();   // prev tile's consumers done (KT, Vs, PT free)
        // stage K transposed + V row-major
        for (int idx = t; idx < 1024; idx += 256) {
            const int r = idx >> 4, c4 = (idx & 15) << 2;
            const float* src = &qkv[((size_t)((b << 9) + j0 + r)) * QKVC + 512 + c4];
            float4 kv = *(const float4*)src;
            KT[c4 + 0][r] = kv.x; KT[c4 + 1][r] = kv.y;
            KT[c4 + 2][r] = kv.z; KT[c4 + 3][r] = kv.w;
            *(float4*)&Vs[r][c4] = *(const float4*)(src + 64);
        }
        __syncthreads();

        // scores: s[r][c] = sum_d Q[i0+ty*4+r][d] * K[j0+tx*4+c][d]
        float s[4][4];
        #pragma unroll
        for (int r = 0; r < 4; ++r)
            #pragma unroll
            for (int c = 0; c < 4; ++c) s[r][c] = 0.f;
        #pragma unroll 16
        for (int k = 0; k < 64; ++k) {
            float4 a4 = *(const float4*)&QT[k][ty << 2];
            float4 b4 = *(const float4*)&KT[k][tx << 2];
            float av[4] = {a4.x, a4.y, a4.z, a4.w};
            float bv[4] = {b4.x, b4.y, b4.z, b4.w};
            #pragma unroll
            for (int r = 0; r < 4; ++r)
                #pragma unroll
                for (int c = 0; c < 4; ++c)
                    s[r][c] = fmaf(av[r], bv[c], s[r][c]);
        }

        // mask
        const int jb = j0 + (tx << 2);
        #pragma unroll
        for (int c = 0; c < 4; ++c) {
            if (jb + c >= VL) {
                #pragma unroll
                for (int r = 0; r < 4; ++r) s[r][c] = -3.0e38f;
            }
        }

        // online softmax update (m shared across tx; l kept as partials)
        #pragma unroll
        for (int r = 0; r < 4; ++r) {
            float tmax = fmaxf(fmaxf(s[r][0], s[r][1]), fmaxf(s[r][2], s[r][3]));
            #pragma unroll
            for (int off = 8; off; off >>= 1) tmax = fmaxf(tmax, __shfl_xor(tmax, off));
            float nm = fmaxf(m[r], tmax);
            float scl = expf(m[r] - nm);
            float ps = 0.f;
            #pragma unroll
            for (int c = 0; c < 4; ++c) {
                float e = expf(s[r][c] - nm);
                s[r][c] = e;
                ps += e;
            }
            l[r] = l[r] * scl + ps;
            #pragma unroll
            for (int c = 0; c < 4; ++c) o[r][c] *= scl;
            m[r] = nm;
        }

        // write P transposed: PT[j][i]
        #pragma unroll
        for (int c = 0; c < 4; ++c) {
            float4 pv = make_float4(s[0][c], s[1][c], s[2][c], s[3][c]);
            *(float4*)&PT[(tx << 2) + c][ty << 2] = pv;
        }
        __syncthreads();

        // PV: o[r][c] += sum_j P[i][j] * V[j][d]
        #pragma unroll 16
        for (int k = 0; k < 64; ++k) {
            float4 a4 = *(const float4*)&PT[k][ty << 2];
            float4 b4 = *(const float4*)&Vs[k][tx << 2];
            float av[4] = {a4.x, a4.y, a4.z, a4.w};
            float bv[4] = {b4.x, b4.y, b4.z, b4.w};
            #pragma unroll
            for (int r = 0; r < 4; ++r)
                #pragma unroll
                for (int c = 0; c < 4; ++c)
                    o[r][c] = fmaf(av[r], bv[c], o[r][c]);
        }
    }

    // final: reduce l across tx, scale, store
    #pragma unroll
    for (int r = 0; r < 4; ++r) {
        float lt = l[r];
        #pragma unroll
        for (int off = 8; off; off >>= 1) lt += __shfl_xor(lt, off);
        float inv = 1.0f / lt;
        const int row = (b << 9) + i0 + (ty << 2) + r;
        *(float4*)&ctx[(size_t)row * DIMM + (h << 6) + (tx << 2)] =
            make_float4(o[r][0] * inv, o[r][1] * inv, o[r][2] * inv, o[r][3] * inv);
    }
}

// ------------------------------ pool ---------------------------------------
__global__ __launch_bounds__(512) void pool_part_k(const float* __restrict__ x,
                                                   float* __restrict__ psum,
                                                   float* __restrict__ pmax)
{
    const int seg = blockIdx.x;    // 0..7
    const int b   = blockIdx.y;
    const int d   = threadIdx.x;
    const float* xb = x + ((size_t)(b << 9) + (seg << 6)) * DIMM;
    float s = 0.f, m = -3.0e38f;
    for (int i = 0; i < 64; ++i) {
        float v = xb[(size_t)i * DIMM + d];
        s += v;
        m = fmaxf(m, v);
    }
    psum[((size_t)b * 8 + seg) * DIMM + d] = s;
    pmax[((size_t)b * 8 + seg) * DIMM + d] = m;
}

__global__ __launch_bounds__(512) void pool_comb_k(const float* __restrict__ psum,
                                                   const float* __restrict__ pmax,
                                                   float* __restrict__ out)
{
    const int b = blockIdx.x;
    const int d = threadIdx.x;
    float s = 0.f, m = -3.0e38f;
    #pragma unroll
    for (int seg = 0; seg < 8; ++seg) {
        s += psum[((size_t)b * 8 + seg) * DIMM + d];
        m = fmaxf(m, pmax[((size_t)b * 8 + seg) * DIMM + d]);
    }
    out[b * 1024 + d] = s * (1.0f / 512.0f);
    out[b * 1024 + 512 + d] = m;
}

// ---------------------------------------------------------------------------
extern "C" void kernel_launch(void* const* d_in, const int* in_sizes, int n_in,
                              void* d_out, int out_size, void* d_ws, size_t ws_size,
                              hipStream_t stream)
{
    const int*   page_in        = (const int*)d_in[0];
    const int*   item_in        = (const int*)d_in[1];
    const int*   item_meta_in   = (const int*)d_in[2];
    const int*   vl_in          = (const int*)d_in[3];
    const int*   page_meta_in   = (const int*)d_in[4];
    const float* pwide          = (const float*)d_in[5];
    const float* iwide          = (const float*)d_in[6];
    const float* page_emb       = (const float*)d_in[7];
    const float* page_meta_emb  = (const float*)d_in[8];
    const float* item_emb       = (const float*)d_in[9];
    const float* item_meta_emb  = (const float*)d_in[10];
    const float* item_pre_emb   = (const float*)d_in[11];
    const float* pW             = (const float*)d_in[12];
    const float* pb             = (const float*)d_in[13];
    const float* pg             = (const float*)d_in[14];
    const float* pbeta          = (const float*)d_in[15];
    const float* iW             = (const float*)d_in[16];
    const float* ib             = (const float*)d_in[17];
    const float* ig             = (const float*)d_in[18];
    const float* ibeta          = (const float*)d_in[19];
    const float* norm_g         = (const float*)d_in[20];
    const float* fused_W        = (const float*)d_in[21];
    const float* attn_out_W     = (const float*)d_in[22];
    const float* ff_out_W       = (const float*)d_in[23];
    float* out = (float*)d_out;

    float* ws  = (float*)d_ws;
    float* x    = ws;                               // 16384*512
    float* xn   = x    + (size_t)NROWS * DIMM;      // 16384*512
    float* qkv  = xn   + (size_t)NROWS * DIMM;      // 16384*640
    float* h    = qkv  + (size_t)NROWS * QKVC;      // 16384*2048
    float* ctx  = h    + (size_t)NROWS * FFIN;      // 16384*512
    float* psum = ctx  + (size_t)NROWS * DIMM;      // 32*8*512
    float* pmax = psum + (size_t)NBATCH * 8 * DIMM; // 32*8*512

    build_x_k<<<NROWS, 512, 0, stream>>>(
        page_in, item_in, item_meta_in, page_meta_in, pwide, iwide,
        page_emb, page_meta_emb, item_emb, item_meta_emb, item_pre_emb,
        pW, pb, pg, pbeta, iW, ib, ig, ibeta, x);

    for (int l = 0; l < 4; ++l) {
        const float* Wf  = fused_W    + (size_t)l * DIMM * NFUSED;
        const float* Wa  = attn_out_W + (size_t)l * DIMM * DIMM;
        const float* Wff = ff_out_W   + (size_t)l * FFIN * DIMM;
        const float* g   = norm_g     + (size_t)l * DIMM;

        ln_k<<<NROWS, 256, 0, stream>>>(x, xn, g);

        gemm128x128_k<false><<<dim3(QKVC / 128, NROWS / 128), 256, 0, stream>>>(
            xn, DIMM, Wf, NFUSED, DIMM,
            nullptr, 0, nullptr, 0, 0,
            qkv, QKVC);

        rope_k<<<NROWS / 4, 256, 0, stream>>>(qkv);

        gemm_dual_silu_k<<<dim3(FFIN / 64, NROWS / 128), 256, 0, stream>>>(
            xn, DIMM, Wf + 640, Wf + 2688, NFUSED, DIMM, h, FFIN);

        attn_k<<<dim3(SEQ / 64, NHEAD, NBATCH), 256, 0, stream>>>(qkv, ctx, vl_in);

        gemm128x128_k<true><<<dim3(DIMM / 128, NROWS / 128), 256, 0, stream>>>(
            ctx, DIMM, Wa, DIMM, DIMM,
            h, FFIN, Wff, DIMM, FFIN,
            x, DIMM);
    }

    pool_part_k<<<dim3(8, NBATCH), 512, 0, stream>>>(x, psum, pmax);
    pool_comb_k<<<NBATCH, 512, 0, stream>>>(psum, pmax, out);
}

// Round 3
// 4698.367 us; speedup vs baseline: 1.9630x; 1.4530x over previous
//
#include <hip/hip_runtime.h>
#include <math.h>

// ---------------------------------------------------------------------------
// ParallelTransformerAEP forward.
// R2: dual(ff) GEMM -> split-bf16 MFMA (hi/lo decomposition, 3 products),
//     weights transposed+split per layer, ln emits xn hi/lo.
// ---------------------------------------------------------------------------

namespace {
constexpr int SEQ    = 512;
constexpr int NBATCH = 32;
constexpr int DIMM   = 512;
constexpr int NHEAD  = 8;
constexpr int FFIN   = 2048;
constexpr int NFUSED = 4736;
constexpr int NROWS  = NBATCH * SEQ;   // 16384
constexpr int QKVC   = 640;            // 512 q + 64 k + 64 v
}

typedef __bf16 bf16x8 __attribute__((ext_vector_type(8)));
typedef float f32x4 __attribute__((ext_vector_type(4)));
typedef unsigned short ushort8 __attribute__((ext_vector_type(8)));

static __device__ __forceinline__ unsigned short bfhi(float v, float* hf) {
    __bf16 h = (__bf16)v;
    *hf = (float)h;
    return __builtin_bit_cast(unsigned short, h);
}
static __device__ __forceinline__ unsigned short bflo(float v, float hf) {
    __bf16 l = (__bf16)(v - hf);
    return __builtin_bit_cast(unsigned short, l);
}

// ------------------------- build x = page * item ---------------------------
__global__ __launch_bounds__(512) void build_x_k(
    const int* __restrict__ page_in, const int* __restrict__ item_in,
    const int* __restrict__ item_meta_in, const int* __restrict__ page_meta_in,
    const float* __restrict__ pwide, const float* __restrict__ iwide,
    const float* __restrict__ page_emb, const float* __restrict__ page_meta_emb,
    const float* __restrict__ item_emb, const float* __restrict__ item_meta_emb,
    const float* __restrict__ item_pre_emb,
    const float* __restrict__ pW, const float* __restrict__ pb,
    const float* __restrict__ pg, const float* __restrict__ pbeta,
    const float* __restrict__ iW, const float* __restrict__ ib,
    const float* __restrict__ ig, const float* __restrict__ ibeta,
    float* __restrict__ x)
{
    const int row = blockIdx.x;
    const int b = row >> 9;
    const int s = row & 511;
    const int d = threadIdx.x;
    const float BNS = 0.9999950000374997f;   // 1/sqrt(1+1e-5)

    float pv, iv;
    if (d < 384) {
        pv = page_emb[(size_t)page_in[row] * 384 + d];
    } else if (d < 448) {
        pv = page_meta_emb[(size_t)page_meta_in[row] * 64 + (d - 384)];
    } else {
        const int dd = d - 448;
        float acc = pb[dd];
        #pragma unroll
        for (int c = 0; c < 8; ++c) {
            float w  = pwide[((size_t)b * 8 + c) * SEQ + s];
            float wn = w * BNS * pg[c] + pbeta[c];
            acc += wn * pW[c * 64 + dd];
        }
        pv = acc > 0.f ? acc : 0.2f * acc;
    }
    if (d < 320) {
        iv = item_emb[(size_t)item_in[row] * 320 + d];
    } else if (d < 384) {
        iv = item_meta_emb[(size_t)item_meta_in[row] * 64 + (d - 320)];
    } else if (d < 448) {
        iv = item_pre_emb[(size_t)item_in[row] * 64 + (d - 384)];
    } else {
        const int dd = d - 448;
        float acc = ib[dd];
        #pragma unroll
        for (int c = 0; c < 8; ++c) {
            float w  = iwide[((size_t)b * 8 + c) * SEQ + s];
            float wn = w * BNS * ig[c] + ibeta[c];
            acc += wn * iW[c * 64 + dd];
        }
        iv = acc > 0.f ? acc : 0.2f * acc;
    }
    x[(size_t)row * DIMM + d] = pv * iv;
}

// ------------------------------ LayerNorm ----------------------------------
// writes fp32 xn + bf16 hi/lo split
__global__ __launch_bounds__(256) void ln_k(const float* __restrict__ x,
                                            float* __restrict__ xn,
                                            unsigned short* __restrict__ xnh,
                                            unsigned short* __restrict__ xnl,
                                            const float* __restrict__ g)
{
    const int row = blockIdx.x;
    const int t = threadIdx.x;
    const float* xr = x + (size_t)row * DIMM;
    __shared__ float red[4];

    float v0 = xr[t], v1 = xr[t + 256];
    float s = v0 + v1;
    #pragma unroll
    for (int o = 32; o; o >>= 1) s += __shfl_xor(s, o);
    if ((t & 63) == 0) red[t >> 6] = s;
    __syncthreads();
    float mu = (red[0] + red[1] + red[2] + red[3]) * (1.0f / 512.0f);
    __syncthreads();

    float d0 = v0 - mu, d1 = v1 - mu;
    float vs = d0 * d0 + d1 * d1;
    #pragma unroll
    for (int o = 32; o; o >>= 1) vs += __shfl_xor(vs, o);
    if ((t & 63) == 0) red[t >> 6] = vs;
    __syncthreads();
    float var = (red[0] + red[1] + red[2] + red[3]) * (1.0f / 512.0f);
    float r = 1.0f / sqrtf(var + 1e-5f);

    const size_t base = (size_t)row * DIMM;
    float o0 = d0 * r * g[t];
    float o1 = d1 * r * g[t + 256];
    xn[base + t]       = o0;
    xn[base + t + 256] = o1;
    float h0f, h1f;
    xnh[base + t]       = bfhi(o0, &h0f);
    xnh[base + t + 256] = bfhi(o1, &h1f);
    xnl[base + t]       = bflo(o0, h0f);
    xnl[base + t + 256] = bflo(o1, h1f);
}

// ---------------- weight transpose + split: WT[n][k] = W[k][col0+n] --------
// grid: (ncols/64, K/64), block 256
__global__ __launch_bounds__(256) void wconv_k(const float* __restrict__ W, int ldw,
                                               int col0,
                                               unsigned short* __restrict__ WTh,
                                               unsigned short* __restrict__ WTl,
                                               int ldt /* = K = 512 */)
{
    __shared__ float tile[64][65];
    const int nt = blockIdx.x << 6;
    const int kt = blockIdx.y << 6;
    const int t  = threadIdx.x;

    #pragma unroll
    for (int i = 0; i < 16; ++i) {
        int flat = i * 256 + t;            // 0..4095
        int r = flat >> 6, c = flat & 63;  // r: k-row, c: n-col
        tile[r][c] = W[(size_t)(kt + r) * ldw + col0 + nt + c];
    }
    __syncthreads();
    #pragma unroll
    for (int i = 0; i < 2; ++i) {
        int flat = i * 256 + t;            // 0..511
        int n = flat >> 3, ck = (flat & 7) << 3;
        ushort8 hv, lv;
        #pragma unroll
        for (int j = 0; j < 8; ++j) {
            float v = tile[ck + j][n];
            float hf;
            hv[j] = bfhi(v, &hf);
            lv[j] = bflo(v, hf);
        }
        size_t o = (size_t)(nt + n) * ldt + kt + ck;
        *(ushort8*)&WTh[o] = hv;
        *(ushort8*)&WTl[o] = lv;
    }
}

// ------------------------------ RoPE (q,k in-place) ------------------------
__global__ __launch_bounds__(256) void rope_k(float* __restrict__ qkv)
{
    const int row = (blockIdx.x << 2) + (threadIdx.x >> 6);
    const int s = row & 511;
    const int d = threadIdx.x & 63;
    const int j = d & 31;

    float invf = powf(10000.0f, -(float)j * (1.0f / 32.0f));
    float ang = (float)s * invf;
    float sn, cs;
    sincosf(ang, &sn, &cs);

    float* rowp = qkv + (size_t)row * QKVC;
    const int pair = (d < 32) ? d + 32 : d - 32;
    const float sgn = (d < 32) ? -1.f : 1.f;

    float kv = rowp[512 + d];
    float kp = rowp[512 + pair];
    float qv[NHEAD], qp[NHEAD];
    #pragma unroll
    for (int h = 0; h < NHEAD; ++h) {
        qv[h] = rowp[h * 64 + d];
        qp[h] = rowp[h * 64 + pair];
    }
    rowp[512 + d] = kv * cs + sgn * kp * sn;
    #pragma unroll
    for (int h = 0; h < NHEAD; ++h)
        rowp[h * 64 + d] = (qv[h] * cs + sgn * qp[h] * sn) * 0.125f;
}

// --------------------- fp32 GEMM 128x128 (single or two-pass+residual) -----
template <bool TWOPASS>
__global__ __launch_bounds__(256) void gemm128x128_k(
    const float* __restrict__ A, int lda,
    const float* __restrict__ B, int ldb, int K,
    const float* __restrict__ A2, int lda2,
    const float* __restrict__ B2, int ldb2, int K2,
    float* __restrict__ C, int ldc)
{
    __shared__ float As[16][132];
    __shared__ float Bs[16][128];
    const int m0 = blockIdx.y << 7;
    const int n0 = blockIdx.x << 7;
    const int t  = threadIdx.x;
    const int tx = t & 15, ty = t >> 4;
    const int ar = t >> 2, aq = (t & 3) << 2;
    const int br = t >> 5, bq = (t & 31) << 2;

    float acc[8][8];
    #pragma unroll
    for (int i = 0; i < 8; ++i)
        #pragma unroll
        for (int jj = 0; jj < 8; ++jj) acc[i][jj] = 0.f;

    for (int pass = 0; pass < (TWOPASS ? 2 : 1); ++pass) {
        const float* Ap = pass ? A2 : A;
        const float* Bp = pass ? B2 : B;
        const int la = pass ? lda2 : lda;
        const int lb = pass ? ldb2 : ldb;
        const int KK = pass ? K2 : K;
        for (int k0 = 0; k0 < KK; k0 += 16) {
            __syncthreads();
            float4 av0 = *(const float4*)(Ap + (size_t)(m0 + ar) * la + k0 + aq);
            float4 av1 = *(const float4*)(Ap + (size_t)(m0 + ar + 64) * la + k0 + aq);
            As[aq + 0][ar] = av0.x; As[aq + 1][ar] = av0.y;
            As[aq + 2][ar] = av0.z; As[aq + 3][ar] = av0.w;
            As[aq + 0][ar + 64] = av1.x; As[aq + 1][ar + 64] = av1.y;
            As[aq + 2][ar + 64] = av1.z; As[aq + 3][ar + 64] = av1.w;
            *(float4*)&Bs[br][bq]     = *(const float4*)(Bp + (size_t)(k0 + br) * lb + n0 + bq);
            *(float4*)&Bs[br + 8][bq] = *(const float4*)(Bp + (size_t)(k0 + br + 8) * lb + n0 + bq);
            __syncthreads();
            #pragma unroll
            for (int k = 0; k < 16; ++k) {
                float a[8], bb[8];
                *(float4*)&a[0]  = *(const float4*)&As[k][ty << 2];
                *(float4*)&a[4]  = *(const float4*)&As[k][64 + (ty << 2)];
                *(float4*)&bb[0] = *(const float4*)&Bs[k][tx << 2];
                *(float4*)&bb[4] = *(const float4*)&Bs[k][64 + (tx << 2)];
                #pragma unroll
                for (int i = 0; i < 8; ++i)
                    #pragma unroll
                    for (int jj = 0; jj < 8; ++jj)
                        acc[i][jj] = fmaf(a[i], bb[jj], acc[i][jj]);
            }
        }
    }

    #pragma unroll
    for (int i = 0; i < 8; ++i) {
        const int r = m0 + ((i < 4) ? (ty << 2) + i : 64 + (ty << 2) + (i - 4));
        float* dst0 = C + (size_t)r * ldc + n0 + (tx << 2);
        float* dst1 = dst0 + 64;
        float4 o0 = make_float4(acc[i][0], acc[i][1], acc[i][2], acc[i][3]);
        float4 o1 = make_float4(acc[i][4], acc[i][5], acc[i][6], acc[i][7]);
        if (TWOPASS) {
            float4 c0 = *(const float4*)dst0;
            float4 c1 = *(const float4*)dst1;
            o0.x += c0.x; o0.y += c0.y; o0.z += c0.z; o0.w += c0.w;
            o1.x += c1.x; o1.y += c1.y; o1.z += c1.z; o1.w += c1.w;
        }
        *(float4*)dst0 = o0;
        *(float4*)dst1 = o1;
    }
}

// ------------- MFMA dual GEMM: h = silu(A@Wg) * (A@Wx), split bf16 ---------
// A: hi/lo [M][512] bf16. WT: hi/lo [4096][512] bf16 (rows 0..2047 = x-part
// transposed, 2048..4095 = gate-part transposed).
// grid: (2048/64, M/128), block 256 (4 waves: wm in {0,1} x wn in {0,1}).
__global__ __launch_bounds__(256, 2) void mfma_dual_silu_k(
    const unsigned short* __restrict__ Ah, const unsigned short* __restrict__ Al,
    const unsigned short* __restrict__ WTh, const unsigned short* __restrict__ WTl,
    float* __restrict__ H)
{
    __shared__ unsigned short sAh[128 * 64];
    __shared__ unsigned short sAl[128 * 64];
    __shared__ unsigned short sBxh[64 * 64];
    __shared__ unsigned short sBxl[64 * 64];
    __shared__ unsigned short sBgh[64 * 64];
    __shared__ unsigned short sBgl[64 * 64];

    const int n0 = blockIdx.x << 6;
    const int m0 = blockIdx.y << 7;
    const int t  = threadIdx.x;
    const int l  = t & 63;
    const int w  = t >> 6;
    const int wm = w >> 1, wn = w & 1;
    const int lr = l & 15, lg = l >> 4;

    f32x4 accX[4][2], accG[4][2];
    #pragma unroll
    for (int fm = 0; fm < 4; ++fm)
        #pragma unroll
        for (int fn = 0; fn < 2; ++fn) {
            accX[fm][fn] = (f32x4)0.f;
            accG[fm][fn] = (f32x4)0.f;
        }

    for (int k0 = 0; k0 < DIMM; k0 += 64) {
        __syncthreads();
        // stage A (hi,lo): 128 rows x 8 chunks of 8 bf16, XOR-swizzled
        #pragma unroll
        for (int i = 0; i < 4; ++i) {
            int flat = i * 256 + t;          // 0..1023
            int m = flat >> 3, c = flat & 7;
            size_t gidx = (size_t)(m0 + m) * DIMM + k0 + c * 8;
            int lidx = m * 64 + ((c ^ (m & 7)) << 3);
            *(ushort8*)&sAh[lidx] = *(const ushort8*)&Ah[gidx];
            *(ushort8*)&sAl[lidx] = *(const ushort8*)&Al[gidx];
        }
        // stage B (x,g)x(hi,lo): 64 rows x 8 chunks
        #pragma unroll
        for (int i = 0; i < 2; ++i) {
            int flat = i * 256 + t;          // 0..511
            int n = flat >> 3, c = flat & 7;
            size_t gx = (size_t)(n0 + n) * DIMM + k0 + c * 8;
            size_t gg = (size_t)(2048 + n0 + n) * DIMM + k0 + c * 8;
            int lidx = n * 64 + ((c ^ (n & 7)) << 3);
            *(ushort8*)&sBxh[lidx] = *(const ushort8*)&WTh[gx];
            *(ushort8*)&sBxl[lidx] = *(const ushort8*)&WTl[gx];
            *(ushort8*)&sBgh[lidx] = *(const ushort8*)&WTh[gg];
            *(ushort8*)&sBgl[lidx] = *(const ushort8*)&WTl[gg];
        }
        __syncthreads();

        #pragma unroll
        for (int kk = 0; kk < 2; ++kk) {
            const int c = kk * 4 + lg;
            bf16x8 afh[4], afl[4];
            #pragma unroll
            for (int fm = 0; fm < 4; ++fm) {
                int m = wm * 64 + fm * 16 + lr;
                int lidx = m * 64 + ((c ^ (m & 7)) << 3);
                afh[fm] = *(bf16x8*)&sAh[lidx];
                afl[fm] = *(bf16x8*)&sAl[lidx];
            }
            bf16x8 bxh[2], bxl[2], bgh[2], bgl[2];
            #pragma unroll
            for (int fn = 0; fn < 2; ++fn) {
                int n = wn * 32 + fn * 16 + lr;
                int lidx = n * 64 + ((c ^ (n & 7)) << 3);
                bxh[fn] = *(bf16x8*)&sBxh[lidx];
                bxl[fn] = *(bf16x8*)&sBxl[lidx];
                bgh[fn] = *(bf16x8*)&sBgh[lidx];
                bgl[fn] = *(bf16x8*)&sBgl[lidx];
            }
            #pragma unroll
            for (int fm = 0; fm < 4; ++fm)
                #pragma unroll
                for (int fn = 0; fn < 2; ++fn) {
                    accX[fm][fn] = __builtin_amdgcn_mfma_f32_16x16x32_bf16(afh[fm], bxh[fn], accX[fm][fn], 0, 0, 0);
                    accX[fm][fn] = __builtin_amdgcn_mfma_f32_16x16x32_bf16(afh[fm], bxl[fn], accX[fm][fn], 0, 0, 0);
                    accX[fm][fn] = __builtin_amdgcn_mfma_f32_16x16x32_bf16(afl[fm], bxh[fn], accX[fm][fn], 0, 0, 0);
                    accG[fm][fn] = __builtin_amdgcn_mfma_f32_16x16x32_bf16(afh[fm], bgh[fn], accG[fm][fn], 0, 0, 0);
                    accG[fm][fn] = __builtin_amdgcn_mfma_f32_16x16x32_bf16(afh[fm], bgl[fn], accG[fm][fn], 0, 0, 0);
                    accG[fm][fn] = __builtin_amdgcn_mfma_f32_16x16x32_bf16(afl[fm], bgh[fn], accG[fm][fn], 0, 0, 0);
                }
        }
    }

    // epilogue: silu(gate)*x, write fp32 H[M][2048]
    // D layout: col = lane&15, row = 4*(lane>>4) + r
    #pragma unroll
    for (int fm = 0; fm < 4; ++fm)
        #pragma unroll
        for (int fn = 0; fn < 2; ++fn) {
            const int n = n0 + wn * 32 + fn * 16 + lr;
            #pragma unroll
            for (int r = 0; r < 4; ++r) {
                const int m = m0 + wm * 64 + fm * 16 + lg * 4 + r;
                float gv = accG[fm][fn][r];
                float xv = accX[fm][fn][r];
                float sig = 1.0f / (1.0f + expf(-gv));
                H[(size_t)m * FFIN + n] = gv * sig * xv;
            }
        }
}

// ------------------------------ attention (flash, microtiled) --------------
__global__ __launch_bounds__(256) void attn_k(const float* __restrict__ qkv,
                                              float* __restrict__ ctx,
                                              const int* __restrict__ vl)
{
    const int rc = blockIdx.x;
    const int h  = blockIdx.y;
    const int b  = blockIdx.z;
    const int i0 = rc << 6;
    const int t  = threadIdx.x;
    const int tx = t & 15, ty = t >> 4;

    __shared__ float QT[64][68];
    __shared__ float KT[64][68];
    __shared__ float Vs[64][68];
    __shared__ float PT[64][68];

    const int VL = vl[b];

    for (int idx = t; idx < 1024; idx += 256) {
        const int r = idx >> 4, c4 = (idx & 15) << 2;
        float4 qv = *(const float4*)&qkv[((size_t)((b << 9) + i0 + r)) * QKVC + (h << 6) + c4];
        QT[c4 + 0][r] = qv.x; QT[c4 + 1][r] = qv.y;
        QT[c4 + 2][r] = qv.z; QT[c4 + 3][r] = qv.w;
    }

    float m[4], l[4], o[4][4];
    #pragma unroll
    for (int r = 0; r < 4; ++r) {
        m[r] = -3.0e38f; l[r] = 0.f;
        #pragma unroll
        for (int c = 0; c < 4; ++c) o[r][c] = 0.f;
    }

    for (int j0 = 0; j0 < SEQ; j0 += 64) {
        __syncthreads();
        for (int idx = t; idx < 1024; idx += 256) {
            const int r = idx >> 4, c4 = (idx & 15) << 2;
            const float* src = &qkv[((size_t)((b << 9) + j0 + r)) * QKVC + 512 + c4];
            float4 kv = *(const float4*)src;
            KT[c4 + 0][r] = kv.x; KT[c4 + 1][r] = kv.y;
            KT[c4 + 2][r] = kv.z; KT[c4 + 3][r] = kv.w;
            *(float4*)&Vs[r][c4] = *(const float4*)(src + 64);
        }
        __syncthreads();

        float s[4][4];
        #pragma unroll
        for (int r = 0; r < 4; ++r)
            #pragma unroll
            for (int c = 0; c < 4; ++c) s[r][c] = 0.f;
        #pragma unroll 16
        for (int k = 0; k < 64; ++k) {
            float4 a4 = *(const float4*)&QT[k][ty << 2];
            float4 b4 = *(const float4*)&KT[k][tx << 2];
            float av[4] = {a4.x, a4.y, a4.z, a4.w};
            float bv[4] = {b4.x, b4.y, b4.z, b4.w};
            #pragma unroll
            for (int r = 0; r < 4; ++r)
                #pragma unroll
                for (int c = 0; c < 4; ++c)
                    s[r][c] = fmaf(av[r], bv[c], s[r][c]);
        }

        const int jb = j0 + (tx << 2);
        #pragma unroll
        for (int c = 0; c < 4; ++c) {
            if (jb + c >= VL) {
                #pragma unroll
                for (int r = 0; r < 4; ++r) s[r][c] = -3.0e38f;
            }
        }

        #pragma unroll
        for (int r = 0; r < 4; ++r) {
            float tmax = fmaxf(fmaxf(s[r][0], s[r][1]), fmaxf(s[r][2], s[r][3]));
            #pragma unroll
            for (int off = 8; off; off >>= 1) tmax = fmaxf(tmax, __shfl_xor(tmax, off));
            float nm = fmaxf(m[r], tmax);
            float scl = expf(m[r] - nm);
            float ps = 0.f;
            #pragma unroll
            for (int c = 0; c < 4; ++c) {
                float e = expf(s[r][c] - nm);
                s[r][c] = e;
                ps += e;
            }
            l[r] = l[r] * scl + ps;
            #pragma unroll
            for (int c = 0; c < 4; ++c) o[r][c] *= scl;
            m[r] = nm;
        }

        #pragma unroll
        for (int c = 0; c < 4; ++c) {
            float4 pv = make_float4(s[0][c], s[1][c], s[2][c], s[3][c]);
            *(float4*)&PT[(tx << 2) + c][ty << 2] = pv;
        }
        __syncthreads();

        #pragma unroll 16
        for (int k = 0; k < 64; ++k) {
            float4 a4 = *(const float4*)&PT[k][ty << 2];
            float4 b4 = *(const float4*)&Vs[k][tx << 2];
            float av[4] = {a4.x, a4.y, a4.z, a4.w};
            float bv[4] = {b4.x, b4.y, b4.z, b4.w};
            #pragma unroll
            for (int r = 0; r < 4; ++r)
                #pragma unroll
                for (int c = 0; c < 4; ++c)
                    o[r][c] = fmaf(av[r], bv[c], o[r][c]);
        }
    }

    #pragma unroll
    for (int r = 0; r < 4; ++r) {
        float lt = l[r];
        #pragma unroll
        for (int off = 8; off; off >>= 1) lt += __shfl_xor(lt, off);
        float inv = 1.0f / lt;
        const int row = (b << 9) + i0 + (ty << 2) + r;
        *(float4*)&ctx[(size_t)row * DIMM + (h << 6) + (tx << 2)] =
            make_float4(o[r][0] * inv, o[r][1] * inv, o[r][2] * inv, o[r][3] * inv);
    }
}

// ------------------------------ pool ---------------------------------------
__global__ __launch_bounds__(512) void pool_part_k(const float* __restrict__ x,
                                                   float* __restrict__ psum,
                                                   float* __restrict__ pmax)
{
    const int seg = blockIdx.x;
    const int b   = blockIdx.y;
    const int d   = threadIdx.x;
    const float* xb = x + ((size_t)(b << 9) + (seg << 6)) * DIMM;
    float s = 0.f, m = -3.0e38f;
    for (int i = 0; i < 64; ++i) {
        float v = xb[(size_t)i * DIMM + d];
        s += v;
        m = fmaxf(m, v);
    }
    psum[((size_t)b * 8 + seg) * DIMM + d] = s;
    pmax[((size_t)b * 8 + seg) * DIMM + d] = m;
}

__global__ __launch_bounds__(512) void pool_comb_k(const float* __restrict__ psum,
                                                   const float* __restrict__ pmax,
                                                   float* __restrict__ out)
{
    const int b = blockIdx.x;
    const int d = threadIdx.x;
    float s = 0.f, m = -3.0e38f;
    #pragma unroll
    for (int seg = 0; seg < 8; ++seg) {
        s += psum[((size_t)b * 8 + seg) * DIMM + d];
        m = fmaxf(m, pmax[((size_t)b * 8 + seg) * DIMM + d]);
    }
    out[b * 1024 + d] = s * (1.0f / 512.0f);
    out[b * 1024 + 512 + d] = m;
}

// ---------------------------------------------------------------------------
extern "C" void kernel_launch(void* const* d_in, const int* in_sizes, int n_in,
                              void* d_out, int out_size, void* d_ws, size_t ws_size,
                              hipStream_t stream)
{
    const int*   page_in        = (const int*)d_in[0];
    const int*   item_in        = (const int*)d_in[1];
    const int*   item_meta_in   = (const int*)d_in[2];
    const int*   vl_in          = (const int*)d_in[3];
    const int*   page_meta_in   = (const int*)d_in[4];
    const float* pwide          = (const float*)d_in[5];
    const float* iwide          = (const float*)d_in[6];
    const float* page_emb       = (const float*)d_in[7];
    const float* page_meta_emb  = (const float*)d_in[8];
    const float* item_emb       = (const float*)d_in[9];
    const float* item_meta_emb  = (const float*)d_in[10];
    const float* item_pre_emb   = (const float*)d_in[11];
    const float* pW             = (const float*)d_in[12];
    const float* pb             = (const float*)d_in[13];
    const float* pg             = (const float*)d_in[14];
    const float* pbeta          = (const float*)d_in[15];
    const float* iW             = (const float*)d_in[16];
    const float* ib             = (const float*)d_in[17];
    const float* ig             = (const float*)d_in[18];
    const float* ibeta          = (const float*)d_in[19];
    const float* norm_g         = (const float*)d_in[20];
    const float* fused_W        = (const float*)d_in[21];
    const float* attn_out_W     = (const float*)d_in[22];
    const float* ff_out_W       = (const float*)d_in[23];
    float* out = (float*)d_out;

    float* ws  = (float*)d_ws;
    float* x    = ws;                               // 16384*512
    float* xn   = x    + (size_t)NROWS * DIMM;      // 16384*512
    float* qkv  = xn   + (size_t)NROWS * DIMM;      // 16384*640
    float* h    = qkv  + (size_t)NROWS * QKVC;      // 16384*2048
    float* ctx  = h    + (size_t)NROWS * FFIN;      // 16384*512
    float* psum = ctx  + (size_t)NROWS * DIMM;      // 32*8*512
    float* pmax = psum + (size_t)NBATCH * 8 * DIMM; // 32*8*512
    unsigned short* xnh = (unsigned short*)(pmax + (size_t)NBATCH * 8 * DIMM);
    unsigned short* xnl = xnh + (size_t)NROWS * DIMM;
    unsigned short* WTh = xnl + (size_t)NROWS * DIMM;   // [4096][512]
    unsigned short* WTl = WTh + (size_t)4096 * DIMM;

    build_x_k<<<NROWS, 512, 0, stream>>>(
        page_in, item_in, item_meta_in, page_meta_in, pwide, iwide,
        page_emb, page_meta_emb, item_emb, item_meta_emb, item_pre_emb,
        pW, pb, pg, pbeta, iW, ib, ig, ibeta, x);

    for (int l = 0; l < 4; ++l) {
        const float* Wf  = fused_W    + (size_t)l * DIMM * NFUSED;
        const float* Wa  = attn_out_W + (size_t)l * DIMM * DIMM;
        const float* Wff = ff_out_W   + (size_t)l * FFIN * DIMM;
        const float* g   = norm_g     + (size_t)l * DIMM;

        ln_k<<<NROWS, 256, 0, stream>>>(x, xn, xnh, xnl, g);

        // transpose+split ff weight block (cols [640,4736) of Wf)
        wconv_k<<<dim3(4096 / 64, DIMM / 64), 256, 0, stream>>>(
            Wf, NFUSED, 640, WTh, WTl, DIMM);

        gemm128x128_k<false><<<dim3(QKVC / 128, NROWS / 128), 256, 0, stream>>>(
            xn, DIMM, Wf, NFUSED, DIMM,
            nullptr, 0, nullptr, 0, 0,
            qkv, QKVC);

        rope_k<<<NROWS / 4, 256, 0, stream>>>(qkv);

        mfma_dual_silu_k<<<dim3(FFIN / 64, NROWS / 128), 256, 0, stream>>>(
            xnh, xnl, WTh, WTl, h);

        attn_k<<<dim3(SEQ / 64, NHEAD, NBATCH), 256, 0, stream>>>(qkv, ctx, vl_in);

        gemm128x128_k<true><<<dim3(DIMM / 128, NROWS / 128), 256, 0, stream>>>(
            ctx, DIMM, Wa, DIMM, DIMM,
            h, FFIN, Wff, DIMM, FFIN,
            x, DIMM);
    }

    pool_part_k<<<dim3(8, NBATCH), 512, 0, stream>>>(x, psum, pmax);
    pool_comb_k<<<NBATCH, 512, 0, stream>>>(psum, pmax, out);
}

// Round 5
// 3292.026 us; speedup vs baseline: 2.8016x; 1.4272x over previous
//
#include <hip/hip_runtime.h>
#include <math.h>

// ---------------------------------------------------------------------------
// ParallelTransformerAEP forward.
// R4: R3 (all GEMMs split-bf16 MFMA) with B-tile staging loop fix
//     (flat = i*256+t, was i*128+t => unstaged LDS rows => NaN).
// ---------------------------------------------------------------------------

namespace {
constexpr int SEQ    = 512;
constexpr int NBATCH = 32;
constexpr int DIMM   = 512;
constexpr int NHEAD  = 8;
constexpr int FFIN   = 2048;
constexpr int NFUSED = 4736;
constexpr int NROWS  = NBATCH * SEQ;   // 16384
constexpr int QKVC   = 640;            // 512 q + 64 k + 64 v
}

typedef __bf16 bf16x8 __attribute__((ext_vector_type(8)));
typedef float f32x4 __attribute__((ext_vector_type(4)));
typedef unsigned short ushort8 __attribute__((ext_vector_type(8)));

static __device__ __forceinline__ unsigned short bfhi(float v, float* hf) {
    __bf16 h = (__bf16)v;
    *hf = (float)h;
    return __builtin_bit_cast(unsigned short, h);
}
static __device__ __forceinline__ unsigned short bflo(float v, float hf) {
    __bf16 l = (__bf16)(v - hf);
    return __builtin_bit_cast(unsigned short, l);
}

// ------------------------- build x = page * item ---------------------------
__global__ __launch_bounds__(512) void build_x_k(
    const int* __restrict__ page_in, const int* __restrict__ item_in,
    const int* __restrict__ item_meta_in, const int* __restrict__ page_meta_in,
    const float* __restrict__ pwide, const float* __restrict__ iwide,
    const float* __restrict__ page_emb, const float* __restrict__ page_meta_emb,
    const float* __restrict__ item_emb, const float* __restrict__ item_meta_emb,
    const float* __restrict__ item_pre_emb,
    const float* __restrict__ pW, const float* __restrict__ pb,
    const float* __restrict__ pg, const float* __restrict__ pbeta,
    const float* __restrict__ iW, const float* __restrict__ ib,
    const float* __restrict__ ig, const float* __restrict__ ibeta,
    float* __restrict__ x)
{
    const int row = blockIdx.x;
    const int b = row >> 9;
    const int s = row & 511;
    const int d = threadIdx.x;
    const float BNS = 0.9999950000374997f;   // 1/sqrt(1+1e-5)

    float pv, iv;
    if (d < 384) {
        pv = page_emb[(size_t)page_in[row] * 384 + d];
    } else if (d < 448) {
        pv = page_meta_emb[(size_t)page_meta_in[row] * 64 + (d - 384)];
    } else {
        const int dd = d - 448;
        float acc = pb[dd];
        #pragma unroll
        for (int c = 0; c < 8; ++c) {
            float w  = pwide[((size_t)b * 8 + c) * SEQ + s];
            float wn = w * BNS * pg[c] + pbeta[c];
            acc += wn * pW[c * 64 + dd];
        }
        pv = acc > 0.f ? acc : 0.2f * acc;
    }
    if (d < 320) {
        iv = item_emb[(size_t)item_in[row] * 320 + d];
    } else if (d < 384) {
        iv = item_meta_emb[(size_t)item_meta_in[row] * 64 + (d - 320)];
    } else if (d < 448) {
        iv = item_pre_emb[(size_t)item_in[row] * 64 + (d - 384)];
    } else {
        const int dd = d - 448;
        float acc = ib[dd];
        #pragma unroll
        for (int c = 0; c < 8; ++c) {
            float w  = iwide[((size_t)b * 8 + c) * SEQ + s];
            float wn = w * BNS * ig[c] + ibeta[c];
            acc += wn * iW[c * 64 + dd];
        }
        iv = acc > 0.f ? acc : 0.2f * acc;
    }
    x[(size_t)row * DIMM + d] = pv * iv;
}

// ------------------------------ LayerNorm -> bf16 hi/lo --------------------
__global__ __launch_bounds__(256) void ln_k(const float* __restrict__ x,
                                            unsigned short* __restrict__ xnh,
                                            unsigned short* __restrict__ xnl,
                                            const float* __restrict__ g)
{
    const int row = blockIdx.x;
    const int t = threadIdx.x;
    const float* xr = x + (size_t)row * DIMM;
    __shared__ float red[4];

    float v0 = xr[t], v1 = xr[t + 256];
    float s = v0 + v1;
    #pragma unroll
    for (int o = 32; o; o >>= 1) s += __shfl_xor(s, o);
    if ((t & 63) == 0) red[t >> 6] = s;
    __syncthreads();
    float mu = (red[0] + red[1] + red[2] + red[3]) * (1.0f / 512.0f);
    __syncthreads();

    float d0 = v0 - mu, d1 = v1 - mu;
    float vs = d0 * d0 + d1 * d1;
    #pragma unroll
    for (int o = 32; o; o >>= 1) vs += __shfl_xor(vs, o);
    if ((t & 63) == 0) red[t >> 6] = vs;
    __syncthreads();
    float var = (red[0] + red[1] + red[2] + red[3]) * (1.0f / 512.0f);
    float r = 1.0f / sqrtf(var + 1e-5f);

    const size_t base = (size_t)row * DIMM;
    float o0 = d0 * r * g[t];
    float o1 = d1 * r * g[t + 256];
    float h0f, h1f;
    xnh[base + t]       = bfhi(o0, &h0f);
    xnh[base + t + 256] = bfhi(o1, &h1f);
    xnl[base + t]       = bflo(o0, h0f);
    xnl[base + t + 256] = bflo(o1, h1f);
}

// ---------------- weight transpose + split: WT[n][k] = W[k][col0+n] --------
// grid: (ncols/64, K/64), block 256. ldt must equal K.
__global__ __launch_bounds__(256) void wconv_k(const float* __restrict__ W, int ldw,
                                               int col0,
                                               unsigned short* __restrict__ WTh,
                                               unsigned short* __restrict__ WTl,
                                               int ldt)
{
    __shared__ float tile[64][65];
    const int nt = blockIdx.x << 6;
    const int kt = blockIdx.y << 6;
    const int t  = threadIdx.x;

    #pragma unroll
    for (int i = 0; i < 16; ++i) {
        int flat = i * 256 + t;
        int r = flat >> 6, c = flat & 63;
        tile[r][c] = W[(size_t)(kt + r) * ldw + col0 + nt + c];
    }
    __syncthreads();
    #pragma unroll
    for (int i = 0; i < 2; ++i) {
        int flat = i * 256 + t;
        int n = flat >> 3, ck = (flat & 7) << 3;
        ushort8 hv, lv;
        #pragma unroll
        for (int j = 0; j < 8; ++j) {
            float v = tile[ck + j][n];
            float hf;
            hv[j] = bfhi(v, &hf);
            lv[j] = bflo(v, hf);
        }
        size_t o = (size_t)(nt + n) * ldt + kt + ck;
        *(ushort8*)&WTh[o] = hv;
        *(ushort8*)&WTl[o] = lv;
    }
}

// ------------------------------ RoPE (q,k in-place) ------------------------
__global__ __launch_bounds__(256) void rope_k(float* __restrict__ qkv)
{
    const int row = (blockIdx.x << 2) + (threadIdx.x >> 6);
    const int s = row & 511;
    const int d = threadIdx.x & 63;
    const int j = d & 31;

    float invf = powf(10000.0f, -(float)j * (1.0f / 32.0f));
    float ang = (float)s * invf;
    float sn, cs;
    sincosf(ang, &sn, &cs);

    float* rowp = qkv + (size_t)row * QKVC;
    const int pair = (d < 32) ? d + 32 : d - 32;
    const float sgn = (d < 32) ? -1.f : 1.f;

    float kv = rowp[512 + d];
    float kp = rowp[512 + pair];
    float qv[NHEAD], qp[NHEAD];
    #pragma unroll
    for (int h = 0; h < NHEAD; ++h) {
        qv[h] = rowp[h * 64 + d];
        qp[h] = rowp[h * 64 + pair];
    }
    rowp[512 + d] = kv * cs + sgn * kp * sn;
    #pragma unroll
    for (int h = 0; h < NHEAD; ++h)
        rowp[h * 64 + d] = (qv[h] * cs + sgn * qp[h] * sn) * 0.125f;
}

// -------------- MFMA GEMM (split bf16): C_fp32 = A @ B^T -------------------
// A: hi/lo [M][K] bf16, BT: hi/lo [N][K] bf16. grid: (N/64, M/128), 4 waves.
__global__ __launch_bounds__(256, 2) void mfma_gemm_k(
    const unsigned short* __restrict__ Ah, const unsigned short* __restrict__ Al,
    int lda,
    const unsigned short* __restrict__ BTh, const unsigned short* __restrict__ BTl,
    int ldb, int K,
    float* __restrict__ C, int ldc)
{
    __shared__ unsigned short sAh[128 * 64];
    __shared__ unsigned short sAl[128 * 64];
    __shared__ unsigned short sBh[64 * 64];
    __shared__ unsigned short sBl[64 * 64];

    const int n0 = blockIdx.x << 6;
    const int m0 = blockIdx.y << 7;
    const int t  = threadIdx.x;
    const int l  = t & 63;
    const int w  = t >> 6;
    const int wm = w >> 1, wn = w & 1;
    const int lr = l & 15, lg = l >> 4;

    f32x4 acc[4][2];
    #pragma unroll
    for (int fm = 0; fm < 4; ++fm)
        #pragma unroll
        for (int fn = 0; fn < 2; ++fn) acc[fm][fn] = (f32x4)0.f;

    for (int k0 = 0; k0 < K; k0 += 64) {
        __syncthreads();
        #pragma unroll
        for (int i = 0; i < 4; ++i) {
            int flat = i * 256 + t;
            int m = flat >> 3, c = flat & 7;
            size_t gidx = (size_t)(m0 + m) * lda + k0 + c * 8;
            int lidx = m * 64 + ((c ^ (m & 7)) << 3);
            *(ushort8*)&sAh[lidx] = *(const ushort8*)&Ah[gidx];
            *(ushort8*)&sAl[lidx] = *(const ushort8*)&Al[gidx];
        }
        #pragma unroll
        for (int i = 0; i < 2; ++i) {
            int flat = i * 256 + t;          // 0..511: 64 rows x 8 chunks
            int n = flat >> 3, c = flat & 7;
            size_t gidx = (size_t)(n0 + n) * ldb + k0 + c * 8;
            int lidx = n * 64 + ((c ^ (n & 7)) << 3);
            *(ushort8*)&sBh[lidx] = *(const ushort8*)&BTh[gidx];
            *(ushort8*)&sBl[lidx] = *(const ushort8*)&BTl[gidx];
        }
        __syncthreads();

        #pragma unroll
        for (int kk = 0; kk < 2; ++kk) {
            const int c = kk * 4 + lg;
            bf16x8 afh[4], afl[4];
            #pragma unroll
            for (int fm = 0; fm < 4; ++fm) {
                int m = wm * 64 + fm * 16 + lr;
                int lidx = m * 64 + ((c ^ (m & 7)) << 3);
                afh[fm] = *(bf16x8*)&sAh[lidx];
                afl[fm] = *(bf16x8*)&sAl[lidx];
            }
            bf16x8 bh[2], bl[2];
            #pragma unroll
            for (int fn = 0; fn < 2; ++fn) {
                int n = wn * 32 + fn * 16 + lr;
                int lidx = n * 64 + ((c ^ (n & 7)) << 3);
                bh[fn] = *(bf16x8*)&sBh[lidx];
                bl[fn] = *(bf16x8*)&sBl[lidx];
            }
            #pragma unroll
            for (int fm = 0; fm < 4; ++fm)
                #pragma unroll
                for (int fn = 0; fn < 2; ++fn) {
                    acc[fm][fn] = __builtin_amdgcn_mfma_f32_16x16x32_bf16(afh[fm], bh[fn], acc[fm][fn], 0, 0, 0);
                    acc[fm][fn] = __builtin_amdgcn_mfma_f32_16x16x32_bf16(afh[fm], bl[fn], acc[fm][fn], 0, 0, 0);
                    acc[fm][fn] = __builtin_amdgcn_mfma_f32_16x16x32_bf16(afl[fm], bh[fn], acc[fm][fn], 0, 0, 0);
                }
        }
    }

    #pragma unroll
    for (int fm = 0; fm < 4; ++fm)
        #pragma unroll
        for (int fn = 0; fn < 2; ++fn) {
            const int n = n0 + wn * 32 + fn * 16 + lr;
            #pragma unroll
            for (int r = 0; r < 4; ++r) {
                const int m = m0 + wm * 64 + fm * 16 + lg * 4 + r;
                C[(size_t)m * ldc + n] = acc[fm][fn][r];
            }
        }
}

// -------- MFMA out GEMM: x += ctx@Wa + h@Wff (split bf16, 2-pass K) --------
__global__ __launch_bounds__(256, 2) void mfma_out_k(
    const unsigned short* __restrict__ A1h, const unsigned short* __restrict__ A1l,
    const unsigned short* __restrict__ B1h, const unsigned short* __restrict__ B1l,
    const unsigned short* __restrict__ A2h, const unsigned short* __restrict__ A2l,
    const unsigned short* __restrict__ B2h, const unsigned short* __restrict__ B2l,
    float* __restrict__ X)
{
    __shared__ unsigned short sAh[128 * 64];
    __shared__ unsigned short sAl[128 * 64];
    __shared__ unsigned short sBh[64 * 64];
    __shared__ unsigned short sBl[64 * 64];

    const int n0 = blockIdx.x << 6;
    const int m0 = blockIdx.y << 7;
    const int t  = threadIdx.x;
    const int l  = t & 63;
    const int w  = t >> 6;
    const int wm = w >> 1, wn = w & 1;
    const int lr = l & 15, lg = l >> 4;

    f32x4 acc[4][2];
    #pragma unroll
    for (int fm = 0; fm < 4; ++fm)
        #pragma unroll
        for (int fn = 0; fn < 2; ++fn) acc[fm][fn] = (f32x4)0.f;

    #pragma unroll
    for (int pass = 0; pass < 2; ++pass) {
        const unsigned short* pAh = pass ? A2h : A1h;
        const unsigned short* pAl = pass ? A2l : A1l;
        const unsigned short* pBh = pass ? B2h : B1h;
        const unsigned short* pBl = pass ? B2l : B1l;
        const int lda = pass ? FFIN : DIMM;
        const int KK  = pass ? FFIN : DIMM;

        for (int k0 = 0; k0 < KK; k0 += 64) {
            __syncthreads();
            #pragma unroll
            for (int i = 0; i < 4; ++i) {
                int flat = i * 256 + t;
                int m = flat >> 3, c = flat & 7;
                size_t gidx = (size_t)(m0 + m) * lda + k0 + c * 8;
                int lidx = m * 64 + ((c ^ (m & 7)) << 3);
                *(ushort8*)&sAh[lidx] = *(const ushort8*)&pAh[gidx];
                *(ushort8*)&sAl[lidx] = *(const ushort8*)&pAl[gidx];
            }
            #pragma unroll
            for (int i = 0; i < 2; ++i) {
                int flat = i * 256 + t;      // 0..511: 64 rows x 8 chunks
                int n = flat >> 3, c = flat & 7;
                size_t gidx = (size_t)(n0 + n) * KK + k0 + c * 8;
                int lidx = n * 64 + ((c ^ (n & 7)) << 3);
                *(ushort8*)&sBh[lidx] = *(const ushort8*)&pBh[gidx];
                *(ushort8*)&sBl[lidx] = *(const ushort8*)&pBl[gidx];
            }
            __syncthreads();

            #pragma unroll
            for (int kk = 0; kk < 2; ++kk) {
                const int c = kk * 4 + lg;
                bf16x8 afh[4], afl[4];
                #pragma unroll
                for (int fm = 0; fm < 4; ++fm) {
                    int m = wm * 64 + fm * 16 + lr;
                    int lidx = m * 64 + ((c ^ (m & 7)) << 3);
                    afh[fm] = *(bf16x8*)&sAh[lidx];
                    afl[fm] = *(bf16x8*)&sAl[lidx];
                }
                bf16x8 bh[2], bl[2];
                #pragma unroll
                for (int fn = 0; fn < 2; ++fn) {
                    int n = wn * 32 + fn * 16 + lr;
                    int lidx = n * 64 + ((c ^ (n & 7)) << 3);
                    bh[fn] = *(bf16x8*)&sBh[lidx];
                    bl[fn] = *(bf16x8*)&sBl[lidx];
                }
                #pragma unroll
                for (int fm = 0; fm < 4; ++fm)
                    #pragma unroll
                    for (int fn = 0; fn < 2; ++fn) {
                        acc[fm][fn] = __builtin_amdgcn_mfma_f32_16x16x32_bf16(afh[fm], bh[fn], acc[fm][fn], 0, 0, 0);
                        acc[fm][fn] = __builtin_amdgcn_mfma_f32_16x16x32_bf16(afh[fm], bl[fn], acc[fm][fn], 0, 0, 0);
                        acc[fm][fn] = __builtin_amdgcn_mfma_f32_16x16x32_bf16(afl[fm], bh[fn], acc[fm][fn], 0, 0, 0);
                    }
            }
        }
    }

    #pragma unroll
    for (int fm = 0; fm < 4; ++fm)
        #pragma unroll
        for (int fn = 0; fn < 2; ++fn) {
            const int n = n0 + wn * 32 + fn * 16 + lr;
            #pragma unroll
            for (int r = 0; r < 4; ++r) {
                const int m = m0 + wm * 64 + fm * 16 + lg * 4 + r;
                X[(size_t)m * DIMM + n] += acc[fm][fn][r];
            }
        }
}

// ------------- MFMA dual GEMM: h = silu(A@Wg) * (A@Wx) -> bf16 hi/lo -------
__global__ __launch_bounds__(256, 2) void mfma_dual_silu_k(
    const unsigned short* __restrict__ Ah, const unsigned short* __restrict__ Al,
    const unsigned short* __restrict__ WTh, const unsigned short* __restrict__ WTl,
    unsigned short* __restrict__ Hh, unsigned short* __restrict__ Hl)
{
    __shared__ unsigned short sAh[128 * 64];
    __shared__ unsigned short sAl[128 * 64];
    __shared__ unsigned short sBxh[64 * 64];
    __shared__ unsigned short sBxl[64 * 64];
    __shared__ unsigned short sBgh[64 * 64];
    __shared__ unsigned short sBgl[64 * 64];

    const int n0 = blockIdx.x << 6;
    const int m0 = blockIdx.y << 7;
    const int t  = threadIdx.x;
    const int l  = t & 63;
    const int w  = t >> 6;
    const int wm = w >> 1, wn = w & 1;
    const int lr = l & 15, lg = l >> 4;

    f32x4 accX[4][2], accG[4][2];
    #pragma unroll
    for (int fm = 0; fm < 4; ++fm)
        #pragma unroll
        for (int fn = 0; fn < 2; ++fn) {
            accX[fm][fn] = (f32x4)0.f;
            accG[fm][fn] = (f32x4)0.f;
        }

    for (int k0 = 0; k0 < DIMM; k0 += 64) {
        __syncthreads();
        #pragma unroll
        for (int i = 0; i < 4; ++i) {
            int flat = i * 256 + t;
            int m = flat >> 3, c = flat & 7;
            size_t gidx = (size_t)(m0 + m) * DIMM + k0 + c * 8;
            int lidx = m * 64 + ((c ^ (m & 7)) << 3);
            *(ushort8*)&sAh[lidx] = *(const ushort8*)&Ah[gidx];
            *(ushort8*)&sAl[lidx] = *(const ushort8*)&Al[gidx];
        }
        #pragma unroll
        for (int i = 0; i < 2; ++i) {
            int flat = i * 256 + t;
            int n = flat >> 3, c = flat & 7;
            size_t gx = (size_t)(n0 + n) * DIMM + k0 + c * 8;
            size_t gg = (size_t)(2048 + n0 + n) * DIMM + k0 + c * 8;
            int lidx = n * 64 + ((c ^ (n & 7)) << 3);
            *(ushort8*)&sBxh[lidx] = *(const ushort8*)&WTh[gx];
            *(ushort8*)&sBxl[lidx] = *(const ushort8*)&WTl[gx];
            *(ushort8*)&sBgh[lidx] = *(const ushort8*)&WTh[gg];
            *(ushort8*)&sBgl[lidx] = *(const ushort8*)&WTl[gg];
        }
        __syncthreads();

        #pragma unroll
        for (int kk = 0; kk < 2; ++kk) {
            const int c = kk * 4 + lg;
            bf16x8 afh[4], afl[4];
            #pragma unroll
            for (int fm = 0; fm < 4; ++fm) {
                int m = wm * 64 + fm * 16 + lr;
                int lidx = m * 64 + ((c ^ (m & 7)) << 3);
                afh[fm] = *(bf16x8*)&sAh[lidx];
                afl[fm] = *(bf16x8*)&sAl[lidx];
            }
            bf16x8 bxh[2], bxl[2], bgh[2], bgl[2];
            #pragma unroll
            for (int fn = 0; fn < 2; ++fn) {
                int n = wn * 32 + fn * 16 + lr;
                int lidx = n * 64 + ((c ^ (n & 7)) << 3);
                bxh[fn] = *(bf16x8*)&sBxh[lidx];
                bxl[fn] = *(bf16x8*)&sBxl[lidx];
                bgh[fn] = *(bf16x8*)&sBgh[lidx];
                bgl[fn] = *(bf16x8*)&sBgl[lidx];
            }
            #pragma unroll
            for (int fm = 0; fm < 4; ++fm)
                #pragma unroll
                for (int fn = 0; fn < 2; ++fn) {
                    accX[fm][fn] = __builtin_amdgcn_mfma_f32_16x16x32_bf16(afh[fm], bxh[fn], accX[fm][fn], 0, 0, 0);
                    accX[fm][fn] = __builtin_amdgcn_mfma_f32_16x16x32_bf16(afh[fm], bxl[fn], accX[fm][fn], 0, 0, 0);
                    accX[fm][fn] = __builtin_amdgcn_mfma_f32_16x16x32_bf16(afl[fm], bxh[fn], accX[fm][fn], 0, 0, 0);
                    accG[fm][fn] = __builtin_amdgcn_mfma_f32_16x16x32_bf16(afh[fm], bgh[fn], accG[fm][fn], 0, 0, 0);
                    accG[fm][fn] = __builtin_amdgcn_mfma_f32_16x16x32_bf16(afh[fm], bgl[fn], accG[fm][fn], 0, 0, 0);
                    accG[fm][fn] = __builtin_amdgcn_mfma_f32_16x16x32_bf16(afl[fm], bgh[fn], accG[fm][fn], 0, 0, 0);
                }
        }
    }

    #pragma unroll
    for (int fm = 0; fm < 4; ++fm)
        #pragma unroll
        for (int fn = 0; fn < 2; ++fn) {
            const int n = n0 + wn * 32 + fn * 16 + lr;
            #pragma unroll
            for (int r = 0; r < 4; ++r) {
                const int m = m0 + wm * 64 + fm * 16 + lg * 4 + r;
                float gv = accG[fm][fn][r];
                float xv = accX[fm][fn][r];
                float sig = 1.0f / (1.0f + expf(-gv));
                float hv = gv * sig * xv;
                float hf;
                size_t o = (size_t)m * FFIN + n;
                Hh[o] = bfhi(hv, &hf);
                Hl[o] = bflo(hv, hf);
            }
        }
}

// ------------------------------ attention (flash, microtiled) --------------
__global__ __launch_bounds__(256) void attn_k(const float* __restrict__ qkv,
                                              unsigned short* __restrict__ ctxh,
                                              unsigned short* __restrict__ ctxl,
                                              const int* __restrict__ vl)
{
    const int rc = blockIdx.x;
    const int h  = blockIdx.y;
    const int b  = blockIdx.z;
    const int i0 = rc << 6;
    const int t  = threadIdx.x;
    const int tx = t & 15, ty = t >> 4;

    __shared__ float QT[64][68];
    __shared__ float KT[64][68];
    __shared__ float Vs[64][68];
    __shared__ float PT[64][68];

    const int VL = vl[b];

    for (int idx = t; idx < 1024; idx += 256) {
        const int r = idx >> 4, c4 = (idx & 15) << 2;
        float4 qv = *(const float4*)&qkv[((size_t)((b << 9) + i0 + r)) * QKVC + (h << 6) + c4];
        QT[c4 + 0][r] = qv.x; QT[c4 + 1][r] = qv.y;
        QT[c4 + 2][r] = qv.z; QT[c4 + 3][r] = qv.w;
    }

    float m[4], l[4], o[4][4];
    #pragma unroll
    for (int r = 0; r < 4; ++r) {
        m[r] = -3.0e38f; l[r] = 0.f;
        #pragma unroll
        for (int c = 0; c < 4; ++c) o[r][c] = 0.f;
    }

    for (int j0 = 0; j0 < SEQ; j0 += 64) {
        __syncthreads();
        for (int idx = t; idx < 1024; idx += 256) {
            const int r = idx >> 4, c4 = (idx & 15) << 2;
            const float* src = &qkv[((size_t)((b << 9) + j0 + r)) * QKVC + 512 + c4];
            float4 kv = *(const float4*)src;
            KT[c4 + 0][r] = kv.x; KT[c4 + 1][r] = kv.y;
            KT[c4 + 2][r] = kv.z; KT[c4 + 3][r] = kv.w;
            *(float4*)&Vs[r][c4] = *(const float4*)(src + 64);
        }
        __syncthreads();

        float s[4][4];
        #pragma unroll
        for (int r = 0; r < 4; ++r)
            #pragma unroll
            for (int c = 0; c < 4; ++c) s[r][c] = 0.f;
        #pragma unroll 16
        for (int k = 0; k < 64; ++k) {
            float4 a4 = *(const float4*)&QT[k][ty << 2];
            float4 b4 = *(const float4*)&KT[k][tx << 2];
            float av[4] = {a4.x, a4.y, a4.z, a4.w};
            float bv[4] = {b4.x, b4.y, b4.z, b4.w};
            #pragma unroll
            for (int r = 0; r < 4; ++r)
                #pragma unroll
                for (int c = 0; c < 4; ++c)
                    s[r][c] = fmaf(av[r], bv[c], s[r][c]);
        }

        const int jb = j0 + (tx << 2);
        #pragma unroll
        for (int c = 0; c < 4; ++c) {
            if (jb + c >= VL) {
                #pragma unroll
                for (int r = 0; r < 4; ++r) s[r][c] = -3.0e38f;
            }
        }

        #pragma unroll
        for (int r = 0; r < 4; ++r) {
            float tmax = fmaxf(fmaxf(s[r][0], s[r][1]), fmaxf(s[r][2], s[r][3]));
            #pragma unroll
            for (int off = 8; off; off >>= 1) tmax = fmaxf(tmax, __shfl_xor(tmax, off));
            float nm = fmaxf(m[r], tmax);
            float scl = expf(m[r] - nm);
            float ps = 0.f;
            #pragma unroll
            for (int c = 0; c < 4; ++c) {
                float e = expf(s[r][c] - nm);
                s[r][c] = e;
                ps += e;
            }
            l[r] = l[r] * scl + ps;
            #pragma unroll
            for (int c = 0; c < 4; ++c) o[r][c] *= scl;
            m[r] = nm;
        }

        #pragma unroll
        for (int c = 0; c < 4; ++c) {
            float4 pv = make_float4(s[0][c], s[1][c], s[2][c], s[3][c]);
            *(float4*)&PT[(tx << 2) + c][ty << 2] = pv;
        }
        __syncthreads();

        #pragma unroll 16
        for (int k = 0; k < 64; ++k) {
            float4 a4 = *(const float4*)&PT[k][ty << 2];
            float4 b4 = *(const float4*)&Vs[k][tx << 2];
            float av[4] = {a4.x, a4.y, a4.z, a4.w};
            float bv[4] = {b4.x, b4.y, b4.z, b4.w};
            #pragma unroll
            for (int r = 0; r < 4; ++r)
                #pragma unroll
                for (int c = 0; c < 4; ++c)
                    o[r][c] = fmaf(av[r], bv[c], o[r][c]);
        }
    }

    #pragma unroll
    for (int r = 0; r < 4; ++r) {
        float lt = l[r];
        #pragma unroll
        for (int off = 8; off; off >>= 1) lt += __shfl_xor(lt, off);
        float inv = 1.0f / lt;
        const int row = (b << 9) + i0 + (ty << 2) + r;
        const size_t base = (size_t)row * DIMM + (h << 6) + (tx << 2);
        #pragma unroll
        for (int c = 0; c < 4; ++c) {
            float v = o[r][c] * inv;
            float hf;
            ctxh[base + c] = bfhi(v, &hf);
            ctxl[base + c] = bflo(v, hf);
        }
    }
}

// ------------------------------ pool ---------------------------------------
__global__ __launch_bounds__(512) void pool_part_k(const float* __restrict__ x,
                                                   float* __restrict__ psum,
                                                   float* __restrict__ pmax)
{
    const int seg = blockIdx.x;
    const int b   = blockIdx.y;
    const int d   = threadIdx.x;
    const float* xb = x + ((size_t)(b << 9) + (seg << 6)) * DIMM;
    float s = 0.f, m = -3.0e38f;
    for (int i = 0; i < 64; ++i) {
        float v = xb[(size_t)i * DIMM + d];
        s += v;
        m = fmaxf(m, v);
    }
    psum[((size_t)b * 8 + seg) * DIMM + d] = s;
    pmax[((size_t)b * 8 + seg) * DIMM + d] = m;
}

__global__ __launch_bounds__(512) void pool_comb_k(const float* __restrict__ psum,
                                                   const float* __restrict__ pmax,
                                                   float* __restrict__ out)
{
    const int b = blockIdx.x;
    const int d = threadIdx.x;
    float s = 0.f, m = -3.0e38f;
    #pragma unroll
    for (int seg = 0; seg < 8; ++seg) {
        s += psum[((size_t)b * 8 + seg) * DIMM + d];
        m = fmaxf(m, pmax[((size_t)b * 8 + seg) * DIMM + d]);
    }
    out[b * 1024 + d] = s * (1.0f / 512.0f);
    out[b * 1024 + 512 + d] = m;
}

// ---------------------------------------------------------------------------
extern "C" void kernel_launch(void* const* d_in, const int* in_sizes, int n_in,
                              void* d_out, int out_size, void* d_ws, size_t ws_size,
                              hipStream_t stream)
{
    const int*   page_in        = (const int*)d_in[0];
    const int*   item_in        = (const int*)d_in[1];
    const int*   item_meta_in   = (const int*)d_in[2];
    const int*   vl_in          = (const int*)d_in[3];
    const int*   page_meta_in   = (const int*)d_in[4];
    const float* pwide          = (const float*)d_in[5];
    const float* iwide          = (const float*)d_in[6];
    const float* page_emb       = (const float*)d_in[7];
    const float* page_meta_emb  = (const float*)d_in[8];
    const float* item_emb       = (const float*)d_in[9];
    const float* item_meta_emb  = (const float*)d_in[10];
    const float* item_pre_emb   = (const float*)d_in[11];
    const float* pW             = (const float*)d_in[12];
    const float* pb             = (const float*)d_in[13];
    const float* pg             = (const float*)d_in[14];
    const float* pbeta          = (const float*)d_in[15];
    const float* iW             = (const float*)d_in[16];
    const float* ib             = (const float*)d_in[17];
    const float* ig             = (const float*)d_in[18];
    const float* ibeta          = (const float*)d_in[19];
    const float* norm_g         = (const float*)d_in[20];
    const float* fused_W        = (const float*)d_in[21];
    const float* attn_out_W     = (const float*)d_in[22];
    const float* ff_out_W       = (const float*)d_in[23];
    float* out = (float*)d_out;

    float* ws  = (float*)d_ws;
    float* x    = ws;                                      // 16384*512 f32
    unsigned short* xnh = (unsigned short*)(x + (size_t)NROWS * DIMM);
    unsigned short* xnl = xnh + (size_t)NROWS * DIMM;
    float* qkv = (float*)(xnl + (size_t)NROWS * DIMM);     // 16384*640 f32
    unsigned short* hh   = (unsigned short*)(qkv + (size_t)NROWS * QKVC);
    unsigned short* hl   = hh + (size_t)NROWS * FFIN;
    unsigned short* ctxh = hl + (size_t)NROWS * FFIN;
    unsigned short* ctxl = ctxh + (size_t)NROWS * DIMM;
    float* psum = (float*)(ctxl + (size_t)NROWS * DIMM);
    float* pmax = psum + (size_t)NBATCH * 8 * DIMM;
    unsigned short* WqTh = (unsigned short*)(pmax + (size_t)NBATCH * 8 * DIMM);
    unsigned short* WqTl = WqTh + (size_t)QKVC * DIMM;     // 640x512
    unsigned short* WdTh = WqTl + (size_t)QKVC * DIMM;     // 4096x512
    unsigned short* WdTl = WdTh + (size_t)4096 * DIMM;
    unsigned short* WaTh = WdTl + (size_t)4096 * DIMM;     // 512x512
    unsigned short* WaTl = WaTh + (size_t)DIMM * DIMM;
    unsigned short* WfTh = WaTl + (size_t)DIMM * DIMM;     // 512x2048
    unsigned short* WfTl = WfTh + (size_t)DIMM * FFIN;

    build_x_k<<<NROWS, 512, 0, stream>>>(
        page_in, item_in, item_meta_in, page_meta_in, pwide, iwide,
        page_emb, page_meta_emb, item_emb, item_meta_emb, item_pre_emb,
        pW, pb, pg, pbeta, iW, ib, ig, ibeta, x);

    for (int l = 0; l < 4; ++l) {
        const float* Wf  = fused_W    + (size_t)l * DIMM * NFUSED;
        const float* Wa  = attn_out_W + (size_t)l * DIMM * DIMM;
        const float* Wff = ff_out_W   + (size_t)l * FFIN * DIMM;
        const float* g   = norm_g     + (size_t)l * DIMM;

        ln_k<<<NROWS, 256, 0, stream>>>(x, xnh, xnl, g);

        // weight transpose+split: qkv cols [0,640), ff cols [640,4736), Wa, Wff
        wconv_k<<<dim3(QKVC / 64, DIMM / 64), 256, 0, stream>>>(
            Wf, NFUSED, 0, WqTh, WqTl, DIMM);
        wconv_k<<<dim3(4096 / 64, DIMM / 64), 256, 0, stream>>>(
            Wf, NFUSED, 640, WdTh, WdTl, DIMM);
        wconv_k<<<dim3(DIMM / 64, DIMM / 64), 256, 0, stream>>>(
            Wa, DIMM, 0, WaTh, WaTl, DIMM);
        wconv_k<<<dim3(DIMM / 64, FFIN / 64), 256, 0, stream>>>(
            Wff, DIMM, 0, WfTh, WfTl, FFIN);

        mfma_gemm_k<<<dim3(QKVC / 64, NROWS / 128), 256, 0, stream>>>(
            xnh, xnl, DIMM, WqTh, WqTl, DIMM, DIMM, qkv, QKVC);

        rope_k<<<NROWS / 4, 256, 0, stream>>>(qkv);

        mfma_dual_silu_k<<<dim3(FFIN / 64, NROWS / 128), 256, 0, stream>>>(
            xnh, xnl, WdTh, WdTl, hh, hl);

        attn_k<<<dim3(SEQ / 64, NHEAD, NBATCH), 256, 0, stream>>>(qkv, ctxh, ctxl, vl_in);

        mfma_out_k<<<dim3(DIMM / 64, NROWS / 128), 256, 0, stream>>>(
            ctxh, ctxl, WaTh, WaTl, hh, hl, WfTh, WfTl, x);
    }

    pool_part_k<<<dim3(8, NBATCH), 512, 0, stream>>>(x, psum, pmax);
    pool_comb_k<<<NBATCH, 512, 0, stream>>>(psum, pmax, out);
}

// Round 6
// 2345.951 us; speedup vs baseline: 3.9314x; 1.4033x over previous
//
#include <hip/hip_runtime.h>
#include <math.h>

// ---------------------------------------------------------------------------
// ParallelTransformerAEP forward.
// R5: attention on MFMA (split-bf16 QK^T, bf16 P/V for PV, swizzled LDS,
//     Q in registers, online softmax). rope emits bf16 q/k hi/lo + vT.
// ---------------------------------------------------------------------------

namespace {
constexpr int SEQ    = 512;
constexpr int NBATCH = 32;
constexpr int DIMM   = 512;
constexpr int NHEAD  = 8;
constexpr int FFIN   = 2048;
constexpr int NFUSED = 4736;
constexpr int NROWS  = NBATCH * SEQ;   // 16384
constexpr int QKVC   = 640;            // 512 q + 64 k + 64 v
}

typedef __bf16 bf16x8 __attribute__((ext_vector_type(8)));
typedef float f32x4 __attribute__((ext_vector_type(4)));
typedef unsigned short ushort8 __attribute__((ext_vector_type(8)));

static __device__ __forceinline__ unsigned short bfhi(float v, float* hf) {
    __bf16 h = (__bf16)v;
    *hf = (float)h;
    return __builtin_bit_cast(unsigned short, h);
}
static __device__ __forceinline__ unsigned short bflo(float v, float hf) {
    __bf16 l = (__bf16)(v - hf);
    return __builtin_bit_cast(unsigned short, l);
}

// ------------------------- build x = page * item ---------------------------
__global__ __launch_bounds__(512) void build_x_k(
    const int* __restrict__ page_in, const int* __restrict__ item_in,
    const int* __restrict__ item_meta_in, const int* __restrict__ page_meta_in,
    const float* __restrict__ pwide, const float* __restrict__ iwide,
    const float* __restrict__ page_emb, const float* __restrict__ page_meta_emb,
    const float* __restrict__ item_emb, const float* __restrict__ item_meta_emb,
    const float* __restrict__ item_pre_emb,
    const float* __restrict__ pW, const float* __restrict__ pb,
    const float* __restrict__ pg, const float* __restrict__ pbeta,
    const float* __restrict__ iW, const float* __restrict__ ib,
    const float* __restrict__ ig, const float* __restrict__ ibeta,
    float* __restrict__ x)
{
    const int row = blockIdx.x;
    const int b = row >> 9;
    const int s = row & 511;
    const int d = threadIdx.x;
    const float BNS = 0.9999950000374997f;   // 1/sqrt(1+1e-5)

    float pv, iv;
    if (d < 384) {
        pv = page_emb[(size_t)page_in[row] * 384 + d];
    } else if (d < 448) {
        pv = page_meta_emb[(size_t)page_meta_in[row] * 64 + (d - 384)];
    } else {
        const int dd = d - 448;
        float acc = pb[dd];
        #pragma unroll
        for (int c = 0; c < 8; ++c) {
            float w  = pwide[((size_t)b * 8 + c) * SEQ + s];
            float wn = w * BNS * pg[c] + pbeta[c];
            acc += wn * pW[c * 64 + dd];
        }
        pv = acc > 0.f ? acc : 0.2f * acc;
    }
    if (d < 320) {
        iv = item_emb[(size_t)item_in[row] * 320 + d];
    } else if (d < 384) {
        iv = item_meta_emb[(size_t)item_meta_in[row] * 64 + (d - 320)];
    } else if (d < 448) {
        iv = item_pre_emb[(size_t)item_in[row] * 64 + (d - 384)];
    } else {
        const int dd = d - 448;
        float acc = ib[dd];
        #pragma unroll
        for (int c = 0; c < 8; ++c) {
            float w  = iwide[((size_t)b * 8 + c) * SEQ + s];
            float wn = w * BNS * ig[c] + ibeta[c];
            acc += wn * iW[c * 64 + dd];
        }
        iv = acc > 0.f ? acc : 0.2f * acc;
    }
    x[(size_t)row * DIMM + d] = pv * iv;
}

// ------------------------------ LayerNorm -> bf16 hi/lo --------------------
__global__ __launch_bounds__(256) void ln_k(const float* __restrict__ x,
                                            unsigned short* __restrict__ xnh,
                                            unsigned short* __restrict__ xnl,
                                            const float* __restrict__ g)
{
    const int row = blockIdx.x;
    const int t = threadIdx.x;
    const float* xr = x + (size_t)row * DIMM;
    __shared__ float red[4];

    float v0 = xr[t], v1 = xr[t + 256];
    float s = v0 + v1;
    #pragma unroll
    for (int o = 32; o; o >>= 1) s += __shfl_xor(s, o);
    if ((t & 63) == 0) red[t >> 6] = s;
    __syncthreads();
    float mu = (red[0] + red[1] + red[2] + red[3]) * (1.0f / 512.0f);
    __syncthreads();

    float d0 = v0 - mu, d1 = v1 - mu;
    float vs = d0 * d0 + d1 * d1;
    #pragma unroll
    for (int o = 32; o; o >>= 1) vs += __shfl_xor(vs, o);
    if ((t & 63) == 0) red[t >> 6] = vs;
    __syncthreads();
    float var = (red[0] + red[1] + red[2] + red[3]) * (1.0f / 512.0f);
    float r = 1.0f / sqrtf(var + 1e-5f);

    const size_t base = (size_t)row * DIMM;
    float o0 = d0 * r * g[t];
    float o1 = d1 * r * g[t + 256];
    float h0f, h1f;
    xnh[base + t]       = bfhi(o0, &h0f);
    xnh[base + t + 256] = bfhi(o1, &h1f);
    xnl[base + t]       = bflo(o0, h0f);
    xnl[base + t + 256] = bflo(o1, h1f);
}

// ---------------- weight transpose + split: WT[n][k] = W[k][col0+n] --------
__global__ __launch_bounds__(256) void wconv_k(const float* __restrict__ W, int ldw,
                                               int col0,
                                               unsigned short* __restrict__ WTh,
                                               unsigned short* __restrict__ WTl,
                                               int ldt)
{
    __shared__ float tile[64][65];
    const int nt = blockIdx.x << 6;
    const int kt = blockIdx.y << 6;
    const int t  = threadIdx.x;

    #pragma unroll
    for (int i = 0; i < 16; ++i) {
        int flat = i * 256 + t;
        int r = flat >> 6, c = flat & 63;
        tile[r][c] = W[(size_t)(kt + r) * ldw + col0 + nt + c];
    }
    __syncthreads();
    #pragma unroll
    for (int i = 0; i < 2; ++i) {
        int flat = i * 256 + t;
        int n = flat >> 3, ck = (flat & 7) << 3;
        ushort8 hv, lv;
        #pragma unroll
        for (int j = 0; j < 8; ++j) {
            float v = tile[ck + j][n];
            float hf;
            hv[j] = bfhi(v, &hf);
            lv[j] = bflo(v, hf);
        }
        size_t o = (size_t)(nt + n) * ldt + kt + ck;
        *(ushort8*)&WTh[o] = hv;
        *(ushort8*)&WTl[o] = lv;
    }
}

// ----------- RoPE + split: qkv fp32 -> qh/ql [b,h,s,64], kh/kl, vT ---------
__global__ __launch_bounds__(256) void rope_split_k(
    const float* __restrict__ qkv,
    unsigned short* __restrict__ qh, unsigned short* __restrict__ ql,
    unsigned short* __restrict__ kh, unsigned short* __restrict__ kl,
    unsigned short* __restrict__ vT)
{
    const int row = (blockIdx.x << 2) + (threadIdx.x >> 6);
    const int b = row >> 9;
    const int s = row & 511;
    const int d = threadIdx.x & 63;
    const int j = d & 31;

    float invf = powf(10000.0f, -(float)j * (1.0f / 32.0f));
    float ang = (float)s * invf;
    float sn, cs;
    sincosf(ang, &sn, &cs);

    const float* rowp = qkv + (size_t)row * QKVC;
    const int pair = (d < 32) ? d + 32 : d - 32;
    const float sgn = (d < 32) ? -1.f : 1.f;
    float hf;

    // k (rope, no scale)
    float kv = rowp[512 + d];
    float kp = rowp[512 + pair];
    float kr = kv * cs + sgn * kp * sn;
    size_t kidx = ((size_t)b * 512 + s) * 64 + d;
    kh[kidx] = bfhi(kr, &hf);
    kl[kidx] = bflo(kr, hf);

    // v transposed, single bf16
    float vv = rowp[576 + d];
    vT[((size_t)b * 64 + d) * 512 + s] = bfhi(vv, &hf);

    // q per head (rope + 1/sqrt(d) scale)
    #pragma unroll
    for (int h = 0; h < NHEAD; ++h) {
        float qv = rowp[h * 64 + d];
        float qp = rowp[h * 64 + pair];
        float qr = (qv * cs + sgn * qp * sn) * 0.125f;
        size_t qidx = (((size_t)b * 8 + h) * 512 + s) * 64 + d;
        qh[qidx] = bfhi(qr, &hf);
        ql[qidx] = bflo(qr, hf);
    }
}

// -------------- MFMA GEMM (split bf16): C_fp32 = A @ B^T -------------------
__global__ __launch_bounds__(256, 2) void mfma_gemm_k(
    const unsigned short* __restrict__ Ah, const unsigned short* __restrict__ Al,
    int lda,
    const unsigned short* __restrict__ BTh, const unsigned short* __restrict__ BTl,
    int ldb, int K,
    float* __restrict__ C, int ldc)
{
    __shared__ unsigned short sAh[128 * 64];
    __shared__ unsigned short sAl[128 * 64];
    __shared__ unsigned short sBh[64 * 64];
    __shared__ unsigned short sBl[64 * 64];

    const int n0 = blockIdx.x << 6;
    const int m0 = blockIdx.y << 7;
    const int t  = threadIdx.x;
    const int l  = t & 63;
    const int w  = t >> 6;
    const int wm = w >> 1, wn = w & 1;
    const int lr = l & 15, lg = l >> 4;

    f32x4 acc[4][2];
    #pragma unroll
    for (int fm = 0; fm < 4; ++fm)
        #pragma unroll
        for (int fn = 0; fn < 2; ++fn) acc[fm][fn] = (f32x4)0.f;

    for (int k0 = 0; k0 < K; k0 += 64) {
        __syncthreads();
        #pragma unroll
        for (int i = 0; i < 4; ++i) {
            int flat = i * 256 + t;
            int m = flat >> 3, c = flat & 7;
            size_t gidx = (size_t)(m0 + m) * lda + k0 + c * 8;
            int lidx = m * 64 + ((c ^ (m & 7)) << 3);
            *(ushort8*)&sAh[lidx] = *(const ushort8*)&Ah[gidx];
            *(ushort8*)&sAl[lidx] = *(const ushort8*)&Al[gidx];
        }
        #pragma unroll
        for (int i = 0; i < 2; ++i) {
            int flat = i * 256 + t;
            int n = flat >> 3, c = flat & 7;
            size_t gidx = (size_t)(n0 + n) * ldb + k0 + c * 8;
            int lidx = n * 64 + ((c ^ (n & 7)) << 3);
            *(ushort8*)&sBh[lidx] = *(const ushort8*)&BTh[gidx];
            *(ushort8*)&sBl[lidx] = *(const ushort8*)&BTl[gidx];
        }
        __syncthreads();

        #pragma unroll
        for (int kk = 0; kk < 2; ++kk) {
            const int c = kk * 4 + lg;
            bf16x8 afh[4], afl[4];
            #pragma unroll
            for (int fm = 0; fm < 4; ++fm) {
                int m = wm * 64 + fm * 16 + lr;
                int lidx = m * 64 + ((c ^ (m & 7)) << 3);
                afh[fm] = *(bf16x8*)&sAh[lidx];
                afl[fm] = *(bf16x8*)&sAl[lidx];
            }
            bf16x8 bh[2], bl[2];
            #pragma unroll
            for (int fn = 0; fn < 2; ++fn) {
                int n = wn * 32 + fn * 16 + lr;
                int lidx = n * 64 + ((c ^ (n & 7)) << 3);
                bh[fn] = *(bf16x8*)&sBh[lidx];
                bl[fn] = *(bf16x8*)&sBl[lidx];
            }
            #pragma unroll
            for (int fm = 0; fm < 4; ++fm)
                #pragma unroll
                for (int fn = 0; fn < 2; ++fn) {
                    acc[fm][fn] = __builtin_amdgcn_mfma_f32_16x16x32_bf16(afh[fm], bh[fn], acc[fm][fn], 0, 0, 0);
                    acc[fm][fn] = __builtin_amdgcn_mfma_f32_16x16x32_bf16(afh[fm], bl[fn], acc[fm][fn], 0, 0, 0);
                    acc[fm][fn] = __builtin_amdgcn_mfma_f32_16x16x32_bf16(afl[fm], bh[fn], acc[fm][fn], 0, 0, 0);
                }
        }
    }

    #pragma unroll
    for (int fm = 0; fm < 4; ++fm)
        #pragma unroll
        for (int fn = 0; fn < 2; ++fn) {
            const int n = n0 + wn * 32 + fn * 16 + lr;
            #pragma unroll
            for (int r = 0; r < 4; ++r) {
                const int m = m0 + wm * 64 + fm * 16 + lg * 4 + r;
                C[(size_t)m * ldc + n] = acc[fm][fn][r];
            }
        }
}

// -------- MFMA out GEMM: x += ctx@Wa + h@Wff (split bf16, 2-pass K) --------
__global__ __launch_bounds__(256, 2) void mfma_out_k(
    const unsigned short* __restrict__ A1h, const unsigned short* __restrict__ A1l,
    const unsigned short* __restrict__ B1h, const unsigned short* __restrict__ B1l,
    const unsigned short* __restrict__ A2h, const unsigned short* __restrict__ A2l,
    const unsigned short* __restrict__ B2h, const unsigned short* __restrict__ B2l,
    float* __restrict__ X)
{
    __shared__ unsigned short sAh[128 * 64];
    __shared__ unsigned short sAl[128 * 64];
    __shared__ unsigned short sBh[64 * 64];
    __shared__ unsigned short sBl[64 * 64];

    const int n0 = blockIdx.x << 6;
    const int m0 = blockIdx.y << 7;
    const int t  = threadIdx.x;
    const int l  = t & 63;
    const int w  = t >> 6;
    const int wm = w >> 1, wn = w & 1;
    const int lr = l & 15, lg = l >> 4;

    f32x4 acc[4][2];
    #pragma unroll
    for (int fm = 0; fm < 4; ++fm)
        #pragma unroll
        for (int fn = 0; fn < 2; ++fn) acc[fm][fn] = (f32x4)0.f;

    #pragma unroll
    for (int pass = 0; pass < 2; ++pass) {
        const unsigned short* pAh = pass ? A2h : A1h;
        const unsigned short* pAl = pass ? A2l : A1l;
        const unsigned short* pBh = pass ? B2h : B1h;
        const unsigned short* pBl = pass ? B2l : B1l;
        const int lda = pass ? FFIN : DIMM;
        const int KK  = pass ? FFIN : DIMM;

        for (int k0 = 0; k0 < KK; k0 += 64) {
            __syncthreads();
            #pragma unroll
            for (int i = 0; i < 4; ++i) {
                int flat = i * 256 + t;
                int m = flat >> 3, c = flat & 7;
                size_t gidx = (size_t)(m0 + m) * lda + k0 + c * 8;
                int lidx = m * 64 + ((c ^ (m & 7)) << 3);
                *(ushort8*)&sAh[lidx] = *(const ushort8*)&pAh[gidx];
                *(ushort8*)&sAl[lidx] = *(const ushort8*)&pAl[gidx];
            }
            #pragma unroll
            for (int i = 0; i < 2; ++i) {
                int flat = i * 256 + t;
                int n = flat >> 3, c = flat & 7;
                size_t gidx = (size_t)(n0 + n) * KK + k0 + c * 8;
                int lidx = n * 64 + ((c ^ (n & 7)) << 3);
                *(ushort8*)&sBh[lidx] = *(const ushort8*)&pBh[gidx];
                *(ushort8*)&sBl[lidx] = *(const ushort8*)&pBl[gidx];
            }
            __syncthreads();

            #pragma unroll
            for (int kk = 0; kk < 2; ++kk) {
                const int c = kk * 4 + lg;
                bf16x8 afh[4], afl[4];
                #pragma unroll
                for (int fm = 0; fm < 4; ++fm) {
                    int m = wm * 64 + fm * 16 + lr;
                    int lidx = m * 64 + ((c ^ (m & 7)) << 3);
                    afh[fm] = *(bf16x8*)&sAh[lidx];
                    afl[fm] = *(bf16x8*)&sAl[lidx];
                }
                bf16x8 bh[2], bl[2];
                #pragma unroll
                for (int fn = 0; fn < 2; ++fn) {
                    int n = wn * 32 + fn * 16 + lr;
                    int lidx = n * 64 + ((c ^ (n & 7)) << 3);
                    bh[fn] = *(bf16x8*)&sBh[lidx];
                    bl[fn] = *(bf16x8*)&sBl[lidx];
                }
                #pragma unroll
                for (int fm = 0; fm < 4; ++fm)
                    #pragma unroll
                    for (int fn = 0; fn < 2; ++fn) {
                        acc[fm][fn] = __builtin_amdgcn_mfma_f32_16x16x32_bf16(afh[fm], bh[fn], acc[fm][fn], 0, 0, 0);
                        acc[fm][fn] = __builtin_amdgcn_mfma_f32_16x16x32_bf16(afh[fm], bl[fn], acc[fm][fn], 0, 0, 0);
                        acc[fm][fn] = __builtin_amdgcn_mfma_f32_16x16x32_bf16(afl[fm], bh[fn], acc[fm][fn], 0, 0, 0);
                    }
            }
        }
    }

    #pragma unroll
    for (int fm = 0; fm < 4; ++fm)
        #pragma unroll
        for (int fn = 0; fn < 2; ++fn) {
            const int n = n0 + wn * 32 + fn * 16 + lr;
            #pragma unroll
            for (int r = 0; r < 4; ++r) {
                const int m = m0 + wm * 64 + fm * 16 + lg * 4 + r;
                X[(size_t)m * DIMM + n] += acc[fm][fn][r];
            }
        }
}

// ------------- MFMA dual GEMM: h = silu(A@Wg) * (A@Wx) -> bf16 hi/lo -------
__global__ __launch_bounds__(256, 2) void mfma_dual_silu_k(
    const unsigned short* __restrict__ Ah, const unsigned short* __restrict__ Al,
    const unsigned short* __restrict__ WTh, const unsigned short* __restrict__ WTl,
    unsigned short* __restrict__ Hh, unsigned short* __restrict__ Hl)
{
    __shared__ unsigned short sAh[128 * 64];
    __shared__ unsigned short sAl[128 * 64];
    __shared__ unsigned short sBxh[64 * 64];
    __shared__ unsigned short sBxl[64 * 64];
    __shared__ unsigned short sBgh[64 * 64];
    __shared__ unsigned short sBgl[64 * 64];

    const int n0 = blockIdx.x << 6;
    const int m0 = blockIdx.y << 7;
    const int t  = threadIdx.x;
    const int l  = t & 63;
    const int w  = t >> 6;
    const int wm = w >> 1, wn = w & 1;
    const int lr = l & 15, lg = l >> 4;

    f32x4 accX[4][2], accG[4][2];
    #pragma unroll
    for (int fm = 0; fm < 4; ++fm)
        #pragma unroll
        for (int fn = 0; fn < 2; ++fn) {
            accX[fm][fn] = (f32x4)0.f;
            accG[fm][fn] = (f32x4)0.f;
        }

    for (int k0 = 0; k0 < DIMM; k0 += 64) {
        __syncthreads();
        #pragma unroll
        for (int i = 0; i < 4; ++i) {
            int flat = i * 256 + t;
            int m = flat >> 3, c = flat & 7;
            size_t gidx = (size_t)(m0 + m) * DIMM + k0 + c * 8;
            int lidx = m * 64 + ((c ^ (m & 7)) << 3);
            *(ushort8*)&sAh[lidx] = *(const ushort8*)&Ah[gidx];
            *(ushort8*)&sAl[lidx] = *(const ushort8*)&Al[gidx];
        }
        #pragma unroll
        for (int i = 0; i < 2; ++i) {
            int flat = i * 256 + t;
            int n = flat >> 3, c = flat & 7;
            size_t gx = (size_t)(n0 + n) * DIMM + k0 + c * 8;
            size_t gg = (size_t)(2048 + n0 + n) * DIMM + k0 + c * 8;
            int lidx = n * 64 + ((c ^ (n & 7)) << 3);
            *(ushort8*)&sBxh[lidx] = *(const ushort8*)&WTh[gx];
            *(ushort8*)&sBxl[lidx] = *(const ushort8*)&WTl[gx];
            *(ushort8*)&sBgh[lidx] = *(const ushort8*)&WTh[gg];
            *(ushort8*)&sBgl[lidx] = *(const ushort8*)&WTl[gg];
        }
        __syncthreads();

        #pragma unroll
        for (int kk = 0; kk < 2; ++kk) {
            const int c = kk * 4 + lg;
            bf16x8 afh[4], afl[4];
            #pragma unroll
            for (int fm = 0; fm < 4; ++fm) {
                int m = wm * 64 + fm * 16 + lr;
                int lidx = m * 64 + ((c ^ (m & 7)) << 3);
                afh[fm] = *(bf16x8*)&sAh[lidx];
                afl[fm] = *(bf16x8*)&sAl[lidx];
            }
            bf16x8 bxh[2], bxl[2], bgh[2], bgl[2];
            #pragma unroll
            for (int fn = 0; fn < 2; ++fn) {
                int n = wn * 32 + fn * 16 + lr;
                int lidx = n * 64 + ((c ^ (n & 7)) << 3);
                bxh[fn] = *(bf16x8*)&sBxh[lidx];
                bxl[fn] = *(bf16x8*)&sBxl[lidx];
                bgh[fn] = *(bf16x8*)&sBgh[lidx];
                bgl[fn] = *(bf16x8*)&sBgl[lidx];
            }
            #pragma unroll
            for (int fm = 0; fm < 4; ++fm)
                #pragma unroll
                for (int fn = 0; fn < 2; ++fn) {
                    accX[fm][fn] = __builtin_amdgcn_mfma_f32_16x16x32_bf16(afh[fm], bxh[fn], accX[fm][fn], 0, 0, 0);
                    accX[fm][fn] = __builtin_amdgcn_mfma_f32_16x16x32_bf16(afh[fm], bxl[fn], accX[fm][fn], 0, 0, 0);
                    accX[fm][fn] = __builtin_amdgcn_mfma_f32_16x16x32_bf16(afl[fm], bxh[fn], accX[fm][fn], 0, 0, 0);
                    accG[fm][fn] = __builtin_amdgcn_mfma_f32_16x16x32_bf16(afh[fm], bgh[fn], accG[fm][fn], 0, 0, 0);
                    accG[fm][fn] = __builtin_amdgcn_mfma_f32_16x16x32_bf16(afh[fm], bgl[fn], accG[fm][fn], 0, 0, 0);
                    accG[fm][fn] = __builtin_amdgcn_mfma_f32_16x16x32_bf16(afl[fm], bgh[fn], accG[fm][fn], 0, 0, 0);
                }
        }
    }

    #pragma unroll
    for (int fm = 0; fm < 4; ++fm)
        #pragma unroll
        for (int fn = 0; fn < 2; ++fn) {
            const int n = n0 + wn * 32 + fn * 16 + lr;
            #pragma unroll
            for (int r = 0; r < 4; ++r) {
                const int m = m0 + wm * 64 + fm * 16 + lg * 4 + r;
                float gv = accG[fm][fn][r];
                float xv = accX[fm][fn][r];
                float sig = 1.0f / (1.0f + expf(-gv));
                float hv = gv * sig * xv;
                float hf;
                size_t o = (size_t)m * FFIN + n;
                Hh[o] = bfhi(hv, &hf);
                Hl[o] = bflo(hv, hf);
            }
        }
}

// ------------------- attention: MFMA flash (per b,h,64 q-rows) -------------
// grid (8, 8, 32), block 256 = 4 waves; wave w owns q-rows [w*16, w*16+16).
__global__ __launch_bounds__(256) void attn_mfma_k(
    const unsigned short* __restrict__ qh, const unsigned short* __restrict__ ql,
    const unsigned short* __restrict__ kh, const unsigned short* __restrict__ kl,
    const unsigned short* __restrict__ vT,
    unsigned short* __restrict__ ctxh, unsigned short* __restrict__ ctxl,
    const int* __restrict__ vl)
{
    __shared__ unsigned short sKh[64 * 64];
    __shared__ unsigned short sKl[64 * 64];
    __shared__ unsigned short sVT[64 * 64];
    __shared__ unsigned short sP[64 * 64];

    const int i0 = blockIdx.x << 6;
    const int h  = blockIdx.y;
    const int b  = blockIdx.z;
    const int t  = threadIdx.x;
    const int l  = t & 63;
    const int w  = t >> 6;
    const int lr = l & 15, lg = l >> 4;
    const int VL = vl[b];

    // Q fragments (hi/lo), held in registers all kernel
    bf16x8 qfh[2], qfl[2];
    {
        size_t base = (((size_t)(b * 8 + h) * 512) + i0 + w * 16 + lr) * 64 + lg * 8;
        qfh[0] = *(const bf16x8*)&qh[base];
        qfh[1] = *(const bf16x8*)&qh[base + 32];
        qfl[0] = *(const bf16x8*)&ql[base];
        qfl[1] = *(const bf16x8*)&ql[base + 32];
    }

    float mrow[4], lrow[4];
    f32x4 oacc[4];
    #pragma unroll
    for (int r = 0; r < 4; ++r) { mrow[r] = -3.0e38f; lrow[r] = 0.f; }
    #pragma unroll
    for (int nb = 0; nb < 4; ++nb) oacc[nb] = (f32x4)0.f;

    for (int j0 = 0; j0 < SEQ; j0 += 64) {
        __syncthreads();
        // stage K hi/lo + V^T (64 rows x 64 bf16, XOR-swizzled)
        #pragma unroll
        for (int i = 0; i < 2; ++i) {
            int flat = i * 256 + t;          // 0..511
            int m = flat >> 3, c = flat & 7;
            int lidx = m * 64 + ((c ^ (m & 7)) << 3);
            size_t kg = ((size_t)b * 512 + j0 + m) * 64 + c * 8;
            *(ushort8*)&sKh[lidx] = *(const ushort8*)&kh[kg];
            *(ushort8*)&sKl[lidx] = *(const ushort8*)&kl[kg];
            size_t vg = ((size_t)b * 64 + m) * 512 + j0 + c * 8;
            *(ushort8*)&sVT[lidx] = *(const ushort8*)&vT[vg];
        }
        __syncthreads();

        // S = Q K^T  (split-bf16: hh + hl + lh)
        f32x4 accS[4];
        #pragma unroll
        for (int nb = 0; nb < 4; ++nb) accS[nb] = (f32x4)0.f;
        #pragma unroll
        for (int ks = 0; ks < 2; ++ks) {
            const int c = ks * 4 + lg;
            #pragma unroll
            for (int nb = 0; nb < 4; ++nb) {
                int n = nb * 16 + lr;
                int lidx = n * 64 + ((c ^ (n & 7)) << 3);
                bf16x8 kfh = *(bf16x8*)&sKh[lidx];
                bf16x8 kfl = *(bf16x8*)&sKl[lidx];
                accS[nb] = __builtin_amdgcn_mfma_f32_16x16x32_bf16(qfh[ks], kfh, accS[nb], 0, 0, 0);
                accS[nb] = __builtin_amdgcn_mfma_f32_16x16x32_bf16(qfh[ks], kfl, accS[nb], 0, 0, 0);
                accS[nb] = __builtin_amdgcn_mfma_f32_16x16x32_bf16(qfl[ks], kfh, accS[nb], 0, 0, 0);
            }
        }

        // mask: key col = j0 + nb*16 + lr
        #pragma unroll
        for (int nb = 0; nb < 4; ++nb) {
            if (j0 + nb * 16 + lr >= VL) {
                #pragma unroll
                for (int r = 0; r < 4; ++r) accS[nb][r] = -3.0e38f;
            }
        }

        // online softmax (rows lg*4+r; reduce across 16 lr-lanes)
        #pragma unroll
        for (int r = 0; r < 4; ++r) {
            float rm = fmaxf(fmaxf(accS[0][r], accS[1][r]), fmaxf(accS[2][r], accS[3][r]));
            #pragma unroll
            for (int off = 8; off; off >>= 1) rm = fmaxf(rm, __shfl_xor(rm, off));
            float nm = fmaxf(mrow[r], rm);
            float scl = expf(mrow[r] - nm);
            mrow[r] = nm;
            float ps = 0.f;
            #pragma unroll
            for (int nb = 0; nb < 4; ++nb) {
                float p = expf(accS[nb][r] - nm);
                accS[nb][r] = p;
                ps += p;
            }
            lrow[r] = lrow[r] * scl + ps;
            #pragma unroll
            for (int nb = 0; nb < 4; ++nb) oacc[nb][r] *= scl;
        }

        // store P (bf16) to swizzled sP: row q = w*16+lg*4+r, col = nb*16+lr
        #pragma unroll
        for (int nb = 0; nb < 4; ++nb) {
            int cc = nb * 2 + (lr >> 3);
            #pragma unroll
            for (int r = 0; r < 4; ++r) {
                int q = w * 16 + lg * 4 + r;
                int lidx = q * 64 + ((cc ^ (q & 7)) << 3) + (lr & 7);
                float hf2;
                sP[lidx] = bfhi(accS[nb][r], &hf2);
            }
        }

        // PV: oacc[nb] += P(16x64) @ V(64x(nb*16..))  — intra-wave LDS dep
        #pragma unroll
        for (int ks = 0; ks < 2; ++ks) {
            const int c = ks * 4 + lg;
            int qrow = w * 16 + lr;
            int plidx = qrow * 64 + ((c ^ (qrow & 7)) << 3);
            bf16x8 pf = *(bf16x8*)&sP[plidx];
            #pragma unroll
            for (int nb = 0; nb < 4; ++nb) {
                int n = nb * 16 + lr;
                int lidx = n * 64 + ((c ^ (n & 7)) << 3);
                bf16x8 vf = *(bf16x8*)&sVT[lidx];
                oacc[nb] = __builtin_amdgcn_mfma_f32_16x16x32_bf16(pf, vf, oacc[nb], 0, 0, 0);
            }
        }
    }

    // epilogue: reduce l across lr-lanes, normalize, write ctx hi/lo
    #pragma unroll
    for (int r = 0; r < 4; ++r) {
        float lt = lrow[r];
        #pragma unroll
        for (int off = 8; off; off >>= 1) lt += __shfl_xor(lt, off);
        float inv = 1.0f / lt;
        const int row = (b << 9) + i0 + w * 16 + lg * 4 + r;
        const size_t base = (size_t)row * DIMM + h * 64;
        #pragma unroll
        for (int nb = 0; nb < 4; ++nb) {
            float v = oacc[nb][r] * inv;
            float hf;
            ctxh[base + nb * 16 + lr] = bfhi(v, &hf);
            ctxl[base + nb * 16 + lr] = bflo(v, hf);
        }
    }
}

// ------------------------------ pool ---------------------------------------
__global__ __launch_bounds__(512) void pool_part_k(const float* __restrict__ x,
                                                   float* __restrict__ psum,
                                                   float* __restrict__ pmax)
{
    const int seg = blockIdx.x;
    const int b   = blockIdx.y;
    const int d   = threadIdx.x;
    const float* xb = x + ((size_t)(b << 9) + (seg << 6)) * DIMM;
    float s = 0.f, m = -3.0e38f;
    for (int i = 0; i < 64; ++i) {
        float v = xb[(size_t)i * DIMM + d];
        s += v;
        m = fmaxf(m, v);
    }
    psum[((size_t)b * 8 + seg) * DIMM + d] = s;
    pmax[((size_t)b * 8 + seg) * DIMM + d] = m;
}

__global__ __launch_bounds__(512) void pool_comb_k(const float* __restrict__ psum,
                                                   const float* __restrict__ pmax,
                                                   float* __restrict__ out)
{
    const int b = blockIdx.x;
    const int d = threadIdx.x;
    float s = 0.f, m = -3.0e38f;
    #pragma unroll
    for (int seg = 0; seg < 8; ++seg) {
        s += psum[((size_t)b * 8 + seg) * DIMM + d];
        m = fmaxf(m, pmax[((size_t)b * 8 + seg) * DIMM + d]);
    }
    out[b * 1024 + d] = s * (1.0f / 512.0f);
    out[b * 1024 + 512 + d] = m;
}

// ---------------------------------------------------------------------------
extern "C" void kernel_launch(void* const* d_in, const int* in_sizes, int n_in,
                              void* d_out, int out_size, void* d_ws, size_t ws_size,
                              hipStream_t stream)
{
    const int*   page_in        = (const int*)d_in[0];
    const int*   item_in        = (const int*)d_in[1];
    const int*   item_meta_in   = (const int*)d_in[2];
    const int*   vl_in          = (const int*)d_in[3];
    const int*   page_meta_in   = (const int*)d_in[4];
    const float* pwide          = (const float*)d_in[5];
    const float* iwide          = (const float*)d_in[6];
    const float* page_emb       = (const float*)d_in[7];
    const float* page_meta_emb  = (const float*)d_in[8];
    const float* item_emb       = (const float*)d_in[9];
    const float* item_meta_emb  = (const float*)d_in[10];
    const float* item_pre_emb   = (const float*)d_in[11];
    const float* pW             = (const float*)d_in[12];
    const float* pb             = (const float*)d_in[13];
    const float* pg             = (const float*)d_in[14];
    const float* pbeta          = (const float*)d_in[15];
    const float* iW             = (const float*)d_in[16];
    const float* ib             = (const float*)d_in[17];
    const float* ig             = (const float*)d_in[18];
    const float* ibeta          = (const float*)d_in[19];
    const float* norm_g         = (const float*)d_in[20];
    const float* fused_W        = (const float*)d_in[21];
    const float* attn_out_W     = (const float*)d_in[22];
    const float* ff_out_W       = (const float*)d_in[23];
    float* out = (float*)d_out;

    float* ws  = (float*)d_ws;
    float* x    = ws;                                      // 16384*512 f32
    unsigned short* xnh = (unsigned short*)(x + (size_t)NROWS * DIMM);
    unsigned short* xnl = xnh + (size_t)NROWS * DIMM;
    float* qkv = (float*)(xnl + (size_t)NROWS * DIMM);     // 16384*640 f32
    unsigned short* hh   = (unsigned short*)(qkv + (size_t)NROWS * QKVC);
    unsigned short* hl   = hh + (size_t)NROWS * FFIN;
    unsigned short* ctxh = hl + (size_t)NROWS * FFIN;
    unsigned short* ctxl = ctxh + (size_t)NROWS * DIMM;
    float* psum = (float*)(ctxl + (size_t)NROWS * DIMM);
    float* pmax = psum + (size_t)NBATCH * 8 * DIMM;
    unsigned short* WqTh = (unsigned short*)(pmax + (size_t)NBATCH * 8 * DIMM);
    unsigned short* WqTl = WqTh + (size_t)QKVC * DIMM;     // 640x512
    unsigned short* WdTh = WqTl + (size_t)QKVC * DIMM;     // 4096x512
    unsigned short* WdTl = WdTh + (size_t)4096 * DIMM;
    unsigned short* WaTh = WdTl + (size_t)4096 * DIMM;     // 512x512
    unsigned short* WaTl = WaTh + (size_t)DIMM * DIMM;
    unsigned short* WfTh = WaTl + (size_t)DIMM * DIMM;     // 512x2048
    unsigned short* WfTl = WfTh + (size_t)DIMM * FFIN;
    unsigned short* khb  = WfTl + (size_t)DIMM * FFIN;     // 32x512x64
    unsigned short* klb  = khb + (size_t)NBATCH * SEQ * 64;
    unsigned short* vTb  = klb + (size_t)NBATCH * SEQ * 64; // 32x64x512
    // q hi/lo alias xnh/xnl (xn dead after dual-silu; rope runs after it)
    unsigned short* qhb = xnh;
    unsigned short* qlb = xnl;

    build_x_k<<<NROWS, 512, 0, stream>>>(
        page_in, item_in, item_meta_in, page_meta_in, pwide, iwide,
        page_emb, page_meta_emb, item_emb, item_meta_emb, item_pre_emb,
        pW, pb, pg, pbeta, iW, ib, ig, ibeta, x);

    for (int l = 0; l < 4; ++l) {
        const float* Wf  = fused_W    + (size_t)l * DIMM * NFUSED;
        const float* Wa  = attn_out_W + (size_t)l * DIMM * DIMM;
        const float* Wff = ff_out_W   + (size_t)l * FFIN * DIMM;
        const float* g   = norm_g     + (size_t)l * DIMM;

        ln_k<<<NROWS, 256, 0, stream>>>(x, xnh, xnl, g);

        wconv_k<<<dim3(QKVC / 64, DIMM / 64), 256, 0, stream>>>(
            Wf, NFUSED, 0, WqTh, WqTl, DIMM);
        wconv_k<<<dim3(4096 / 64, DIMM / 64), 256, 0, stream>>>(
            Wf, NFUSED, 640, WdTh, WdTl, DIMM);
        wconv_k<<<dim3(DIMM / 64, DIMM / 64), 256, 0, stream>>>(
            Wa, DIMM, 0, WaTh, WaTl, DIMM);
        wconv_k<<<dim3(DIMM / 64, FFIN / 64), 256, 0, stream>>>(
            Wff, DIMM, 0, WfTh, WfTl, FFIN);

        mfma_gemm_k<<<dim3(QKVC / 64, NROWS / 128), 256, 0, stream>>>(
            xnh, xnl, DIMM, WqTh, WqTl, DIMM, DIMM, qkv, QKVC);

        mfma_dual_silu_k<<<dim3(FFIN / 64, NROWS / 128), 256, 0, stream>>>(
            xnh, xnl, WdTh, WdTl, hh, hl);

        // xn dead now; rope writes q hi/lo into its space
        rope_split_k<<<NROWS / 4, 256, 0, stream>>>(qkv, qhb, qlb, khb, klb, vTb);

        attn_mfma_k<<<dim3(SEQ / 64, NHEAD, NBATCH), 256, 0, stream>>>(
            qhb, qlb, khb, klb, vTb, ctxh, ctxl, vl_in);

        mfma_out_k<<<dim3(DIMM / 64, NROWS / 128), 256, 0, stream>>>(
            ctxh, ctxl, WaTh, WaTl, hh, hl, WfTh, WfTl, x);
    }

    pool_part_k<<<dim3(8, NBATCH), 512, 0, stream>>>(x, psum, pmax);
    pool_comb_k<<<NBATCH, 512, 0, stream>>>(psum, pmax, out);
}

// Round 7
// 1723.677 us; speedup vs baseline: 5.3507x; 1.3610x over previous
//
#include <hip/hip_runtime.h>
#include <math.h>

// ---------------------------------------------------------------------------
// ParallelTransformerAEP forward.
// R6: precision-tiered MFMA — qkv GEMM keeps 3-product split; dual/out GEMMs
//     use single-bf16 activations x split weights (2 products); h/ctx single
//     bf16; rope uses precomputed trig table.
// ---------------------------------------------------------------------------

namespace {
constexpr int SEQ    = 512;
constexpr int NBATCH = 32;
constexpr int DIMM   = 512;
constexpr int NHEAD  = 8;
constexpr int FFIN   = 2048;
constexpr int NFUSED = 4736;
constexpr int NROWS  = NBATCH * SEQ;   // 16384
constexpr int QKVC   = 640;            // 512 q + 64 k + 64 v
}

typedef __bf16 bf16x8 __attribute__((ext_vector_type(8)));
typedef float f32x4 __attribute__((ext_vector_type(4)));
typedef unsigned short ushort8 __attribute__((ext_vector_type(8)));

static __device__ __forceinline__ unsigned short bfhi(float v, float* hf) {
    __bf16 h = (__bf16)v;
    *hf = (float)h;
    return __builtin_bit_cast(unsigned short, h);
}
static __device__ __forceinline__ unsigned short bflo(float v, float hf) {
    __bf16 l = (__bf16)(v - hf);
    return __builtin_bit_cast(unsigned short, l);
}

// ------------------------- build x = page * item ---------------------------
__global__ __launch_bounds__(512) void build_x_k(
    const int* __restrict__ page_in, const int* __restrict__ item_in,
    const int* __restrict__ item_meta_in, const int* __restrict__ page_meta_in,
    const float* __restrict__ pwide, const float* __restrict__ iwide,
    const float* __restrict__ page_emb, const float* __restrict__ page_meta_emb,
    const float* __restrict__ item_emb, const float* __restrict__ item_meta_emb,
    const float* __restrict__ item_pre_emb,
    const float* __restrict__ pW, const float* __restrict__ pb,
    const float* __restrict__ pg, const float* __restrict__ pbeta,
    const float* __restrict__ iW, const float* __restrict__ ib,
    const float* __restrict__ ig, const float* __restrict__ ibeta,
    float* __restrict__ x)
{
    const int row = blockIdx.x;
    const int b = row >> 9;
    const int s = row & 511;
    const int d = threadIdx.x;
    const float BNS = 0.9999950000374997f;   // 1/sqrt(1+1e-5)

    float pv, iv;
    if (d < 384) {
        pv = page_emb[(size_t)page_in[row] * 384 + d];
    } else if (d < 448) {
        pv = page_meta_emb[(size_t)page_meta_in[row] * 64 + (d - 384)];
    } else {
        const int dd = d - 448;
        float acc = pb[dd];
        #pragma unroll
        for (int c = 0; c < 8; ++c) {
            float w  = pwide[((size_t)b * 8 + c) * SEQ + s];
            float wn = w * BNS * pg[c] + pbeta[c];
            acc += wn * pW[c * 64 + dd];
        }
        pv = acc > 0.f ? acc : 0.2f * acc;
    }
    if (d < 320) {
        iv = item_emb[(size_t)item_in[row] * 320 + d];
    } else if (d < 384) {
        iv = item_meta_emb[(size_t)item_meta_in[row] * 64 + (d - 320)];
    } else if (d < 448) {
        iv = item_pre_emb[(size_t)item_in[row] * 64 + (d - 384)];
    } else {
        const int dd = d - 448;
        float acc = ib[dd];
        #pragma unroll
        for (int c = 0; c < 8; ++c) {
            float w  = iwide[((size_t)b * 8 + c) * SEQ + s];
            float wn = w * BNS * ig[c] + ibeta[c];
            acc += wn * iW[c * 64 + dd];
        }
        iv = acc > 0.f ? acc : 0.2f * acc;
    }
    x[(size_t)row * DIMM + d] = pv * iv;
}

// ------------------------------ trig table ---------------------------------
__global__ __launch_bounds__(256) void trig_k(float* __restrict__ cost,
                                              float* __restrict__ sint)
{
    const int idx = blockIdx.x * 256 + threadIdx.x;   // 16384 = 512 x 32
    const int s = idx >> 5, j = idx & 31;
    float invf = powf(10000.0f, -(float)j * (1.0f / 32.0f));
    float ang = (float)s * invf;
    float sn, cs;
    sincosf(ang, &sn, &cs);
    cost[idx] = cs;
    sint[idx] = sn;
}

// ------------------------------ LayerNorm -> bf16 hi/lo --------------------
__global__ __launch_bounds__(256) void ln_k(const float* __restrict__ x,
                                            unsigned short* __restrict__ xnh,
                                            unsigned short* __restrict__ xnl,
                                            const float* __restrict__ g)
{
    const int row = blockIdx.x;
    const int t = threadIdx.x;
    const float* xr = x + (size_t)row * DIMM;
    __shared__ float red[4];

    float v0 = xr[t], v1 = xr[t + 256];
    float s = v0 + v1;
    #pragma unroll
    for (int o = 32; o; o >>= 1) s += __shfl_xor(s, o);
    if ((t & 63) == 0) red[t >> 6] = s;
    __syncthreads();
    float mu = (red[0] + red[1] + red[2] + red[3]) * (1.0f / 512.0f);
    __syncthreads();

    float d0 = v0 - mu, d1 = v1 - mu;
    float vs = d0 * d0 + d1 * d1;
    #pragma unroll
    for (int o = 32; o; o >>= 1) vs += __shfl_xor(vs, o);
    if ((t & 63) == 0) red[t >> 6] = vs;
    __syncthreads();
    float var = (red[0] + red[1] + red[2] + red[3]) * (1.0f / 512.0f);
    float r = 1.0f / sqrtf(var + 1e-5f);

    const size_t base = (size_t)row * DIMM;
    float o0 = d0 * r * g[t];
    float o1 = d1 * r * g[t + 256];
    float h0f, h1f;
    xnh[base + t]       = bfhi(o0, &h0f);
    xnh[base + t + 256] = bfhi(o1, &h1f);
    xnl[base + t]       = bflo(o0, h0f);
    xnl[base + t + 256] = bflo(o1, h1f);
}

// ---------------- weight transpose + split: WT[n][k] = W[k][col0+n] --------
__global__ __launch_bounds__(256) void wconv_k(const float* __restrict__ W, int ldw,
                                               int col0,
                                               unsigned short* __restrict__ WTh,
                                               unsigned short* __restrict__ WTl,
                                               int ldt)
{
    __shared__ float tile[64][65];
    const int nt = blockIdx.x << 6;
    const int kt = blockIdx.y << 6;
    const int t  = threadIdx.x;

    #pragma unroll
    for (int i = 0; i < 16; ++i) {
        int flat = i * 256 + t;
        int r = flat >> 6, c = flat & 63;
        tile[r][c] = W[(size_t)(kt + r) * ldw + col0 + nt + c];
    }
    __syncthreads();
    #pragma unroll
    for (int i = 0; i < 2; ++i) {
        int flat = i * 256 + t;
        int n = flat >> 3, ck = (flat & 7) << 3;
        ushort8 hv, lv;
        #pragma unroll
        for (int j = 0; j < 8; ++j) {
            float v = tile[ck + j][n];
            float hf;
            hv[j] = bfhi(v, &hf);
            lv[j] = bflo(v, hf);
        }
        size_t o = (size_t)(nt + n) * ldt + kt + ck;
        *(ushort8*)&WTh[o] = hv;
        *(ushort8*)&WTl[o] = lv;
    }
}

// ----------- RoPE + split: qkv fp32 -> qh/ql [b,h,s,64], kh/kl, vT ---------
__global__ __launch_bounds__(256) void rope_split_k(
    const float* __restrict__ qkv,
    const float* __restrict__ cost, const float* __restrict__ sint,
    unsigned short* __restrict__ qh, unsigned short* __restrict__ ql,
    unsigned short* __restrict__ kh, unsigned short* __restrict__ kl,
    unsigned short* __restrict__ vT)
{
    const int row = (blockIdx.x << 2) + (threadIdx.x >> 6);
    const int b = row >> 9;
    const int s = row & 511;
    const int d = threadIdx.x & 63;
    const int j = d & 31;

    const float cs = cost[s * 32 + j];
    const float sn = sint[s * 32 + j];

    const float* rowp = qkv + (size_t)row * QKVC;
    const int pair = (d < 32) ? d + 32 : d - 32;
    const float sgn = (d < 32) ? -1.f : 1.f;
    float hf;

    // k (rope, no scale)
    float kv = rowp[512 + d];
    float kp = rowp[512 + pair];
    float kr = kv * cs + sgn * kp * sn;
    size_t kidx = ((size_t)b * 512 + s) * 64 + d;
    kh[kidx] = bfhi(kr, &hf);
    kl[kidx] = bflo(kr, hf);

    // v transposed, single bf16
    float vv = rowp[576 + d];
    vT[((size_t)b * 64 + d) * 512 + s] = bfhi(vv, &hf);

    // q per head (rope + 1/sqrt(d) scale)
    #pragma unroll
    for (int h = 0; h < NHEAD; ++h) {
        float qv = rowp[h * 64 + d];
        float qp = rowp[h * 64 + pair];
        float qr = (qv * cs + sgn * qp * sn) * 0.125f;
        size_t qidx = (((size_t)b * 8 + h) * 512 + s) * 64 + d;
        qh[qidx] = bfhi(qr, &hf);
        ql[qidx] = bflo(qr, hf);
    }
}

// -------------- MFMA GEMM (split bf16, 3-product): C_fp32 = A @ B^T --------
__global__ __launch_bounds__(256, 2) void mfma_gemm_k(
    const unsigned short* __restrict__ Ah, const unsigned short* __restrict__ Al,
    int lda,
    const unsigned short* __restrict__ BTh, const unsigned short* __restrict__ BTl,
    int ldb, int K,
    float* __restrict__ C, int ldc)
{
    __shared__ unsigned short sAh[128 * 64];
    __shared__ unsigned short sAl[128 * 64];
    __shared__ unsigned short sBh[64 * 64];
    __shared__ unsigned short sBl[64 * 64];

    const int n0 = blockIdx.x << 6;
    const int m0 = blockIdx.y << 7;
    const int t  = threadIdx.x;
    const int l  = t & 63;
    const int w  = t >> 6;
    const int wm = w >> 1, wn = w & 1;
    const int lr = l & 15, lg = l >> 4;

    f32x4 acc[4][2];
    #pragma unroll
    for (int fm = 0; fm < 4; ++fm)
        #pragma unroll
        for (int fn = 0; fn < 2; ++fn) acc[fm][fn] = (f32x4)0.f;

    for (int k0 = 0; k0 < K; k0 += 64) {
        __syncthreads();
        #pragma unroll
        for (int i = 0; i < 4; ++i) {
            int flat = i * 256 + t;
            int m = flat >> 3, c = flat & 7;
            size_t gidx = (size_t)(m0 + m) * lda + k0 + c * 8;
            int lidx = m * 64 + ((c ^ (m & 7)) << 3);
            *(ushort8*)&sAh[lidx] = *(const ushort8*)&Ah[gidx];
            *(ushort8*)&sAl[lidx] = *(const ushort8*)&Al[gidx];
        }
        #pragma unroll
        for (int i = 0; i < 2; ++i) {
            int flat = i * 256 + t;
            int n = flat >> 3, c = flat & 7;
            size_t gidx = (size_t)(n0 + n) * ldb + k0 + c * 8;
            int lidx = n * 64 + ((c ^ (n & 7)) << 3);
            *(ushort8*)&sBh[lidx] = *(const ushort8*)&BTh[gidx];
            *(ushort8*)&sBl[lidx] = *(const ushort8*)&BTl[gidx];
        }
        __syncthreads();

        #pragma unroll
        for (int kk = 0; kk < 2; ++kk) {
            const int c = kk * 4 + lg;
            bf16x8 afh[4], afl[4];
            #pragma unroll
            for (int fm = 0; fm < 4; ++fm) {
                int m = wm * 64 + fm * 16 + lr;
                int lidx = m * 64 + ((c ^ (m & 7)) << 3);
                afh[fm] = *(bf16x8*)&sAh[lidx];
                afl[fm] = *(bf16x8*)&sAl[lidx];
            }
            bf16x8 bh[2], bl[2];
            #pragma unroll
            for (int fn = 0; fn < 2; ++fn) {
                int n = wn * 32 + fn * 16 + lr;
                int lidx = n * 64 + ((c ^ (n & 7)) << 3);
                bh[fn] = *(bf16x8*)&sBh[lidx];
                bl[fn] = *(bf16x8*)&sBl[lidx];
            }
            #pragma unroll
            for (int fm = 0; fm < 4; ++fm)
                #pragma unroll
                for (int fn = 0; fn < 2; ++fn) {
                    acc[fm][fn] = __builtin_amdgcn_mfma_f32_16x16x32_bf16(afh[fm], bh[fn], acc[fm][fn], 0, 0, 0);
                    acc[fm][fn] = __builtin_amdgcn_mfma_f32_16x16x32_bf16(afh[fm], bl[fn], acc[fm][fn], 0, 0, 0);
                    acc[fm][fn] = __builtin_amdgcn_mfma_f32_16x16x32_bf16(afl[fm], bh[fn], acc[fm][fn], 0, 0, 0);
                }
        }
    }

    #pragma unroll
    for (int fm = 0; fm < 4; ++fm)
        #pragma unroll
        for (int fn = 0; fn < 2; ++fn) {
            const int n = n0 + wn * 32 + fn * 16 + lr;
            #pragma unroll
            for (int r = 0; r < 4; ++r) {
                const int m = m0 + wm * 64 + fm * 16 + lg * 4 + r;
                C[(size_t)m * ldc + n] = acc[fm][fn][r];
            }
        }
}

// ---- MFMA out GEMM: x += ctx@Wa + h@Wff (A single bf16, B split, 2-pass) --
__global__ __launch_bounds__(256, 2) void mfma_out_k(
    const unsigned short* __restrict__ A1,
    const unsigned short* __restrict__ B1h, const unsigned short* __restrict__ B1l,
    const unsigned short* __restrict__ A2,
    const unsigned short* __restrict__ B2h, const unsigned short* __restrict__ B2l,
    float* __restrict__ X)
{
    __shared__ unsigned short sA[128 * 64];
    __shared__ unsigned short sBh[64 * 64];
    __shared__ unsigned short sBl[64 * 64];

    const int n0 = blockIdx.x << 6;
    const int m0 = blockIdx.y << 7;
    const int t  = threadIdx.x;
    const int l  = t & 63;
    const int w  = t >> 6;
    const int wm = w >> 1, wn = w & 1;
    const int lr = l & 15, lg = l >> 4;

    f32x4 acc[4][2];
    #pragma unroll
    for (int fm = 0; fm < 4; ++fm)
        #pragma unroll
        for (int fn = 0; fn < 2; ++fn) acc[fm][fn] = (f32x4)0.f;

    #pragma unroll
    for (int pass = 0; pass < 2; ++pass) {
        const unsigned short* pA  = pass ? A2 : A1;
        const unsigned short* pBh = pass ? B2h : B1h;
        const unsigned short* pBl = pass ? B2l : B1l;
        const int lda = pass ? FFIN : DIMM;
        const int KK  = pass ? FFIN : DIMM;

        for (int k0 = 0; k0 < KK; k0 += 64) {
            __syncthreads();
            #pragma unroll
            for (int i = 0; i < 4; ++i) {
                int flat = i * 256 + t;
                int m = flat >> 3, c = flat & 7;
                size_t gidx = (size_t)(m0 + m) * lda + k0 + c * 8;
                int lidx = m * 64 + ((c ^ (m & 7)) << 3);
                *(ushort8*)&sA[lidx] = *(const ushort8*)&pA[gidx];
            }
            #pragma unroll
            for (int i = 0; i < 2; ++i) {
                int flat = i * 256 + t;
                int n = flat >> 3, c = flat & 7;
                size_t gidx = (size_t)(n0 + n) * KK + k0 + c * 8;
                int lidx = n * 64 + ((c ^ (n & 7)) << 3);
                *(ushort8*)&sBh[lidx] = *(const ushort8*)&pBh[gidx];
                *(ushort8*)&sBl[lidx] = *(const ushort8*)&pBl[gidx];
            }
            __syncthreads();

            #pragma unroll
            for (int kk = 0; kk < 2; ++kk) {
                const int c = kk * 4 + lg;
                bf16x8 af[4];
                #pragma unroll
                for (int fm = 0; fm < 4; ++fm) {
                    int m = wm * 64 + fm * 16 + lr;
                    int lidx = m * 64 + ((c ^ (m & 7)) << 3);
                    af[fm] = *(bf16x8*)&sA[lidx];
                }
                bf16x8 bh[2], bl[2];
                #pragma unroll
                for (int fn = 0; fn < 2; ++fn) {
                    int n = wn * 32 + fn * 16 + lr;
                    int lidx = n * 64 + ((c ^ (n & 7)) << 3);
                    bh[fn] = *(bf16x8*)&sBh[lidx];
                    bl[fn] = *(bf16x8*)&sBl[lidx];
                }
                #pragma unroll
                for (int fm = 0; fm < 4; ++fm)
                    #pragma unroll
                    for (int fn = 0; fn < 2; ++fn) {
                        acc[fm][fn] = __builtin_amdgcn_mfma_f32_16x16x32_bf16(af[fm], bh[fn], acc[fm][fn], 0, 0, 0);
                        acc[fm][fn] = __builtin_amdgcn_mfma_f32_16x16x32_bf16(af[fm], bl[fn], acc[fm][fn], 0, 0, 0);
                    }
            }
        }
    }

    #pragma unroll
    for (int fm = 0; fm < 4; ++fm)
        #pragma unroll
        for (int fn = 0; fn < 2; ++fn) {
            const int n = n0 + wn * 32 + fn * 16 + lr;
            #pragma unroll
            for (int r = 0; r < 4; ++r) {
                const int m = m0 + wm * 64 + fm * 16 + lg * 4 + r;
                X[(size_t)m * DIMM + n] += acc[fm][fn][r];
            }
        }
}

// -- MFMA dual GEMM: h = silu(A@Wg)*(A@Wx), A single bf16, B split -> bf16 --
__global__ __launch_bounds__(256, 2) void mfma_dual_silu_k(
    const unsigned short* __restrict__ Ah,
    const unsigned short* __restrict__ WTh, const unsigned short* __restrict__ WTl,
    unsigned short* __restrict__ Hh)
{
    __shared__ unsigned short sA[128 * 64];
    __shared__ unsigned short sBxh[64 * 64];
    __shared__ unsigned short sBxl[64 * 64];
    __shared__ unsigned short sBgh[64 * 64];
    __shared__ unsigned short sBgl[64 * 64];

    const int n0 = blockIdx.x << 6;
    const int m0 = blockIdx.y << 7;
    const int t  = threadIdx.x;
    const int l  = t & 63;
    const int w  = t >> 6;
    const int wm = w >> 1, wn = w & 1;
    const int lr = l & 15, lg = l >> 4;

    f32x4 accX[4][2], accG[4][2];
    #pragma unroll
    for (int fm = 0; fm < 4; ++fm)
        #pragma unroll
        for (int fn = 0; fn < 2; ++fn) {
            accX[fm][fn] = (f32x4)0.f;
            accG[fm][fn] = (f32x4)0.f;
        }

    for (int k0 = 0; k0 < DIMM; k0 += 64) {
        __syncthreads();
        #pragma unroll
        for (int i = 0; i < 4; ++i) {
            int flat = i * 256 + t;
            int m = flat >> 3, c = flat & 7;
            size_t gidx = (size_t)(m0 + m) * DIMM + k0 + c * 8;
            int lidx = m * 64 + ((c ^ (m & 7)) << 3);
            *(ushort8*)&sA[lidx] = *(const ushort8*)&Ah[gidx];
        }
        #pragma unroll
        for (int i = 0; i < 2; ++i) {
            int flat = i * 256 + t;
            int n = flat >> 3, c = flat & 7;
            size_t gx = (size_t)(n0 + n) * DIMM + k0 + c * 8;
            size_t gg = (size_t)(2048 + n0 + n) * DIMM + k0 + c * 8;
            int lidx = n * 64 + ((c ^ (n & 7)) << 3);
            *(ushort8*)&sBxh[lidx] = *(const ushort8*)&WTh[gx];
            *(ushort8*)&sBxl[lidx] = *(const ushort8*)&WTl[gx];
            *(ushort8*)&sBgh[lidx] = *(const ushort8*)&WTh[gg];
            *(ushort8*)&sBgl[lidx] = *(const ushort8*)&WTl[gg];
        }
        __syncthreads();

        #pragma unroll
        for (int kk = 0; kk < 2; ++kk) {
            const int c = kk * 4 + lg;
            bf16x8 af[4];
            #pragma unroll
            for (int fm = 0; fm < 4; ++fm) {
                int m = wm * 64 + fm * 16 + lr;
                int lidx = m * 64 + ((c ^ (m & 7)) << 3);
                af[fm] = *(bf16x8*)&sA[lidx];
            }
            bf16x8 bxh[2], bxl[2], bgh[2], bgl[2];
            #pragma unroll
            for (int fn = 0; fn < 2; ++fn) {
                int n = wn * 32 + fn * 16 + lr;
                int lidx = n * 64 + ((c ^ (n & 7)) << 3);
                bxh[fn] = *(bf16x8*)&sBxh[lidx];
                bxl[fn] = *(bf16x8*)&sBxl[lidx];
                bgh[fn] = *(bf16x8*)&sBgh[lidx];
                bgl[fn] = *(bf16x8*)&sBgl[lidx];
            }
            #pragma unroll
            for (int fm = 0; fm < 4; ++fm)
                #pragma unroll
                for (int fn = 0; fn < 2; ++fn) {
                    accX[fm][fn] = __builtin_amdgcn_mfma_f32_16x16x32_bf16(af[fm], bxh[fn], accX[fm][fn], 0, 0, 0);
                    accX[fm][fn] = __builtin_amdgcn_mfma_f32_16x16x32_bf16(af[fm], bxl[fn], accX[fm][fn], 0, 0, 0);
                    accG[fm][fn] = __builtin_amdgcn_mfma_f32_16x16x32_bf16(af[fm], bgh[fn], accG[fm][fn], 0, 0, 0);
                    accG[fm][fn] = __builtin_amdgcn_mfma_f32_16x16x32_bf16(af[fm], bgl[fn], accG[fm][fn], 0, 0, 0);
                }
        }
    }

    #pragma unroll
    for (int fm = 0; fm < 4; ++fm)
        #pragma unroll
        for (int fn = 0; fn < 2; ++fn) {
            const int n = n0 + wn * 32 + fn * 16 + lr;
            #pragma unroll
            for (int r = 0; r < 4; ++r) {
                const int m = m0 + wm * 64 + fm * 16 + lg * 4 + r;
                float gv = accG[fm][fn][r];
                float xv = accX[fm][fn][r];
                float sig = 1.0f / (1.0f + expf(-gv));
                float hv = gv * sig * xv;
                float hf;
                Hh[(size_t)m * FFIN + n] = bfhi(hv, &hf);
            }
        }
}

// ------------------- attention: MFMA flash (per b,h,64 q-rows) -------------
__global__ __launch_bounds__(256) void attn_mfma_k(
    const unsigned short* __restrict__ qh, const unsigned short* __restrict__ ql,
    const unsigned short* __restrict__ kh, const unsigned short* __restrict__ kl,
    const unsigned short* __restrict__ vT,
    unsigned short* __restrict__ ctxh,
    const int* __restrict__ vl)
{
    __shared__ unsigned short sKh[64 * 64];
    __shared__ unsigned short sKl[64 * 64];
    __shared__ unsigned short sVT[64 * 64];
    __shared__ unsigned short sP[64 * 64];

    const int i0 = blockIdx.x << 6;
    const int h  = blockIdx.y;
    const int b  = blockIdx.z;
    const int t  = threadIdx.x;
    const int l  = t & 63;
    const int w  = t >> 6;
    const int lr = l & 15, lg = l >> 4;
    const int VL = vl[b];

    bf16x8 qfh[2], qfl[2];
    {
        size_t base = (((size_t)(b * 8 + h) * 512) + i0 + w * 16 + lr) * 64 + lg * 8;
        qfh[0] = *(const bf16x8*)&qh[base];
        qfh[1] = *(const bf16x8*)&qh[base + 32];
        qfl[0] = *(const bf16x8*)&ql[base];
        qfl[1] = *(const bf16x8*)&ql[base + 32];
    }

    float mrow[4], lrow[4];
    f32x4 oacc[4];
    #pragma unroll
    for (int r = 0; r < 4; ++r) { mrow[r] = -3.0e38f; lrow[r] = 0.f; }
    #pragma unroll
    for (int nb = 0; nb < 4; ++nb) oacc[nb] = (f32x4)0.f;

    for (int j0 = 0; j0 < SEQ; j0 += 64) {
        __syncthreads();
        #pragma unroll
        for (int i = 0; i < 2; ++i) {
            int flat = i * 256 + t;
            int m = flat >> 3, c = flat & 7;
            int lidx = m * 64 + ((c ^ (m & 7)) << 3);
            size_t kg = ((size_t)b * 512 + j0 + m) * 64 + c * 8;
            *(ushort8*)&sKh[lidx] = *(const ushort8*)&kh[kg];
            *(ushort8*)&sKl[lidx] = *(const ushort8*)&kl[kg];
            size_t vg = ((size_t)b * 64 + m) * 512 + j0 + c * 8;
            *(ushort8*)&sVT[lidx] = *(const ushort8*)&vT[vg];
        }
        __syncthreads();

        f32x4 accS[4];
        #pragma unroll
        for (int nb = 0; nb < 4; ++nb) accS[nb] = (f32x4)0.f;
        #pragma unroll
        for (int ks = 0; ks < 2; ++ks) {
            const int c = ks * 4 + lg;
            #pragma unroll
            for (int nb = 0; nb < 4; ++nb) {
                int n = nb * 16 + lr;
                int lidx = n * 64 + ((c ^ (n & 7)) << 3);
                bf16x8 kfh = *(bf16x8*)&sKh[lidx];
                bf16x8 kfl = *(bf16x8*)&sKl[lidx];
                accS[nb] = __builtin_amdgcn_mfma_f32_16x16x32_bf16(qfh[ks], kfh, accS[nb], 0, 0, 0);
                accS[nb] = __builtin_amdgcn_mfma_f32_16x16x32_bf16(qfh[ks], kfl, accS[nb], 0, 0, 0);
                accS[nb] = __builtin_amdgcn_mfma_f32_16x16x32_bf16(qfl[ks], kfh, accS[nb], 0, 0, 0);
            }
        }

        #pragma unroll
        for (int nb = 0; nb < 4; ++nb) {
            if (j0 + nb * 16 + lr >= VL) {
                #pragma unroll
                for (int r = 0; r < 4; ++r) accS[nb][r] = -3.0e38f;
            }
        }

        #pragma unroll
        for (int r = 0; r < 4; ++r) {
            float rm = fmaxf(fmaxf(accS[0][r], accS[1][r]), fmaxf(accS[2][r], accS[3][r]));
            #pragma unroll
            for (int off = 8; off; off >>= 1) rm = fmaxf(rm, __shfl_xor(rm, off));
            float nm = fmaxf(mrow[r], rm);
            float scl = expf(mrow[r] - nm);
            mrow[r] = nm;
            float ps = 0.f;
            #pragma unroll
            for (int nb = 0; nb < 4; ++nb) {
                float p = expf(accS[nb][r] - nm);
                accS[nb][r] = p;
                ps += p;
            }
            lrow[r] = lrow[r] * scl + ps;
            #pragma unroll
            for (int nb = 0; nb < 4; ++nb) oacc[nb][r] *= scl;
        }

        #pragma unroll
        for (int nb = 0; nb < 4; ++nb) {
            int cc = nb * 2 + (lr >> 3);
            #pragma unroll
            for (int r = 0; r < 4; ++r) {
                int q = w * 16 + lg * 4 + r;
                int lidx = q * 64 + ((cc ^ (q & 7)) << 3) + (lr & 7);
                float hf2;
                sP[lidx] = bfhi(accS[nb][r], &hf2);
            }
        }

        #pragma unroll
        for (int ks = 0; ks < 2; ++ks) {
            const int c = ks * 4 + lg;
            int qrow = w * 16 + lr;
            int plidx = qrow * 64 + ((c ^ (qrow & 7)) << 3);
            bf16x8 pf = *(bf16x8*)&sP[plidx];
            #pragma unroll
            for (int nb = 0; nb < 4; ++nb) {
                int n = nb * 16 + lr;
                int lidx = n * 64 + ((c ^ (n & 7)) << 3);
                bf16x8 vf = *(bf16x8*)&sVT[lidx];
                oacc[nb] = __builtin_amdgcn_mfma_f32_16x16x32_bf16(pf, vf, oacc[nb], 0, 0, 0);
            }
        }
    }

    #pragma unroll
    for (int r = 0; r < 4; ++r) {
        float lt = lrow[r];
        #pragma unroll
        for (int off = 8; off; off >>= 1) lt += __shfl_xor(lt, off);
        float inv = 1.0f / lt;
        const int row = (b << 9) + i0 + w * 16 + lg * 4 + r;
        const size_t base = (size_t)row * DIMM + h * 64;
        #pragma unroll
        for (int nb = 0; nb < 4; ++nb) {
            float v = oacc[nb][r] * inv;
            float hf;
            ctxh[base + nb * 16 + lr] = bfhi(v, &hf);
        }
    }
}

// ------------------------------ pool ---------------------------------------
__global__ __launch_bounds__(512) void pool_part_k(const float* __restrict__ x,
                                                   float* __restrict__ psum,
                                                   float* __restrict__ pmax)
{
    const int seg = blockIdx.x;
    const int b   = blockIdx.y;
    const int d   = threadIdx.x;
    const float* xb = x + ((size_t)(b << 9) + (seg << 6)) * DIMM;
    float s = 0.f, m = -3.0e38f;
    for (int i = 0; i < 64; ++i) {
        float v = xb[(size_t)i * DIMM + d];
        s += v;
        m = fmaxf(m, v);
    }
    psum[((size_t)b * 8 + seg) * DIMM + d] = s;
    pmax[((size_t)b * 8 + seg) * DIMM + d] = m;
}

__global__ __launch_bounds__(512) void pool_comb_k(const float* __restrict__ psum,
                                                   const float* __restrict__ pmax,
                                                   float* __restrict__ out)
{
    const int b = blockIdx.x;
    const int d = threadIdx.x;
    float s = 0.f, m = -3.0e38f;
    #pragma unroll
    for (int seg = 0; seg < 8; ++seg) {
        s += psum[((size_t)b * 8 + seg) * DIMM + d];
        m = fmaxf(m, pmax[((size_t)b * 8 + seg) * DIMM + d]);
    }
    out[b * 1024 + d] = s * (1.0f / 512.0f);
    out[b * 1024 + 512 + d] = m;
}

// ---------------------------------------------------------------------------
extern "C" void kernel_launch(void* const* d_in, const int* in_sizes, int n_in,
                              void* d_out, int out_size, void* d_ws, size_t ws_size,
                              hipStream_t stream)
{
    const int*   page_in        = (const int*)d_in[0];
    const int*   item_in        = (const int*)d_in[1];
    const int*   item_meta_in   = (const int*)d_in[2];
    const int*   vl_in          = (const int*)d_in[3];
    const int*   page_meta_in   = (const int*)d_in[4];
    const float* pwide          = (const float*)d_in[5];
    const float* iwide          = (const float*)d_in[6];
    const float* page_emb       = (const float*)d_in[7];
    const float* page_meta_emb  = (const float*)d_in[8];
    const float* item_emb       = (const float*)d_in[9];
    const float* item_meta_emb  = (const float*)d_in[10];
    const float* item_pre_emb   = (const float*)d_in[11];
    const float* pW             = (const float*)d_in[12];
    const float* pb             = (const float*)d_in[13];
    const float* pg             = (const float*)d_in[14];
    const float* pbeta          = (const float*)d_in[15];
    const float* iW             = (const float*)d_in[16];
    const float* ib             = (const float*)d_in[17];
    const float* ig             = (const float*)d_in[18];
    const float* ibeta          = (const float*)d_in[19];
    const float* norm_g         = (const float*)d_in[20];
    const float* fused_W        = (const float*)d_in[21];
    const float* attn_out_W     = (const float*)d_in[22];
    const float* ff_out_W       = (const float*)d_in[23];
    float* out = (float*)d_out;

    float* ws  = (float*)d_ws;
    float* x    = ws;                                      // 16384*512 f32
    unsigned short* xnh = (unsigned short*)(x + (size_t)NROWS * DIMM);
    unsigned short* xnl = xnh + (size_t)NROWS * DIMM;
    float* qkv = (float*)(xnl + (size_t)NROWS * DIMM);     // 16384*640 f32
    unsigned short* hh   = (unsigned short*)(qkv + (size_t)NROWS * QKVC);
    unsigned short* ctxh = hh + (size_t)NROWS * FFIN;
    float* psum = (float*)(ctxh + (size_t)NROWS * DIMM);
    float* pmax = psum + (size_t)NBATCH * 8 * DIMM;
    unsigned short* WqTh = (unsigned short*)(pmax + (size_t)NBATCH * 8 * DIMM);
    unsigned short* WqTl = WqTh + (size_t)QKVC * DIMM;     // 640x512
    unsigned short* WdTh = WqTl + (size_t)QKVC * DIMM;     // 4096x512
    unsigned short* WdTl = WdTh + (size_t)4096 * DIMM;
    unsigned short* WaTh = WdTl + (size_t)4096 * DIMM;     // 512x512
    unsigned short* WaTl = WaTh + (size_t)DIMM * DIMM;
    unsigned short* WfTh = WaTl + (size_t)DIMM * DIMM;     // 512x2048
    unsigned short* WfTl = WfTh + (size_t)DIMM * FFIN;
    unsigned short* khb  = WfTl + (size_t)DIMM * FFIN;     // 32x512x64
    unsigned short* klb  = khb + (size_t)NBATCH * SEQ * 64;
    unsigned short* vTb  = klb + (size_t)NBATCH * SEQ * 64; // 32x64x512
    float* cost = (float*)(vTb + (size_t)NBATCH * 64 * SEQ); // 512x32
    float* sint = cost + 512 * 32;
    // q hi/lo alias xnh/xnl (xn dead after dual-silu; rope runs after it)
    unsigned short* qhb = xnh;
    unsigned short* qlb = xnl;

    build_x_k<<<NROWS, 512, 0, stream>>>(
        page_in, item_in, item_meta_in, page_meta_in, pwide, iwide,
        page_emb, page_meta_emb, item_emb, item_meta_emb, item_pre_emb,
        pW, pb, pg, pbeta, iW, ib, ig, ibeta, x);

    trig_k<<<64, 256, 0, stream>>>(cost, sint);

    for (int l = 0; l < 4; ++l) {
        const float* Wf  = fused_W    + (size_t)l * DIMM * NFUSED;
        const float* Wa  = attn_out_W + (size_t)l * DIMM * DIMM;
        const float* Wff = ff_out_W   + (size_t)l * FFIN * DIMM;
        const float* g   = norm_g     + (size_t)l * DIMM;

        ln_k<<<NROWS, 256, 0, stream>>>(x, xnh, xnl, g);

        wconv_k<<<dim3(QKVC / 64, DIMM / 64), 256, 0, stream>>>(
            Wf, NFUSED, 0, WqTh, WqTl, DIMM);
        wconv_k<<<dim3(4096 / 64, DIMM / 64), 256, 0, stream>>>(
            Wf, NFUSED, 640, WdTh, WdTl, DIMM);
        wconv_k<<<dim3(DIMM / 64, DIMM / 64), 256, 0, stream>>>(
            Wa, DIMM, 0, WaTh, WaTl, DIMM);
        wconv_k<<<dim3(DIMM / 64, FFIN / 64), 256, 0, stream>>>(
            Wff, DIMM, 0, WfTh, WfTl, FFIN);

        mfma_gemm_k<<<dim3(QKVC / 64, NROWS / 128), 256, 0, stream>>>(
            xnh, xnl, DIMM, WqTh, WqTl, DIMM, DIMM, qkv, QKVC);

        mfma_dual_silu_k<<<dim3(FFIN / 64, NROWS / 128), 256, 0, stream>>>(
            xnh, WdTh, WdTl, hh);

        // xn dead now; rope writes q hi/lo into its space
        rope_split_k<<<NROWS / 4, 256, 0, stream>>>(
            qkv, cost, sint, qhb, qlb, khb, klb, vTb);

        attn_mfma_k<<<dim3(SEQ / 64, NHEAD, NBATCH), 256, 0, stream>>>(
            qhb, qlb, khb, klb, vTb, ctxh, vl_in);

        mfma_out_k<<<dim3(DIMM / 64, NROWS / 128), 256, 0, stream>>>(
            ctxh, WaTh, WaTl, hh, WfTh, WfTl, x);
    }

    pool_part_k<<<dim3(8, NBATCH), 512, 0, stream>>>(x, psum, pmax);
    pool_comb_k<<<NBATCH, 512, 0, stream>>>(psum, pmax, out);
}

// Round 8
// 1503.756 us; speedup vs baseline: 6.1332x; 1.1462x over previous
//
#include <hip/hip_runtime.h>
#include <math.h>

// ---------------------------------------------------------------------------
// ParallelTransformerAEP forward.
// R7: precision tiering deepened — dual/out GEMMs use single-bf16 weights
//     (1-2 MFMA products); only qkv GEMM + attention QK keep split products.
// ---------------------------------------------------------------------------

namespace {
constexpr int SEQ    = 512;
constexpr int NBATCH = 32;
constexpr int DIMM   = 512;
constexpr int NHEAD  = 8;
constexpr int FFIN   = 2048;
constexpr int NFUSED = 4736;
constexpr int NROWS  = NBATCH * SEQ;   // 16384
constexpr int QKVC   = 640;            // 512 q + 64 k + 64 v
}

typedef __bf16 bf16x8 __attribute__((ext_vector_type(8)));
typedef float f32x4 __attribute__((ext_vector_type(4)));
typedef unsigned short ushort8 __attribute__((ext_vector_type(8)));

static __device__ __forceinline__ unsigned short bfhi(float v, float* hf) {
    __bf16 h = (__bf16)v;
    *hf = (float)h;
    return __builtin_bit_cast(unsigned short, h);
}
static __device__ __forceinline__ unsigned short bflo(float v, float hf) {
    __bf16 l = (__bf16)(v - hf);
    return __builtin_bit_cast(unsigned short, l);
}

// ------------------------- build x = page * item ---------------------------
__global__ __launch_bounds__(512) void build_x_k(
    const int* __restrict__ page_in, const int* __restrict__ item_in,
    const int* __restrict__ item_meta_in, const int* __restrict__ page_meta_in,
    const float* __restrict__ pwide, const float* __restrict__ iwide,
    const float* __restrict__ page_emb, const float* __restrict__ page_meta_emb,
    const float* __restrict__ item_emb, const float* __restrict__ item_meta_emb,
    const float* __restrict__ item_pre_emb,
    const float* __restrict__ pW, const float* __restrict__ pb,
    const float* __restrict__ pg, const float* __restrict__ pbeta,
    const float* __restrict__ iW, const float* __restrict__ ib,
    const float* __restrict__ ig, const float* __restrict__ ibeta,
    float* __restrict__ x)
{
    const int row = blockIdx.x;
    const int b = row >> 9;
    const int s = row & 511;
    const int d = threadIdx.x;
    const float BNS = 0.9999950000374997f;   // 1/sqrt(1+1e-5)

    float pv, iv;
    if (d < 384) {
        pv = page_emb[(size_t)page_in[row] * 384 + d];
    } else if (d < 448) {
        pv = page_meta_emb[(size_t)page_meta_in[row] * 64 + (d - 384)];
    } else {
        const int dd = d - 448;
        float acc = pb[dd];
        #pragma unroll
        for (int c = 0; c < 8; ++c) {
            float w  = pwide[((size_t)b * 8 + c) * SEQ + s];
            float wn = w * BNS * pg[c] + pbeta[c];
            acc += wn * pW[c * 64 + dd];
        }
        pv = acc > 0.f ? acc : 0.2f * acc;
    }
    if (d < 320) {
        iv = item_emb[(size_t)item_in[row] * 320 + d];
    } else if (d < 384) {
        iv = item_meta_emb[(size_t)item_meta_in[row] * 64 + (d - 320)];
    } else if (d < 448) {
        iv = item_pre_emb[(size_t)item_in[row] * 64 + (d - 384)];
    } else {
        const int dd = d - 448;
        float acc = ib[dd];
        #pragma unroll
        for (int c = 0; c < 8; ++c) {
            float w  = iwide[((size_t)b * 8 + c) * SEQ + s];
            float wn = w * BNS * ig[c] + ibeta[c];
            acc += wn * iW[c * 64 + dd];
        }
        iv = acc > 0.f ? acc : 0.2f * acc;
    }
    x[(size_t)row * DIMM + d] = pv * iv;
}

// ------------------------------ trig table ---------------------------------
__global__ __launch_bounds__(256) void trig_k(float* __restrict__ cost,
                                              float* __restrict__ sint)
{
    const int idx = blockIdx.x * 256 + threadIdx.x;   // 16384 = 512 x 32
    const int s = idx >> 5, j = idx & 31;
    float invf = powf(10000.0f, -(float)j * (1.0f / 32.0f));
    float ang = (float)s * invf;
    float sn, cs;
    sincosf(ang, &sn, &cs);
    cost[idx] = cs;
    sint[idx] = sn;
}

// ------------------------------ LayerNorm -> bf16 hi/lo --------------------
__global__ __launch_bounds__(256) void ln_k(const float* __restrict__ x,
                                            unsigned short* __restrict__ xnh,
                                            unsigned short* __restrict__ xnl,
                                            const float* __restrict__ g)
{
    const int row = blockIdx.x;
    const int t = threadIdx.x;
    const float* xr = x + (size_t)row * DIMM;
    __shared__ float red[4];

    float v0 = xr[t], v1 = xr[t + 256];
    float s = v0 + v1;
    #pragma unroll
    for (int o = 32; o; o >>= 1) s += __shfl_xor(s, o);
    if ((t & 63) == 0) red[t >> 6] = s;
    __syncthreads();
    float mu = (red[0] + red[1] + red[2] + red[3]) * (1.0f / 512.0f);
    __syncthreads();

    float d0 = v0 - mu, d1 = v1 - mu;
    float vs = d0 * d0 + d1 * d1;
    #pragma unroll
    for (int o = 32; o; o >>= 1) vs += __shfl_xor(vs, o);
    if ((t & 63) == 0) red[t >> 6] = vs;
    __syncthreads();
    float var = (red[0] + red[1] + red[2] + red[3]) * (1.0f / 512.0f);
    float r = 1.0f / sqrtf(var + 1e-5f);

    const size_t base = (size_t)row * DIMM;
    float o0 = d0 * r * g[t];
    float o1 = d1 * r * g[t + 256];
    float h0f, h1f;
    xnh[base + t]       = bfhi(o0, &h0f);
    xnh[base + t + 256] = bfhi(o1, &h1f);
    xnl[base + t]       = bflo(o0, h0f);
    xnl[base + t + 256] = bflo(o1, h1f);
}

// ---------------- weight transpose + split: WT[n][k] = W[k][col0+n] --------
// SPLIT: emit hi+lo; else hi only.
template <bool SPLIT>
__global__ __launch_bounds__(256) void wconv_k(const float* __restrict__ W, int ldw,
                                               int col0,
                                               unsigned short* __restrict__ WTh,
                                               unsigned short* __restrict__ WTl,
                                               int ldt)
{
    __shared__ float tile[64][65];
    const int nt = blockIdx.x << 6;
    const int kt = blockIdx.y << 6;
    const int t  = threadIdx.x;

    #pragma unroll
    for (int i = 0; i < 16; ++i) {
        int flat = i * 256 + t;
        int r = flat >> 6, c = flat & 63;
        tile[r][c] = W[(size_t)(kt + r) * ldw + col0 + nt + c];
    }
    __syncthreads();
    #pragma unroll
    for (int i = 0; i < 2; ++i) {
        int flat = i * 256 + t;
        int n = flat >> 3, ck = (flat & 7) << 3;
        ushort8 hv, lv;
        #pragma unroll
        for (int j = 0; j < 8; ++j) {
            float v = tile[ck + j][n];
            float hf;
            hv[j] = bfhi(v, &hf);
            if (SPLIT) lv[j] = bflo(v, hf);
        }
        size_t o = (size_t)(nt + n) * ldt + kt + ck;
        *(ushort8*)&WTh[o] = hv;
        if (SPLIT) *(ushort8*)&WTl[o] = lv;
    }
}

// ----------- RoPE + split: qkv fp32 -> qh/ql [b,h,s,64], kh/kl, vT ---------
__global__ __launch_bounds__(256) void rope_split_k(
    const float* __restrict__ qkv,
    const float* __restrict__ cost, const float* __restrict__ sint,
    unsigned short* __restrict__ qh, unsigned short* __restrict__ ql,
    unsigned short* __restrict__ kh, unsigned short* __restrict__ kl,
    unsigned short* __restrict__ vT)
{
    const int row = (blockIdx.x << 2) + (threadIdx.x >> 6);
    const int b = row >> 9;
    const int s = row & 511;
    const int d = threadIdx.x & 63;
    const int j = d & 31;

    const float cs = cost[s * 32 + j];
    const float sn = sint[s * 32 + j];

    const float* rowp = qkv + (size_t)row * QKVC;
    const int pair = (d < 32) ? d + 32 : d - 32;
    const float sgn = (d < 32) ? -1.f : 1.f;
    float hf;

    // k (rope, no scale)
    float kv = rowp[512 + d];
    float kp = rowp[512 + pair];
    float kr = kv * cs + sgn * kp * sn;
    size_t kidx = ((size_t)b * 512 + s) * 64 + d;
    kh[kidx] = bfhi(kr, &hf);
    kl[kidx] = bflo(kr, hf);

    // v transposed, single bf16
    float vv = rowp[576 + d];
    vT[((size_t)b * 64 + d) * 512 + s] = bfhi(vv, &hf);

    // q per head (rope + 1/sqrt(d) scale)
    #pragma unroll
    for (int h = 0; h < NHEAD; ++h) {
        float qv = rowp[h * 64 + d];
        float qp = rowp[h * 64 + pair];
        float qr = (qv * cs + sgn * qp * sn) * 0.125f;
        size_t qidx = (((size_t)b * 8 + h) * 512 + s) * 64 + d;
        qh[qidx] = bfhi(qr, &hf);
        ql[qidx] = bflo(qr, hf);
    }
}

// -------------- MFMA GEMM (split bf16, 3-product): C_fp32 = A @ B^T --------
__global__ __launch_bounds__(256, 2) void mfma_gemm_k(
    const unsigned short* __restrict__ Ah, const unsigned short* __restrict__ Al,
    int lda,
    const unsigned short* __restrict__ BTh, const unsigned short* __restrict__ BTl,
    int ldb, int K,
    float* __restrict__ C, int ldc)
{
    __shared__ unsigned short sAh[128 * 64];
    __shared__ unsigned short sAl[128 * 64];
    __shared__ unsigned short sBh[64 * 64];
    __shared__ unsigned short sBl[64 * 64];

    const int n0 = blockIdx.x << 6;
    const int m0 = blockIdx.y << 7;
    const int t  = threadIdx.x;
    const int l  = t & 63;
    const int w  = t >> 6;
    const int wm = w >> 1, wn = w & 1;
    const int lr = l & 15, lg = l >> 4;

    f32x4 acc[4][2];
    #pragma unroll
    for (int fm = 0; fm < 4; ++fm)
        #pragma unroll
        for (int fn = 0; fn < 2; ++fn) acc[fm][fn] = (f32x4)0.f;

    for (int k0 = 0; k0 < K; k0 += 64) {
        __syncthreads();
        #pragma unroll
        for (int i = 0; i < 4; ++i) {
            int flat = i * 256 + t;
            int m = flat >> 3, c = flat & 7;
            size_t gidx = (size_t)(m0 + m) * lda + k0 + c * 8;
            int lidx = m * 64 + ((c ^ (m & 7)) << 3);
            *(ushort8*)&sAh[lidx] = *(const ushort8*)&Ah[gidx];
            *(ushort8*)&sAl[lidx] = *(const ushort8*)&Al[gidx];
        }
        #pragma unroll
        for (int i = 0; i < 2; ++i) {
            int flat = i * 256 + t;
            int n = flat >> 3, c = flat & 7;
            size_t gidx = (size_t)(n0 + n) * ldb + k0 + c * 8;
            int lidx = n * 64 + ((c ^ (n & 7)) << 3);
            *(ushort8*)&sBh[lidx] = *(const ushort8*)&BTh[gidx];
            *(ushort8*)&sBl[lidx] = *(const ushort8*)&BTl[gidx];
        }
        __syncthreads();

        #pragma unroll
        for (int kk = 0; kk < 2; ++kk) {
            const int c = kk * 4 + lg;
            bf16x8 afh[4], afl[4];
            #pragma unroll
            for (int fm = 0; fm < 4; ++fm) {
                int m = wm * 64 + fm * 16 + lr;
                int lidx = m * 64 + ((c ^ (m & 7)) << 3);
                afh[fm] = *(bf16x8*)&sAh[lidx];
                afl[fm] = *(bf16x8*)&sAl[lidx];
            }
            bf16x8 bh[2], bl[2];
            #pragma unroll
            for (int fn = 0; fn < 2; ++fn) {
                int n = wn * 32 + fn * 16 + lr;
                int lidx = n * 64 + ((c ^ (n & 7)) << 3);
                bh[fn] = *(bf16x8*)&sBh[lidx];
                bl[fn] = *(bf16x8*)&sBl[lidx];
            }
            #pragma unroll
            for (int fm = 0; fm < 4; ++fm)
                #pragma unroll
                for (int fn = 0; fn < 2; ++fn) {
                    acc[fm][fn] = __builtin_amdgcn_mfma_f32_16x16x32_bf16(afh[fm], bh[fn], acc[fm][fn], 0, 0, 0);
                    acc[fm][fn] = __builtin_amdgcn_mfma_f32_16x16x32_bf16(afh[fm], bl[fn], acc[fm][fn], 0, 0, 0);
                    acc[fm][fn] = __builtin_amdgcn_mfma_f32_16x16x32_bf16(afl[fm], bh[fn], acc[fm][fn], 0, 0, 0);
                }
        }
    }

    #pragma unroll
    for (int fm = 0; fm < 4; ++fm)
        #pragma unroll
        for (int fn = 0; fn < 2; ++fn) {
            const int n = n0 + wn * 32 + fn * 16 + lr;
            #pragma unroll
            for (int r = 0; r < 4; ++r) {
                const int m = m0 + wm * 64 + fm * 16 + lg * 4 + r;
                C[(size_t)m * ldc + n] = acc[fm][fn][r];
            }
        }
}

// ----- MFMA out GEMM: x += ctx@Wa + h@Wff (all single bf16, 2-pass K) ------
__global__ __launch_bounds__(256, 2) void mfma_out_k(
    const unsigned short* __restrict__ A1,
    const unsigned short* __restrict__ B1,
    const unsigned short* __restrict__ A2,
    const unsigned short* __restrict__ B2,
    float* __restrict__ X)
{
    __shared__ unsigned short sA[128 * 64];
    __shared__ unsigned short sB[64 * 64];

    const int n0 = blockIdx.x << 6;
    const int m0 = blockIdx.y << 7;
    const int t  = threadIdx.x;
    const int l  = t & 63;
    const int w  = t >> 6;
    const int wm = w >> 1, wn = w & 1;
    const int lr = l & 15, lg = l >> 4;

    f32x4 acc[4][2];
    #pragma unroll
    for (int fm = 0; fm < 4; ++fm)
        #pragma unroll
        for (int fn = 0; fn < 2; ++fn) acc[fm][fn] = (f32x4)0.f;

    #pragma unroll
    for (int pass = 0; pass < 2; ++pass) {
        const unsigned short* pA = pass ? A2 : A1;
        const unsigned short* pB = pass ? B2 : B1;
        const int lda = pass ? FFIN : DIMM;
        const int KK  = pass ? FFIN : DIMM;

        for (int k0 = 0; k0 < KK; k0 += 64) {
            __syncthreads();
            #pragma unroll
            for (int i = 0; i < 4; ++i) {
                int flat = i * 256 + t;
                int m = flat >> 3, c = flat & 7;
                size_t gidx = (size_t)(m0 + m) * lda + k0 + c * 8;
                int lidx = m * 64 + ((c ^ (m & 7)) << 3);
                *(ushort8*)&sA[lidx] = *(const ushort8*)&pA[gidx];
            }
            #pragma unroll
            for (int i = 0; i < 2; ++i) {
                int flat = i * 256 + t;
                int n = flat >> 3, c = flat & 7;
                size_t gidx = (size_t)(n0 + n) * KK + k0 + c * 8;
                int lidx = n * 64 + ((c ^ (n & 7)) << 3);
                *(ushort8*)&sB[lidx] = *(const ushort8*)&pB[gidx];
            }
            __syncthreads();

            #pragma unroll
            for (int kk = 0; kk < 2; ++kk) {
                const int c = kk * 4 + lg;
                bf16x8 af[4];
                #pragma unroll
                for (int fm = 0; fm < 4; ++fm) {
                    int m = wm * 64 + fm * 16 + lr;
                    int lidx = m * 64 + ((c ^ (m & 7)) << 3);
                    af[fm] = *(bf16x8*)&sA[lidx];
                }
                bf16x8 bf[2];
                #pragma unroll
                for (int fn = 0; fn < 2; ++fn) {
                    int n = wn * 32 + fn * 16 + lr;
                    int lidx = n * 64 + ((c ^ (n & 7)) << 3);
                    bf[fn] = *(bf16x8*)&sB[lidx];
                }
                #pragma unroll
                for (int fm = 0; fm < 4; ++fm)
                    #pragma unroll
                    for (int fn = 0; fn < 2; ++fn)
                        acc[fm][fn] = __builtin_amdgcn_mfma_f32_16x16x32_bf16(af[fm], bf[fn], acc[fm][fn], 0, 0, 0);
            }
        }
    }

    #pragma unroll
    for (int fm = 0; fm < 4; ++fm)
        #pragma unroll
        for (int fn = 0; fn < 2; ++fn) {
            const int n = n0 + wn * 32 + fn * 16 + lr;
            #pragma unroll
            for (int r = 0; r < 4; ++r) {
                const int m = m0 + wm * 64 + fm * 16 + lg * 4 + r;
                X[(size_t)m * DIMM + n] += acc[fm][fn][r];
            }
        }
}

// --- MFMA dual GEMM: h = silu(A@Wg)*(A@Wx), all single bf16 -> bf16 --------
__global__ __launch_bounds__(256, 2) void mfma_dual_silu_k(
    const unsigned short* __restrict__ Ah,
    const unsigned short* __restrict__ WTh,
    unsigned short* __restrict__ Hh)
{
    __shared__ unsigned short sA[128 * 64];
    __shared__ unsigned short sBx[64 * 64];
    __shared__ unsigned short sBg[64 * 64];

    const int n0 = blockIdx.x << 6;
    const int m0 = blockIdx.y << 7;
    const int t  = threadIdx.x;
    const int l  = t & 63;
    const int w  = t >> 6;
    const int wm = w >> 1, wn = w & 1;
    const int lr = l & 15, lg = l >> 4;

    f32x4 accX[4][2], accG[4][2];
    #pragma unroll
    for (int fm = 0; fm < 4; ++fm)
        #pragma unroll
        for (int fn = 0; fn < 2; ++fn) {
            accX[fm][fn] = (f32x4)0.f;
            accG[fm][fn] = (f32x4)0.f;
        }

    for (int k0 = 0; k0 < DIMM; k0 += 64) {
        __syncthreads();
        #pragma unroll
        for (int i = 0; i < 4; ++i) {
            int flat = i * 256 + t;
            int m = flat >> 3, c = flat & 7;
            size_t gidx = (size_t)(m0 + m) * DIMM + k0 + c * 8;
            int lidx = m * 64 + ((c ^ (m & 7)) << 3);
            *(ushort8*)&sA[lidx] = *(const ushort8*)&Ah[gidx];
        }
        #pragma unroll
        for (int i = 0; i < 2; ++i) {
            int flat = i * 256 + t;
            int n = flat >> 3, c = flat & 7;
            size_t gx = (size_t)(n0 + n) * DIMM + k0 + c * 8;
            size_t gg = (size_t)(2048 + n0 + n) * DIMM + k0 + c * 8;
            int lidx = n * 64 + ((c ^ (n & 7)) << 3);
            *(ushort8*)&sBx[lidx] = *(const ushort8*)&WTh[gx];
            *(ushort8*)&sBg[lidx] = *(const ushort8*)&WTh[gg];
        }
        __syncthreads();

        #pragma unroll
        for (int kk = 0; kk < 2; ++kk) {
            const int c = kk * 4 + lg;
            bf16x8 af[4];
            #pragma unroll
            for (int fm = 0; fm < 4; ++fm) {
                int m = wm * 64 + fm * 16 + lr;
                int lidx = m * 64 + ((c ^ (m & 7)) << 3);
                af[fm] = *(bf16x8*)&sA[lidx];
            }
            bf16x8 bx[2], bg[2];
            #pragma unroll
            for (int fn = 0; fn < 2; ++fn) {
                int n = wn * 32 + fn * 16 + lr;
                int lidx = n * 64 + ((c ^ (n & 7)) << 3);
                bx[fn] = *(bf16x8*)&sBx[lidx];
                bg[fn] = *(bf16x8*)&sBg[lidx];
            }
            #pragma unroll
            for (int fm = 0; fm < 4; ++fm)
                #pragma unroll
                for (int fn = 0; fn < 2; ++fn) {
                    accX[fm][fn] = __builtin_amdgcn_mfma_f32_16x16x32_bf16(af[fm], bx[fn], accX[fm][fn], 0, 0, 0);
                    accG[fm][fn] = __builtin_amdgcn_mfma_f32_16x16x32_bf16(af[fm], bg[fn], accG[fm][fn], 0, 0, 0);
                }
        }
    }

    #pragma unroll
    for (int fm = 0; fm < 4; ++fm)
        #pragma unroll
        for (int fn = 0; fn < 2; ++fn) {
            const int n = n0 + wn * 32 + fn * 16 + lr;
            #pragma unroll
            for (int r = 0; r < 4; ++r) {
                const int m = m0 + wm * 64 + fm * 16 + lg * 4 + r;
                float gv = accG[fm][fn][r];
                float xv = accX[fm][fn][r];
                float sig = 1.0f / (1.0f + expf(-gv));
                float hv = gv * sig * xv;
                float hf;
                Hh[(size_t)m * FFIN + n] = bfhi(hv, &hf);
            }
        }
}

// ------------------- attention: MFMA flash (per b,h,64 q-rows) -------------
__global__ __launch_bounds__(256) void attn_mfma_k(
    const unsigned short* __restrict__ qh, const unsigned short* __restrict__ ql,
    const unsigned short* __restrict__ kh, const unsigned short* __restrict__ kl,
    const unsigned short* __restrict__ vT,
    unsigned short* __restrict__ ctxh,
    const int* __restrict__ vl)
{
    __shared__ unsigned short sKh[64 * 64];
    __shared__ unsigned short sKl[64 * 64];
    __shared__ unsigned short sVT[64 * 64];
    __shared__ unsigned short sP[64 * 64];

    const int i0 = blockIdx.x << 6;
    const int h  = blockIdx.y;
    const int b  = blockIdx.z;
    const int t  = threadIdx.x;
    const int l  = t & 63;
    const int w  = t >> 6;
    const int lr = l & 15, lg = l >> 4;
    const int VL = vl[b];

    bf16x8 qfh[2], qfl[2];
    {
        size_t base = (((size_t)(b * 8 + h) * 512) + i0 + w * 16 + lr) * 64 + lg * 8;
        qfh[0] = *(const bf16x8*)&qh[base];
        qfh[1] = *(const bf16x8*)&qh[base + 32];
        qfl[0] = *(const bf16x8*)&ql[base];
        qfl[1] = *(const bf16x8*)&ql[base + 32];
    }

    float mrow[4], lrow[4];
    f32x4 oacc[4];
    #pragma unroll
    for (int r = 0; r < 4; ++r) { mrow[r] = -3.0e38f; lrow[r] = 0.f; }
    #pragma unroll
    for (int nb = 0; nb < 4; ++nb) oacc[nb] = (f32x4)0.f;

    for (int j0 = 0; j0 < SEQ; j0 += 64) {
        __syncthreads();
        #pragma unroll
        for (int i = 0; i < 2; ++i) {
            int flat = i * 256 + t;
            int m = flat >> 3, c = flat & 7;
            int lidx = m * 64 + ((c ^ (m & 7)) << 3);
            size_t kg = ((size_t)b * 512 + j0 + m) * 64 + c * 8;
            *(ushort8*)&sKh[lidx] = *(const ushort8*)&kh[kg];
            *(ushort8*)&sKl[lidx] = *(const ushort8*)&kl[kg];
            size_t vg = ((size_t)b * 64 + m) * 512 + j0 + c * 8;
            *(ushort8*)&sVT[lidx] = *(const ushort8*)&vT[vg];
        }
        __syncthreads();

        f32x4 accS[4];
        #pragma unroll
        for (int nb = 0; nb < 4; ++nb) accS[nb] = (f32x4)0.f;
        #pragma unroll
        for (int ks = 0; ks < 2; ++ks) {
            const int c = ks * 4 + lg;
            #pragma unroll
            for (int nb = 0; nb < 4; ++nb) {
                int n = nb * 16 + lr;
                int lidx = n * 64 + ((c ^ (n & 7)) << 3);
                bf16x8 kfh = *(bf16x8*)&sKh[lidx];
                bf16x8 kfl = *(bf16x8*)&sKl[lidx];
                accS[nb] = __builtin_amdgcn_mfma_f32_16x16x32_bf16(qfh[ks], kfh, accS[nb], 0, 0, 0);
                accS[nb] = __builtin_amdgcn_mfma_f32_16x16x32_bf16(qfh[ks], kfl, accS[nb], 0, 0, 0);
                accS[nb] = __builtin_amdgcn_mfma_f32_16x16x32_bf16(qfl[ks], kfh, accS[nb], 0, 0, 0);
            }
        }

        #pragma unroll
        for (int nb = 0; nb < 4; ++nb) {
            if (j0 + nb * 16 + lr >= VL) {
                #pragma unroll
                for (int r = 0; r < 4; ++r) accS[nb][r] = -3.0e38f;
            }
        }

        #pragma unroll
        for (int r = 0; r < 4; ++r) {
            float rm = fmaxf(fmaxf(accS[0][r], accS[1][r]), fmaxf(accS[2][r], accS[3][r]));
            #pragma unroll
            for (int off = 8; off; off >>= 1) rm = fmaxf(rm, __shfl_xor(rm, off));
            float nm = fmaxf(mrow[r], rm);
            float scl = expf(mrow[r] - nm);
            mrow[r] = nm;
            float ps = 0.f;
            #pragma unroll
            for (int nb = 0; nb < 4; ++nb) {
                float p = expf(accS[nb][r] - nm);
                accS[nb][r] = p;
                ps += p;
            }
            lrow[r] = lrow[r] * scl + ps;
            #pragma unroll
            for (int nb = 0; nb < 4; ++nb) oacc[nb][r] *= scl;
        }

        #pragma unroll
        for (int nb = 0; nb < 4; ++nb) {
            int cc = nb * 2 + (lr >> 3);
            #pragma unroll
            for (int r = 0; r < 4; ++r) {
                int q = w * 16 + lg * 4 + r;
                int lidx = q * 64 + ((cc ^ (q & 7)) << 3) + (lr & 7);
                float hf2;
                sP[lidx] = bfhi(accS[nb][r], &hf2);
            }
        }

        #pragma unroll
        for (int ks = 0; ks < 2; ++ks) {
            const int c = ks * 4 + lg;
            int qrow = w * 16 + lr;
            int plidx = qrow * 64 + ((c ^ (qrow & 7)) << 3);
            bf16x8 pf = *(bf16x8*)&sP[plidx];
            #pragma unroll
            for (int nb = 0; nb < 4; ++nb) {
                int n = nb * 16 + lr;
                int lidx = n * 64 + ((c ^ (n & 7)) << 3);
                bf16x8 vf = *(bf16x8*)&sVT[lidx];
                oacc[nb] = __builtin_amdgcn_mfma_f32_16x16x32_bf16(pf, vf, oacc[nb], 0, 0, 0);
            }
        }
    }

    #pragma unroll
    for (int r = 0; r < 4; ++r) {
        float lt = lrow[r];
        #pragma unroll
        for (int off = 8; off; off >>= 1) lt += __shfl_xor(lt, off);
        float inv = 1.0f / lt;
        const int row = (b << 9) + i0 + w * 16 + lg * 4 + r;
        const size_t base = (size_t)row * DIMM + h * 64;
        #pragma unroll
        for (int nb = 0; nb < 4; ++nb) {
            float v = oacc[nb][r] * inv;
            float hf;
            ctxh[base + nb * 16 + lr] = bfhi(v, &hf);
        }
    }
}

// ------------------------------ pool ---------------------------------------
__global__ __launch_bounds__(512) void pool_part_k(const float* __restrict__ x,
                                                   float* __restrict__ psum,
                                                   float* __restrict__ pmax)
{
    const int seg = blockIdx.x;
    const int b   = blockIdx.y;
    const int d   = threadIdx.x;
    const float* xb = x + ((size_t)(b << 9) + (seg << 6)) * DIMM;
    float s = 0.f, m = -3.0e38f;
    for (int i = 0; i < 64; ++i) {
        float v = xb[(size_t)i * DIMM + d];
        s += v;
        m = fmaxf(m, v);
    }
    psum[((size_t)b * 8 + seg) * DIMM + d] = s;
    pmax[((size_t)b * 8 + seg) * DIMM + d] = m;
}

__global__ __launch_bounds__(512) void pool_comb_k(const float* __restrict__ psum,
                                                   const float* __restrict__ pmax,
                                                   float* __restrict__ out)
{
    const int b = blockIdx.x;
    const int d = threadIdx.x;
    float s = 0.f, m = -3.0e38f;
    #pragma unroll
    for (int seg = 0; seg < 8; ++seg) {
        s += psum[((size_t)b * 8 + seg) * DIMM + d];
        m = fmaxf(m, pmax[((size_t)b * 8 + seg) * DIMM + d]);
    }
    out[b * 1024 + d] = s * (1.0f / 512.0f);
    out[b * 1024 + 512 + d] = m;
}

// ---------------------------------------------------------------------------
extern "C" void kernel_launch(void* const* d_in, const int* in_sizes, int n_in,
                              void* d_out, int out_size, void* d_ws, size_t ws_size,
                              hipStream_t stream)
{
    const int*   page_in        = (const int*)d_in[0];
    const int*   item_in        = (const int*)d_in[1];
    const int*   item_meta_in   = (const int*)d_in[2];
    const int*   vl_in          = (const int*)d_in[3];
    const int*   page_meta_in   = (const int*)d_in[4];
    const float* pwide          = (const float*)d_in[5];
    const float* iwide          = (const float*)d_in[6];
    const float* page_emb       = (const float*)d_in[7];
    const float* page_meta_emb  = (const float*)d_in[8];
    const float* item_emb       = (const float*)d_in[9];
    const float* item_meta_emb  = (const float*)d_in[10];
    const float* item_pre_emb   = (const float*)d_in[11];
    const float* pW             = (const float*)d_in[12];
    const float* pb             = (const float*)d_in[13];
    const float* pg             = (const float*)d_in[14];
    const float* pbeta          = (const float*)d_in[15];
    const float* iW             = (const float*)d_in[16];
    const float* ib             = (const float*)d_in[17];
    const float* ig             = (const float*)d_in[18];
    const float* ibeta          = (const float*)d_in[19];
    const float* norm_g         = (const float*)d_in[20];
    const float* fused_W        = (const float*)d_in[21];
    const float* attn_out_W     = (const float*)d_in[22];
    const float* ff_out_W       = (const float*)d_in[23];
    float* out = (float*)d_out;

    float* ws  = (float*)d_ws;
    float* x    = ws;                                      // 16384*512 f32
    unsigned short* xnh = (unsigned short*)(x + (size_t)NROWS * DIMM);
    unsigned short* xnl = xnh + (size_t)NROWS * DIMM;
    float* qkv = (float*)(xnl + (size_t)NROWS * DIMM);     // 16384*640 f32
    unsigned short* hh   = (unsigned short*)(qkv + (size_t)NROWS * QKVC);
    unsigned short* ctxh = hh + (size_t)NROWS * FFIN;
    float* psum = (float*)(ctxh + (size_t)NROWS * DIMM);
    float* pmax = psum + (size_t)NBATCH * 8 * DIMM;
    unsigned short* WqTh = (unsigned short*)(pmax + (size_t)NBATCH * 8 * DIMM);
    unsigned short* WqTl = WqTh + (size_t)QKVC * DIMM;     // 640x512
    unsigned short* WdTh = WqTl + (size_t)QKVC * DIMM;     // 4096x512 (hi only)
    unsigned short* WaTh = WdTh + (size_t)4096 * DIMM;     // 512x512 (hi only)
    unsigned short* WfTh = WaTh + (size_t)DIMM * DIMM;     // 512x2048 (hi only)
    unsigned short* khb  = WfTh + (size_t)DIMM * FFIN;     // 32x512x64
    unsigned short* klb  = khb + (size_t)NBATCH * SEQ * 64;
    unsigned short* vTb  = klb + (size_t)NBATCH * SEQ * 64; // 32x64x512
    float* cost = (float*)(vTb + (size_t)NBATCH * 64 * SEQ); // 512x32
    float* sint = cost + 512 * 32;
    // q hi/lo alias xnh/xnl (xn dead after dual-silu; rope runs after it)
    unsigned short* qhb = xnh;
    unsigned short* qlb = xnl;

    build_x_k<<<NROWS, 512, 0, stream>>>(
        page_in, item_in, item_meta_in, page_meta_in, pwide, iwide,
        page_emb, page_meta_emb, item_emb, item_meta_emb, item_pre_emb,
        pW, pb, pg, pbeta, iW, ib, ig, ibeta, x);

    trig_k<<<64, 256, 0, stream>>>(cost, sint);

    for (int l = 0; l < 4; ++l) {
        const float* Wf  = fused_W    + (size_t)l * DIMM * NFUSED;
        const float* Wa  = attn_out_W + (size_t)l * DIMM * DIMM;
        const float* Wff = ff_out_W   + (size_t)l * FFIN * DIMM;
        const float* g   = norm_g     + (size_t)l * DIMM;

        ln_k<<<NROWS, 256, 0, stream>>>(x, xnh, xnl, g);

        wconv_k<true><<<dim3(QKVC / 64, DIMM / 64), 256, 0, stream>>>(
            Wf, NFUSED, 0, WqTh, WqTl, DIMM);
        wconv_k<false><<<dim3(4096 / 64, DIMM / 64), 256, 0, stream>>>(
            Wf, NFUSED, 640, WdTh, nullptr, DIMM);
        wconv_k<false><<<dim3(DIMM / 64, DIMM / 64), 256, 0, stream>>>(
            Wa, DIMM, 0, WaTh, nullptr, DIMM);
        wconv_k<false><<<dim3(DIMM / 64, FFIN / 64), 256, 0, stream>>>(
            Wff, DIMM, 0, WfTh, nullptr, FFIN);

        mfma_gemm_k<<<dim3(QKVC / 64, NROWS / 128), 256, 0, stream>>>(
            xnh, xnl, DIMM, WqTh, WqTl, DIMM, DIMM, qkv, QKVC);

        mfma_dual_silu_k<<<dim3(FFIN / 64, NROWS / 128), 256, 0, stream>>>(
            xnh, WdTh, hh);

        // xn dead now; rope writes q hi/lo into its space
        rope_split_k<<<NROWS / 4, 256, 0, stream>>>(
            qkv, cost, sint, qhb, qlb, khb, klb, vTb);

        attn_mfma_k<<<dim3(SEQ / 64, NHEAD, NBATCH), 256, 0, stream>>>(
            qhb, qlb, khb, klb, vTb, ctxh, vl_in);

        mfma_out_k<<<dim3(DIMM / 64, NROWS / 128), 256, 0, stream>>>(
            ctxh, WaTh, hh, WfTh, x);
    }

    pool_part_k<<<dim3(8, NBATCH), 512, 0, stream>>>(x, psum, pmax);
    pool_comb_k<<<NBATCH, 512, 0, stream>>>(psum, pmax, out);
}

// Round 9
// 1330.017 us; speedup vs baseline: 6.9344x; 1.1306x over previous
//
#include <hip/hip_runtime.h>
#include <math.h>

// ---------------------------------------------------------------------------
// ParallelTransformerAEP forward.
// R8: attention masked-tile skip (trip count ceil(VL/64), block-uniform) +
//     __expf (v_exp_f32) in softmax/silu. Rest identical to R7.
// ---------------------------------------------------------------------------

namespace {
constexpr int SEQ    = 512;
constexpr int NBATCH = 32;
constexpr int DIMM   = 512;
constexpr int NHEAD  = 8;
constexpr int FFIN   = 2048;
constexpr int NFUSED = 4736;
constexpr int NROWS  = NBATCH * SEQ;   // 16384
constexpr int QKVC   = 640;            // 512 q + 64 k + 64 v
}

typedef __bf16 bf16x8 __attribute__((ext_vector_type(8)));
typedef float f32x4 __attribute__((ext_vector_type(4)));
typedef unsigned short ushort8 __attribute__((ext_vector_type(8)));

static __device__ __forceinline__ unsigned short bfhi(float v, float* hf) {
    __bf16 h = (__bf16)v;
    *hf = (float)h;
    return __builtin_bit_cast(unsigned short, h);
}
static __device__ __forceinline__ unsigned short bflo(float v, float hf) {
    __bf16 l = (__bf16)(v - hf);
    return __builtin_bit_cast(unsigned short, l);
}

// ------------------------- build x = page * item ---------------------------
__global__ __launch_bounds__(512) void build_x_k(
    const int* __restrict__ page_in, const int* __restrict__ item_in,
    const int* __restrict__ item_meta_in, const int* __restrict__ page_meta_in,
    const float* __restrict__ pwide, const float* __restrict__ iwide,
    const float* __restrict__ page_emb, const float* __restrict__ page_meta_emb,
    const float* __restrict__ item_emb, const float* __restrict__ item_meta_emb,
    const float* __restrict__ item_pre_emb,
    const float* __restrict__ pW, const float* __restrict__ pb,
    const float* __restrict__ pg, const float* __restrict__ pbeta,
    const float* __restrict__ iW, const float* __restrict__ ib,
    const float* __restrict__ ig, const float* __restrict__ ibeta,
    float* __restrict__ x)
{
    const int row = blockIdx.x;
    const int b = row >> 9;
    const int s = row & 511;
    const int d = threadIdx.x;
    const float BNS = 0.9999950000374997f;   // 1/sqrt(1+1e-5)

    float pv, iv;
    if (d < 384) {
        pv = page_emb[(size_t)page_in[row] * 384 + d];
    } else if (d < 448) {
        pv = page_meta_emb[(size_t)page_meta_in[row] * 64 + (d - 384)];
    } else {
        const int dd = d - 448;
        float acc = pb[dd];
        #pragma unroll
        for (int c = 0; c < 8; ++c) {
            float w  = pwide[((size_t)b * 8 + c) * SEQ + s];
            float wn = w * BNS * pg[c] + pbeta[c];
            acc += wn * pW[c * 64 + dd];
        }
        pv = acc > 0.f ? acc : 0.2f * acc;
    }
    if (d < 320) {
        iv = item_emb[(size_t)item_in[row] * 320 + d];
    } else if (d < 384) {
        iv = item_meta_emb[(size_t)item_meta_in[row] * 64 + (d - 320)];
    } else if (d < 448) {
        iv = item_pre_emb[(size_t)item_in[row] * 64 + (d - 384)];
    } else {
        const int dd = d - 448;
        float acc = ib[dd];
        #pragma unroll
        for (int c = 0; c < 8; ++c) {
            float w  = iwide[((size_t)b * 8 + c) * SEQ + s];
            float wn = w * BNS * ig[c] + ibeta[c];
            acc += wn * iW[c * 64 + dd];
        }
        iv = acc > 0.f ? acc : 0.2f * acc;
    }
    x[(size_t)row * DIMM + d] = pv * iv;
}

// ------------------------------ trig table ---------------------------------
__global__ __launch_bounds__(256) void trig_k(float* __restrict__ cost,
                                              float* __restrict__ sint)
{
    const int idx = blockIdx.x * 256 + threadIdx.x;   // 16384 = 512 x 32
    const int s = idx >> 5, j = idx & 31;
    float invf = powf(10000.0f, -(float)j * (1.0f / 32.0f));
    float ang = (float)s * invf;
    float sn, cs;
    sincosf(ang, &sn, &cs);
    cost[idx] = cs;
    sint[idx] = sn;
}

// ------------------------------ LayerNorm -> bf16 hi/lo --------------------
__global__ __launch_bounds__(256) void ln_k(const float* __restrict__ x,
                                            unsigned short* __restrict__ xnh,
                                            unsigned short* __restrict__ xnl,
                                            const float* __restrict__ g)
{
    const int row = blockIdx.x;
    const int t = threadIdx.x;
    const float* xr = x + (size_t)row * DIMM;
    __shared__ float red[4];

    float v0 = xr[t], v1 = xr[t + 256];
    float s = v0 + v1;
    #pragma unroll
    for (int o = 32; o; o >>= 1) s += __shfl_xor(s, o);
    if ((t & 63) == 0) red[t >> 6] = s;
    __syncthreads();
    float mu = (red[0] + red[1] + red[2] + red[3]) * (1.0f / 512.0f);
    __syncthreads();

    float d0 = v0 - mu, d1 = v1 - mu;
    float vs = d0 * d0 + d1 * d1;
    #pragma unroll
    for (int o = 32; o; o >>= 1) vs += __shfl_xor(vs, o);
    if ((t & 63) == 0) red[t >> 6] = vs;
    __syncthreads();
    float var = (red[0] + red[1] + red[2] + red[3]) * (1.0f / 512.0f);
    float r = 1.0f / sqrtf(var + 1e-5f);

    const size_t base = (size_t)row * DIMM;
    float o0 = d0 * r * g[t];
    float o1 = d1 * r * g[t + 256];
    float h0f, h1f;
    xnh[base + t]       = bfhi(o0, &h0f);
    xnh[base + t + 256] = bfhi(o1, &h1f);
    xnl[base + t]       = bflo(o0, h0f);
    xnl[base + t + 256] = bflo(o1, h1f);
}

// ---------------- weight transpose + split: WT[n][k] = W[k][col0+n] --------
// SPLIT: emit hi+lo; else hi only.
template <bool SPLIT>
__global__ __launch_bounds__(256) void wconv_k(const float* __restrict__ W, int ldw,
                                               int col0,
                                               unsigned short* __restrict__ WTh,
                                               unsigned short* __restrict__ WTl,
                                               int ldt)
{
    __shared__ float tile[64][65];
    const int nt = blockIdx.x << 6;
    const int kt = blockIdx.y << 6;
    const int t  = threadIdx.x;

    #pragma unroll
    for (int i = 0; i < 16; ++i) {
        int flat = i * 256 + t;
        int r = flat >> 6, c = flat & 63;
        tile[r][c] = W[(size_t)(kt + r) * ldw + col0 + nt + c];
    }
    __syncthreads();
    #pragma unroll
    for (int i = 0; i < 2; ++i) {
        int flat = i * 256 + t;
        int n = flat >> 3, ck = (flat & 7) << 3;
        ushort8 hv, lv;
        #pragma unroll
        for (int j = 0; j < 8; ++j) {
            float v = tile[ck + j][n];
            float hf;
            hv[j] = bfhi(v, &hf);
            if (SPLIT) lv[j] = bflo(v, hf);
        }
        size_t o = (size_t)(nt + n) * ldt + kt + ck;
        *(ushort8*)&WTh[o] = hv;
        if (SPLIT) *(ushort8*)&WTl[o] = lv;
    }
}

// ----------- RoPE + split: qkv fp32 -> qh/ql [b,h,s,64], kh/kl, vT ---------
__global__ __launch_bounds__(256) void rope_split_k(
    const float* __restrict__ qkv,
    const float* __restrict__ cost, const float* __restrict__ sint,
    unsigned short* __restrict__ qh, unsigned short* __restrict__ ql,
    unsigned short* __restrict__ kh, unsigned short* __restrict__ kl,
    unsigned short* __restrict__ vT)
{
    const int row = (blockIdx.x << 2) + (threadIdx.x >> 6);
    const int b = row >> 9;
    const int s = row & 511;
    const int d = threadIdx.x & 63;
    const int j = d & 31;

    const float cs = cost[s * 32 + j];
    const float sn = sint[s * 32 + j];

    const float* rowp = qkv + (size_t)row * QKVC;
    const int pair = (d < 32) ? d + 32 : d - 32;
    const float sgn = (d < 32) ? -1.f : 1.f;
    float hf;

    // k (rope, no scale)
    float kv = rowp[512 + d];
    float kp = rowp[512 + pair];
    float kr = kv * cs + sgn * kp * sn;
    size_t kidx = ((size_t)b * 512 + s) * 64 + d;
    kh[kidx] = bfhi(kr, &hf);
    kl[kidx] = bflo(kr, hf);

    // v transposed, single bf16
    float vv = rowp[576 + d];
    vT[((size_t)b * 64 + d) * 512 + s] = bfhi(vv, &hf);

    // q per head (rope + 1/sqrt(d) scale)
    #pragma unroll
    for (int h = 0; h < NHEAD; ++h) {
        float qv = rowp[h * 64 + d];
        float qp = rowp[h * 64 + pair];
        float qr = (qv * cs + sgn * qp * sn) * 0.125f;
        size_t qidx = (((size_t)b * 8 + h) * 512 + s) * 64 + d;
        qh[qidx] = bfhi(qr, &hf);
        ql[qidx] = bflo(qr, hf);
    }
}

// -------------- MFMA GEMM (split bf16, 3-product): C_fp32 = A @ B^T --------
__global__ __launch_bounds__(256, 2) void mfma_gemm_k(
    const unsigned short* __restrict__ Ah, const unsigned short* __restrict__ Al,
    int lda,
    const unsigned short* __restrict__ BTh, const unsigned short* __restrict__ BTl,
    int ldb, int K,
    float* __restrict__ C, int ldc)
{
    __shared__ unsigned short sAh[128 * 64];
    __shared__ unsigned short sAl[128 * 64];
    __shared__ unsigned short sBh[64 * 64];
    __shared__ unsigned short sBl[64 * 64];

    const int n0 = blockIdx.x << 6;
    const int m0 = blockIdx.y << 7;
    const int t  = threadIdx.x;
    const int l  = t & 63;
    const int w  = t >> 6;
    const int wm = w >> 1, wn = w & 1;
    const int lr = l & 15, lg = l >> 4;

    f32x4 acc[4][2];
    #pragma unroll
    for (int fm = 0; fm < 4; ++fm)
        #pragma unroll
        for (int fn = 0; fn < 2; ++fn) acc[fm][fn] = (f32x4)0.f;

    for (int k0 = 0; k0 < K; k0 += 64) {
        __syncthreads();
        #pragma unroll
        for (int i = 0; i < 4; ++i) {
            int flat = i * 256 + t;
            int m = flat >> 3, c = flat & 7;
            size_t gidx = (size_t)(m0 + m) * lda + k0 + c * 8;
            int lidx = m * 64 + ((c ^ (m & 7)) << 3);
            *(ushort8*)&sAh[lidx] = *(const ushort8*)&Ah[gidx];
            *(ushort8*)&sAl[lidx] = *(const ushort8*)&Al[gidx];
        }
        #pragma unroll
        for (int i = 0; i < 2; ++i) {
            int flat = i * 256 + t;
            int n = flat >> 3, c = flat & 7;
            size_t gidx = (size_t)(n0 + n) * ldb + k0 + c * 8;
            int lidx = n * 64 + ((c ^ (n & 7)) << 3);
            *(ushort8*)&sBh[lidx] = *(const ushort8*)&BTh[gidx];
            *(ushort8*)&sBl[lidx] = *(const ushort8*)&BTl[gidx];
        }
        __syncthreads();

        #pragma unroll
        for (int kk = 0; kk < 2; ++kk) {
            const int c = kk * 4 + lg;
            bf16x8 afh[4], afl[4];
            #pragma unroll
            for (int fm = 0; fm < 4; ++fm) {
                int m = wm * 64 + fm * 16 + lr;
                int lidx = m * 64 + ((c ^ (m & 7)) << 3);
                afh[fm] = *(bf16x8*)&sAh[lidx];
                afl[fm] = *(bf16x8*)&sAl[lidx];
            }
            bf16x8 bh[2], bl[2];
            #pragma unroll
            for (int fn = 0; fn < 2; ++fn) {
                int n = wn * 32 + fn * 16 + lr;
                int lidx = n * 64 + ((c ^ (n & 7)) << 3);
                bh[fn] = *(bf16x8*)&sBh[lidx];
                bl[fn] = *(bf16x8*)&sBl[lidx];
            }
            #pragma unroll
            for (int fm = 0; fm < 4; ++fm)
                #pragma unroll
                for (int fn = 0; fn < 2; ++fn) {
                    acc[fm][fn] = __builtin_amdgcn_mfma_f32_16x16x32_bf16(afh[fm], bh[fn], acc[fm][fn], 0, 0, 0);
                    acc[fm][fn] = __builtin_amdgcn_mfma_f32_16x16x32_bf16(afh[fm], bl[fn], acc[fm][fn], 0, 0, 0);
                    acc[fm][fn] = __builtin_amdgcn_mfma_f32_16x16x32_bf16(afl[fm], bh[fn], acc[fm][fn], 0, 0, 0);
                }
        }
    }

    #pragma unroll
    for (int fm = 0; fm < 4; ++fm)
        #pragma unroll
        for (int fn = 0; fn < 2; ++fn) {
            const int n = n0 + wn * 32 + fn * 16 + lr;
            #pragma unroll
            for (int r = 0; r < 4; ++r) {
                const int m = m0 + wm * 64 + fm * 16 + lg * 4 + r;
                C[(size_t)m * ldc + n] = acc[fm][fn][r];
            }
        }
}

// ----- MFMA out GEMM: x += ctx@Wa + h@Wff (all single bf16, 2-pass K) ------
__global__ __launch_bounds__(256, 2) void mfma_out_k(
    const unsigned short* __restrict__ A1,
    const unsigned short* __restrict__ B1,
    const unsigned short* __restrict__ A2,
    const unsigned short* __restrict__ B2,
    float* __restrict__ X)
{
    __shared__ unsigned short sA[128 * 64];
    __shared__ unsigned short sB[64 * 64];

    const int n0 = blockIdx.x << 6;
    const int m0 = blockIdx.y << 7;
    const int t  = threadIdx.x;
    const int l  = t & 63;
    const int w  = t >> 6;
    const int wm = w >> 1, wn = w & 1;
    const int lr = l & 15, lg = l >> 4;

    f32x4 acc[4][2];
    #pragma unroll
    for (int fm = 0; fm < 4; ++fm)
        #pragma unroll
        for (int fn = 0; fn < 2; ++fn) acc[fm][fn] = (f32x4)0.f;

    #pragma unroll
    for (int pass = 0; pass < 2; ++pass) {
        const unsigned short* pA = pass ? A2 : A1;
        const unsigned short* pB = pass ? B2 : B1;
        const int lda = pass ? FFIN : DIMM;
        const int KK  = pass ? FFIN : DIMM;

        for (int k0 = 0; k0 < KK; k0 += 64) {
            __syncthreads();
            #pragma unroll
            for (int i = 0; i < 4; ++i) {
                int flat = i * 256 + t;
                int m = flat >> 3, c = flat & 7;
                size_t gidx = (size_t)(m0 + m) * lda + k0 + c * 8;
                int lidx = m * 64 + ((c ^ (m & 7)) << 3);
                *(ushort8*)&sA[lidx] = *(const ushort8*)&pA[gidx];
            }
            #pragma unroll
            for (int i = 0; i < 2; ++i) {
                int flat = i * 256 + t;
                int n = flat >> 3, c = flat & 7;
                size_t gidx = (size_t)(n0 + n) * KK + k0 + c * 8;
                int lidx = n * 64 + ((c ^ (n & 7)) << 3);
                *(ushort8*)&sB[lidx] = *(const ushort8*)&pB[gidx];
            }
            __syncthreads();

            #pragma unroll
            for (int kk = 0; kk < 2; ++kk) {
                const int c = kk * 4 + lg;
                bf16x8 af[4];
                #pragma unroll
                for (int fm = 0; fm < 4; ++fm) {
                    int m = wm * 64 + fm * 16 + lr;
                    int lidx = m * 64 + ((c ^ (m & 7)) << 3);
                    af[fm] = *(bf16x8*)&sA[lidx];
                }
                bf16x8 bf[2];
                #pragma unroll
                for (int fn = 0; fn < 2; ++fn) {
                    int n = wn * 32 + fn * 16 + lr;
                    int lidx = n * 64 + ((c ^ (n & 7)) << 3);
                    bf[fn] = *(bf16x8*)&sB[lidx];
                }
                #pragma unroll
                for (int fm = 0; fm < 4; ++fm)
                    #pragma unroll
                    for (int fn = 0; fn < 2; ++fn)
                        acc[fm][fn] = __builtin_amdgcn_mfma_f32_16x16x32_bf16(af[fm], bf[fn], acc[fm][fn], 0, 0, 0);
            }
        }
    }

    #pragma unroll
    for (int fm = 0; fm < 4; ++fm)
        #pragma unroll
        for (int fn = 0; fn < 2; ++fn) {
            const int n = n0 + wn * 32 + fn * 16 + lr;
            #pragma unroll
            for (int r = 0; r < 4; ++r) {
                const int m = m0 + wm * 64 + fm * 16 + lg * 4 + r;
                X[(size_t)m * DIMM + n] += acc[fm][fn][r];
            }
        }
}

// --- MFMA dual GEMM: h = silu(A@Wg)*(A@Wx), all single bf16 -> bf16 --------
__global__ __launch_bounds__(256, 2) void mfma_dual_silu_k(
    const unsigned short* __restrict__ Ah,
    const unsigned short* __restrict__ WTh,
    unsigned short* __restrict__ Hh)
{
    __shared__ unsigned short sA[128 * 64];
    __shared__ unsigned short sBx[64 * 64];
    __shared__ unsigned short sBg[64 * 64];

    const int n0 = blockIdx.x << 6;
    const int m0 = blockIdx.y << 7;
    const int t  = threadIdx.x;
    const int l  = t & 63;
    const int w  = t >> 6;
    const int wm = w >> 1, wn = w & 1;
    const int lr = l & 15, lg = l >> 4;

    f32x4 accX[4][2], accG[4][2];
    #pragma unroll
    for (int fm = 0; fm < 4; ++fm)
        #pragma unroll
        for (int fn = 0; fn < 2; ++fn) {
            accX[fm][fn] = (f32x4)0.f;
            accG[fm][fn] = (f32x4)0.f;
        }

    for (int k0 = 0; k0 < DIMM; k0 += 64) {
        __syncthreads();
        #pragma unroll
        for (int i = 0; i < 4; ++i) {
            int flat = i * 256 + t;
            int m = flat >> 3, c = flat & 7;
            size_t gidx = (size_t)(m0 + m) * DIMM + k0 + c * 8;
            int lidx = m * 64 + ((c ^ (m & 7)) << 3);
            *(ushort8*)&sA[lidx] = *(const ushort8*)&Ah[gidx];
        }
        #pragma unroll
        for (int i = 0; i < 2; ++i) {
            int flat = i * 256 + t;
            int n = flat >> 3, c = flat & 7;
            size_t gx = (size_t)(n0 + n) * DIMM + k0 + c * 8;
            size_t gg = (size_t)(2048 + n0 + n) * DIMM + k0 + c * 8;
            int lidx = n * 64 + ((c ^ (n & 7)) << 3);
            *(ushort8*)&sBx[lidx] = *(const ushort8*)&WTh[gx];
            *(ushort8*)&sBg[lidx] = *(const ushort8*)&WTh[gg];
        }
        __syncthreads();

        #pragma unroll
        for (int kk = 0; kk < 2; ++kk) {
            const int c = kk * 4 + lg;
            bf16x8 af[4];
            #pragma unroll
            for (int fm = 0; fm < 4; ++fm) {
                int m = wm * 64 + fm * 16 + lr;
                int lidx = m * 64 + ((c ^ (m & 7)) << 3);
                af[fm] = *(bf16x8*)&sA[lidx];
            }
            bf16x8 bx[2], bg[2];
            #pragma unroll
            for (int fn = 0; fn < 2; ++fn) {
                int n = wn * 32 + fn * 16 + lr;
                int lidx = n * 64 + ((c ^ (n & 7)) << 3);
                bx[fn] = *(bf16x8*)&sBx[lidx];
                bg[fn] = *(bf16x8*)&sBg[lidx];
            }
            #pragma unroll
            for (int fm = 0; fm < 4; ++fm)
                #pragma unroll
                for (int fn = 0; fn < 2; ++fn) {
                    accX[fm][fn] = __builtin_amdgcn_mfma_f32_16x16x32_bf16(af[fm], bx[fn], accX[fm][fn], 0, 0, 0);
                    accG[fm][fn] = __builtin_amdgcn_mfma_f32_16x16x32_bf16(af[fm], bg[fn], accG[fm][fn], 0, 0, 0);
                }
        }
    }

    #pragma unroll
    for (int fm = 0; fm < 4; ++fm)
        #pragma unroll
        for (int fn = 0; fn < 2; ++fn) {
            const int n = n0 + wn * 32 + fn * 16 + lr;
            #pragma unroll
            for (int r = 0; r < 4; ++r) {
                const int m = m0 + wm * 64 + fm * 16 + lg * 4 + r;
                float gv = accG[fm][fn][r];
                float xv = accX[fm][fn][r];
                float sig = 1.0f / (1.0f + __expf(-gv));
                float hv = gv * sig * xv;
                float hf;
                Hh[(size_t)m * FFIN + n] = bfhi(hv, &hf);
            }
        }
}

// ------------------- attention: MFMA flash (per b,h,64 q-rows) -------------
// Masked-tile skip: trip count ceil(VL/64), uniform per block (VL per batch).
__global__ __launch_bounds__(256) void attn_mfma_k(
    const unsigned short* __restrict__ qh, const unsigned short* __restrict__ ql,
    const unsigned short* __restrict__ kh, const unsigned short* __restrict__ kl,
    const unsigned short* __restrict__ vT,
    unsigned short* __restrict__ ctxh,
    const int* __restrict__ vl)
{
    __shared__ unsigned short sKh[64 * 64];
    __shared__ unsigned short sKl[64 * 64];
    __shared__ unsigned short sVT[64 * 64];
    __shared__ unsigned short sP[64 * 64];

    const int i0 = blockIdx.x << 6;
    const int h  = blockIdx.y;
    const int b  = blockIdx.z;
    const int t  = threadIdx.x;
    const int l  = t & 63;
    const int w  = t >> 6;
    const int lr = l & 15, lg = l >> 4;
    const int VL = vl[b];
    const int ntiles = (VL + 63) >> 6;   // fully-masked tiles contribute 0

    bf16x8 qfh[2], qfl[2];
    {
        size_t base = (((size_t)(b * 8 + h) * 512) + i0 + w * 16 + lr) * 64 + lg * 8;
        qfh[0] = *(const bf16x8*)&qh[base];
        qfh[1] = *(const bf16x8*)&qh[base + 32];
        qfl[0] = *(const bf16x8*)&ql[base];
        qfl[1] = *(const bf16x8*)&ql[base + 32];
    }

    float mrow[4], lrow[4];
    f32x4 oacc[4];
    #pragma unroll
    for (int r = 0; r < 4; ++r) { mrow[r] = -3.0e38f; lrow[r] = 0.f; }
    #pragma unroll
    for (int nb = 0; nb < 4; ++nb) oacc[nb] = (f32x4)0.f;

    for (int jt = 0; jt < ntiles; ++jt) {
        const int j0 = jt << 6;
        __syncthreads();
        #pragma unroll
        for (int i = 0; i < 2; ++i) {
            int flat = i * 256 + t;
            int m = flat >> 3, c = flat & 7;
            int lidx = m * 64 + ((c ^ (m & 7)) << 3);
            size_t kg = ((size_t)b * 512 + j0 + m) * 64 + c * 8;
            *(ushort8*)&sKh[lidx] = *(const ushort8*)&kh[kg];
            *(ushort8*)&sKl[lidx] = *(const ushort8*)&kl[kg];
            size_t vg = ((size_t)b * 64 + m) * 512 + j0 + c * 8;
            *(ushort8*)&sVT[lidx] = *(const ushort8*)&vT[vg];
        }
        __syncthreads();

        f32x4 accS[4];
        #pragma unroll
        for (int nb = 0; nb < 4; ++nb) accS[nb] = (f32x4)0.f;
        #pragma unroll
        for (int ks = 0; ks < 2; ++ks) {
            const int c = ks * 4 + lg;
            #pragma unroll
            for (int nb = 0; nb < 4; ++nb) {
                int n = nb * 16 + lr;
                int lidx = n * 64 + ((c ^ (n & 7)) << 3);
                bf16x8 kfh = *(bf16x8*)&sKh[lidx];
                bf16x8 kfl = *(bf16x8*)&sKl[lidx];
                accS[nb] = __builtin_amdgcn_mfma_f32_16x16x32_bf16(qfh[ks], kfh, accS[nb], 0, 0, 0);
                accS[nb] = __builtin_amdgcn_mfma_f32_16x16x32_bf16(qfh[ks], kfl, accS[nb], 0, 0, 0);
                accS[nb] = __builtin_amdgcn_mfma_f32_16x16x32_bf16(qfl[ks], kfh, accS[nb], 0, 0, 0);
            }
        }

        #pragma unroll
        for (int nb = 0; nb < 4; ++nb) {
            if (j0 + nb * 16 + lr >= VL) {
                #pragma unroll
                for (int r = 0; r < 4; ++r) accS[nb][r] = -3.0e38f;
            }
        }

        #pragma unroll
        for (int r = 0; r < 4; ++r) {
            float rm = fmaxf(fmaxf(accS[0][r], accS[1][r]), fmaxf(accS[2][r], accS[3][r]));
            #pragma unroll
            for (int off = 8; off; off >>= 1) rm = fmaxf(rm, __shfl_xor(rm, off));
            float nm = fmaxf(mrow[r], rm);
            float scl = __expf(mrow[r] - nm);
            mrow[r] = nm;
            float ps = 0.f;
            #pragma unroll
            for (int nb = 0; nb < 4; ++nb) {
                float p = __expf(accS[nb][r] - nm);
                accS[nb][r] = p;
                ps += p;
            }
            lrow[r] = lrow[r] * scl + ps;
            #pragma unroll
            for (int nb = 0; nb < 4; ++nb) oacc[nb][r] *= scl;
        }

        #pragma unroll
        for (int nb = 0; nb < 4; ++nb) {
            int cc = nb * 2 + (lr >> 3);
            #pragma unroll
            for (int r = 0; r < 4; ++r) {
                int q = w * 16 + lg * 4 + r;
                int lidx = q * 64 + ((cc ^ (q & 7)) << 3) + (lr & 7);
                float hf2;
                sP[lidx] = bfhi(accS[nb][r], &hf2);
            }
        }

        #pragma unroll
        for (int ks = 0; ks < 2; ++ks) {
            const int c = ks * 4 + lg;
            int qrow = w * 16 + lr;
            int plidx = qrow * 64 + ((c ^ (qrow & 7)) << 3);
            bf16x8 pf = *(bf16x8*)&sP[plidx];
            #pragma unroll
            for (int nb = 0; nb < 4; ++nb) {
                int n = nb * 16 + lr;
                int lidx = n * 64 + ((c ^ (n & 7)) << 3);
                bf16x8 vf = *(bf16x8*)&sVT[lidx];
                oacc[nb] = __builtin_amdgcn_mfma_f32_16x16x32_bf16(pf, vf, oacc[nb], 0, 0, 0);
            }
        }
    }

    #pragma unroll
    for (int r = 0; r < 4; ++r) {
        float lt = lrow[r];
        #pragma unroll
        for (int off = 8; off; off >>= 1) lt += __shfl_xor(lt, off);
        float inv = 1.0f / lt;
        const int row = (b << 9) + i0 + w * 16 + lg * 4 + r;
        const size_t base = (size_t)row * DIMM + h * 64;
        #pragma unroll
        for (int nb = 0; nb < 4; ++nb) {
            float v = oacc[nb][r] * inv;
            float hf;
            ctxh[base + nb * 16 + lr] = bfhi(v, &hf);
        }
    }
}

// ------------------------------ pool ---------------------------------------
__global__ __launch_bounds__(512) void pool_part_k(const float* __restrict__ x,
                                                   float* __restrict__ psum,
                                                   float* __restrict__ pmax)
{
    const int seg = blockIdx.x;
    const int b   = blockIdx.y;
    const int d   = threadIdx.x;
    const float* xb = x + ((size_t)(b << 9) + (seg << 6)) * DIMM;
    float s = 0.f, m = -3.0e38f;
    for (int i = 0; i < 64; ++i) {
        float v = xb[(size_t)i * DIMM + d];
        s += v;
        m = fmaxf(m, v);
    }
    psum[((size_t)b * 8 + seg) * DIMM + d] = s;
    pmax[((size_t)b * 8 + seg) * DIMM + d] = m;
}

__global__ __launch_bounds__(512) void pool_comb_k(const float* __restrict__ psum,
                                                   const float* __restrict__ pmax,
                                                   float* __restrict__ out)
{
    const int b = blockIdx.x;
    const int d = threadIdx.x;
    float s = 0.f, m = -3.0e38f;
    #pragma unroll
    for (int seg = 0; seg < 8; ++seg) {
        s += psum[((size_t)b * 8 + seg) * DIMM + d];
        m = fmaxf(m, pmax[((size_t)b * 8 + seg) * DIMM + d]);
    }
    out[b * 1024 + d] = s * (1.0f / 512.0f);
    out[b * 1024 + 512 + d] = m;
}

// ---------------------------------------------------------------------------
extern "C" void kernel_launch(void* const* d_in, const int* in_sizes, int n_in,
                              void* d_out, int out_size, void* d_ws, size_t ws_size,
                              hipStream_t stream)
{
    const int*   page_in        = (const int*)d_in[0];
    const int*   item_in        = (const int*)d_in[1];
    const int*   item_meta_in   = (const int*)d_in[2];
    const int*   vl_in          = (const int*)d_in[3];
    const int*   page_meta_in   = (const int*)d_in[4];
    const float* pwide          = (const float*)d_in[5];
    const float* iwide          = (const float*)d_in[6];
    const float* page_emb       = (const float*)d_in[7];
    const float* page_meta_emb  = (const float*)d_in[8];
    const float* item_emb       = (const float*)d_in[9];
    const float* item_meta_emb  = (const float*)d_in[10];
    const float* item_pre_emb   = (const float*)d_in[11];
    const float* pW             = (const float*)d_in[12];
    const float* pb             = (const float*)d_in[13];
    const float* pg             = (const float*)d_in[14];
    const float* pbeta          = (const float*)d_in[15];
    const float* iW             = (const float*)d_in[16];
    const float* ib             = (const float*)d_in[17];
    const float* ig             = (const float*)d_in[18];
    const float* ibeta          = (const float*)d_in[19];
    const float* norm_g         = (const float*)d_in[20];
    const float* fused_W        = (const float*)d_in[21];
    const float* attn_out_W     = (const float*)d_in[22];
    const float* ff_out_W       = (const float*)d_in[23];
    float* out = (float*)d_out;

    float* ws  = (float*)d_ws;
    float* x    = ws;                                      // 16384*512 f32
    unsigned short* xnh = (unsigned short*)(x + (size_t)NROWS * DIMM);
    unsigned short* xnl = xnh + (size_t)NROWS * DIMM;
    float* qkv = (float*)(xnl + (size_t)NROWS * DIMM);     // 16384*640 f32
    unsigned short* hh   = (unsigned short*)(qkv + (size_t)NROWS * QKVC);
    unsigned short* ctxh = hh + (size_t)NROWS * FFIN;
    float* psum = (float*)(ctxh + (size_t)NROWS * DIMM);
    float* pmax = psum + (size_t)NBATCH * 8 * DIMM;
    unsigned short* WqTh = (unsigned short*)(pmax + (size_t)NBATCH * 8 * DIMM);
    unsigned short* WqTl = WqTh + (size_t)QKVC * DIMM;     // 640x512
    unsigned short* WdTh = WqTl + (size_t)QKVC * DIMM;     // 4096x512 (hi only)
    unsigned short* WaTh = WdTh + (size_t)4096 * DIMM;     // 512x512 (hi only)
    unsigned short* WfTh = WaTh + (size_t)DIMM * DIMM;     // 512x2048 (hi only)
    unsigned short* khb  = WfTh + (size_t)DIMM * FFIN;     // 32x512x64
    unsigned short* klb  = khb + (size_t)NBATCH * SEQ * 64;
    unsigned short* vTb  = klb + (size_t)NBATCH * SEQ * 64; // 32x64x512
    float* cost = (float*)(vTb + (size_t)NBATCH * 64 * SEQ); // 512x32
    float* sint = cost + 512 * 32;
    // q hi/lo alias xnh/xnl (xn dead after dual-silu; rope runs after it)
    unsigned short* qhb = xnh;
    unsigned short* qlb = xnl;

    build_x_k<<<NROWS, 512, 0, stream>>>(
        page_in, item_in, item_meta_in, page_meta_in, pwide, iwide,
        page_emb, page_meta_emb, item_emb, item_meta_emb, item_pre_emb,
        pW, pb, pg, pbeta, iW, ib, ig, ibeta, x);

    trig_k<<<64, 256, 0, stream>>>(cost, sint);

    for (int l = 0; l < 4; ++l) {
        const float* Wf  = fused_W    + (size_t)l * DIMM * NFUSED;
        const float* Wa  = attn_out_W + (size_t)l * DIMM * DIMM;
        const float* Wff = ff_out_W   + (size_t)l * FFIN * DIMM;
        const float* g   = norm_g     + (size_t)l * DIMM;

        ln_k<<<NROWS, 256, 0, stream>>>(x, xnh, xnl, g);

        wconv_k<true><<<dim3(QKVC / 64, DIMM / 64), 256, 0, stream>>>(
            Wf, NFUSED, 0, WqTh, WqTl, DIMM);
        wconv_k<false><<<dim3(4096 / 64, DIMM / 64), 256, 0, stream>>>(
            Wf, NFUSED, 640, WdTh, nullptr, DIMM);
        wconv_k<false><<<dim3(DIMM / 64, DIMM / 64), 256, 0, stream>>>(
            Wa, DIMM, 0, WaTh, nullptr, DIMM);
        wconv_k<false><<<dim3(DIMM / 64, FFIN / 64), 256, 0, stream>>>(
            Wff, DIMM, 0, WfTh, nullptr, FFIN);

        mfma_gemm_k<<<dim3(QKVC / 64, NROWS / 128), 256, 0, stream>>>(
            xnh, xnl, DIMM, WqTh, WqTl, DIMM, DIMM, qkv, QKVC);

        mfma_dual_silu_k<<<dim3(FFIN / 64, NROWS / 128), 256, 0, stream>>>(
            xnh, WdTh, hh);

        // xn dead now; rope writes q hi/lo into its space
        rope_split_k<<<NROWS / 4, 256, 0, stream>>>(
            qkv, cost, sint, qhb, qlb, khb, klb, vTb);

        attn_mfma_k<<<dim3(SEQ / 64, NHEAD, NBATCH), 256, 0, stream>>>(
            qhb, qlb, khb, klb, vTb, ctxh, vl_in);

        mfma_out_k<<<dim3(DIMM / 64, NROWS / 128), 256, 0, stream>>>(
            ctxh, WaTh, hh, WfTh, x);
    }

    pool_part_k<<<dim3(8, NBATCH), 512, 0, stream>>>(x, psum, pmax);
    pool_comb_k<<<NBATCH, 512, 0, stream>>>(psum, pmax, out);
}

// Round 11
// 1159.690 us; speedup vs baseline: 7.9529x; 1.1469x over previous
//
#include <hip/hip_runtime.h>
#include <math.h>

// ---------------------------------------------------------------------------
// ParallelTransformerAEP forward.
// R10: resubmit of R9 (container was unresponsive; kernel never measured).
// R9: out-GEMM retiled BM=64 x BN=256 (grid 2x256) to cut h over-fetch
//     (8x -> 2x logical reads). Rest identical to R8.
// ---------------------------------------------------------------------------

namespace {
constexpr int SEQ    = 512;
constexpr int NBATCH = 32;
constexpr int DIMM   = 512;
constexpr int NHEAD  = 8;
constexpr int FFIN   = 2048;
constexpr int NFUSED = 4736;
constexpr int NROWS  = NBATCH * SEQ;   // 16384
constexpr int QKVC   = 640;            // 512 q + 64 k + 64 v
}

typedef __bf16 bf16x8 __attribute__((ext_vector_type(8)));
typedef float f32x4 __attribute__((ext_vector_type(4)));
typedef unsigned short ushort8 __attribute__((ext_vector_type(8)));

static __device__ __forceinline__ unsigned short bfhi(float v, float* hf) {
    __bf16 h = (__bf16)v;
    *hf = (float)h;
    return __builtin_bit_cast(unsigned short, h);
}
static __device__ __forceinline__ unsigned short bflo(float v, float hf) {
    __bf16 l = (__bf16)(v - hf);
    return __builtin_bit_cast(unsigned short, l);
}

// ------------------------- build x = page * item ---------------------------
__global__ __launch_bounds__(512) void build_x_k(
    const int* __restrict__ page_in, const int* __restrict__ item_in,
    const int* __restrict__ item_meta_in, const int* __restrict__ page_meta_in,
    const float* __restrict__ pwide, const float* __restrict__ iwide,
    const float* __restrict__ page_emb, const float* __restrict__ page_meta_emb,
    const float* __restrict__ item_emb, const float* __restrict__ item_meta_emb,
    const float* __restrict__ item_pre_emb,
    const float* __restrict__ pW, const float* __restrict__ pb,
    const float* __restrict__ pg, const float* __restrict__ pbeta,
    const float* __restrict__ iW, const float* __restrict__ ib,
    const float* __restrict__ ig, const float* __restrict__ ibeta,
    float* __restrict__ x)
{
    const int row = blockIdx.x;
    const int b = row >> 9;
    const int s = row & 511;
    const int d = threadIdx.x;
    const float BNS = 0.9999950000374997f;   // 1/sqrt(1+1e-5)

    float pv, iv;
    if (d < 384) {
        pv = page_emb[(size_t)page_in[row] * 384 + d];
    } else if (d < 448) {
        pv = page_meta_emb[(size_t)page_meta_in[row] * 64 + (d - 384)];
    } else {
        const int dd = d - 448;
        float acc = pb[dd];
        #pragma unroll
        for (int c = 0; c < 8; ++c) {
            float w  = pwide[((size_t)b * 8 + c) * SEQ + s];
            float wn = w * BNS * pg[c] + pbeta[c];
            acc += wn * pW[c * 64 + dd];
        }
        pv = acc > 0.f ? acc : 0.2f * acc;
    }
    if (d < 320) {
        iv = item_emb[(size_t)item_in[row] * 320 + d];
    } else if (d < 384) {
        iv = item_meta_emb[(size_t)item_meta_in[row] * 64 + (d - 320)];
    } else if (d < 448) {
        iv = item_pre_emb[(size_t)item_in[row] * 64 + (d - 384)];
    } else {
        const int dd = d - 448;
        float acc = ib[dd];
        #pragma unroll
        for (int c = 0; c < 8; ++c) {
            float w  = iwide[((size_t)b * 8 + c) * SEQ + s];
            float wn = w * BNS * ig[c] + ibeta[c];
            acc += wn * iW[c * 64 + dd];
        }
        iv = acc > 0.f ? acc : 0.2f * acc;
    }
    x[(size_t)row * DIMM + d] = pv * iv;
}

// ------------------------------ trig table ---------------------------------
__global__ __launch_bounds__(256) void trig_k(float* __restrict__ cost,
                                              float* __restrict__ sint)
{
    const int idx = blockIdx.x * 256 + threadIdx.x;   // 16384 = 512 x 32
    const int s = idx >> 5, j = idx & 31;
    float invf = powf(10000.0f, -(float)j * (1.0f / 32.0f));
    float ang = (float)s * invf;
    float sn, cs;
    sincosf(ang, &sn, &cs);
    cost[idx] = cs;
    sint[idx] = sn;
}

// ------------------------------ LayerNorm -> bf16 hi/lo --------------------
__global__ __launch_bounds__(256) void ln_k(const float* __restrict__ x,
                                            unsigned short* __restrict__ xnh,
                                            unsigned short* __restrict__ xnl,
                                            const float* __restrict__ g)
{
    const int row = blockIdx.x;
    const int t = threadIdx.x;
    const float* xr = x + (size_t)row * DIMM;
    __shared__ float red[4];

    float v0 = xr[t], v1 = xr[t + 256];
    float s = v0 + v1;
    #pragma unroll
    for (int o = 32; o; o >>= 1) s += __shfl_xor(s, o);
    if ((t & 63) == 0) red[t >> 6] = s;
    __syncthreads();
    float mu = (red[0] + red[1] + red[2] + red[3]) * (1.0f / 512.0f);
    __syncthreads();

    float d0 = v0 - mu, d1 = v1 - mu;
    float vs = d0 * d0 + d1 * d1;
    #pragma unroll
    for (int o = 32; o; o >>= 1) vs += __shfl_xor(vs, o);
    if ((t & 63) == 0) red[t >> 6] = vs;
    __syncthreads();
    float var = (red[0] + red[1] + red[2] + red[3]) * (1.0f / 512.0f);
    float r = 1.0f / sqrtf(var + 1e-5f);

    const size_t base = (size_t)row * DIMM;
    float o0 = d0 * r * g[t];
    float o1 = d1 * r * g[t + 256];
    float h0f, h1f;
    xnh[base + t]       = bfhi(o0, &h0f);
    xnh[base + t + 256] = bfhi(o1, &h1f);
    xnl[base + t]       = bflo(o0, h0f);
    xnl[base + t + 256] = bflo(o1, h1f);
}

// ---------------- weight transpose + split: WT[n][k] = W[k][col0+n] --------
// SPLIT: emit hi+lo; else hi only.
template <bool SPLIT>
__global__ __launch_bounds__(256) void wconv_k(const float* __restrict__ W, int ldw,
                                               int col0,
                                               unsigned short* __restrict__ WTh,
                                               unsigned short* __restrict__ WTl,
                                               int ldt)
{
    __shared__ float tile[64][65];
    const int nt = blockIdx.x << 6;
    const int kt = blockIdx.y << 6;
    const int t  = threadIdx.x;

    #pragma unroll
    for (int i = 0; i < 16; ++i) {
        int flat = i * 256 + t;
        int r = flat >> 6, c = flat & 63;
        tile[r][c] = W[(size_t)(kt + r) * ldw + col0 + nt + c];
    }
    __syncthreads();
    #pragma unroll
    for (int i = 0; i < 2; ++i) {
        int flat = i * 256 + t;
        int n = flat >> 3, ck = (flat & 7) << 3;
        ushort8 hv, lv;
        #pragma unroll
        for (int j = 0; j < 8; ++j) {
            float v = tile[ck + j][n];
            float hf;
            hv[j] = bfhi(v, &hf);
            if (SPLIT) lv[j] = bflo(v, hf);
        }
        size_t o = (size_t)(nt + n) * ldt + kt + ck;
        *(ushort8*)&WTh[o] = hv;
        if (SPLIT) *(ushort8*)&WTl[o] = lv;
    }
}

// ----------- RoPE + split: qkv fp32 -> qh/ql [b,h,s,64], kh/kl, vT ---------
__global__ __launch_bounds__(256) void rope_split_k(
    const float* __restrict__ qkv,
    const float* __restrict__ cost, const float* __restrict__ sint,
    unsigned short* __restrict__ qh, unsigned short* __restrict__ ql,
    unsigned short* __restrict__ kh, unsigned short* __restrict__ kl,
    unsigned short* __restrict__ vT)
{
    const int row = (blockIdx.x << 2) + (threadIdx.x >> 6);
    const int b = row >> 9;
    const int s = row & 511;
    const int d = threadIdx.x & 63;
    const int j = d & 31;

    const float cs = cost[s * 32 + j];
    const float sn = sint[s * 32 + j];

    const float* rowp = qkv + (size_t)row * QKVC;
    const int pair = (d < 32) ? d + 32 : d - 32;
    const float sgn = (d < 32) ? -1.f : 1.f;
    float hf;

    // k (rope, no scale)
    float kv = rowp[512 + d];
    float kp = rowp[512 + pair];
    float kr = kv * cs + sgn * kp * sn;
    size_t kidx = ((size_t)b * 512 + s) * 64 + d;
    kh[kidx] = bfhi(kr, &hf);
    kl[kidx] = bflo(kr, hf);

    // v transposed, single bf16
    float vv = rowp[576 + d];
    vT[((size_t)b * 64 + d) * 512 + s] = bfhi(vv, &hf);

    // q per head (rope + 1/sqrt(d) scale)
    #pragma unroll
    for (int h = 0; h < NHEAD; ++h) {
        float qv = rowp[h * 64 + d];
        float qp = rowp[h * 64 + pair];
        float qr = (qv * cs + sgn * qp * sn) * 0.125f;
        size_t qidx = (((size_t)b * 8 + h) * 512 + s) * 64 + d;
        qh[qidx] = bfhi(qr, &hf);
        ql[qidx] = bflo(qr, hf);
    }
}

// -------------- MFMA GEMM (split bf16, 3-product): C_fp32 = A @ B^T --------
__global__ __launch_bounds__(256, 2) void mfma_gemm_k(
    const unsigned short* __restrict__ Ah, const unsigned short* __restrict__ Al,
    int lda,
    const unsigned short* __restrict__ BTh, const unsigned short* __restrict__ BTl,
    int ldb, int K,
    float* __restrict__ C, int ldc)
{
    __shared__ unsigned short sAh[128 * 64];
    __shared__ unsigned short sAl[128 * 64];
    __shared__ unsigned short sBh[64 * 64];
    __shared__ unsigned short sBl[64 * 64];

    const int n0 = blockIdx.x << 6;
    const int m0 = blockIdx.y << 7;
    const int t  = threadIdx.x;
    const int l  = t & 63;
    const int w  = t >> 6;
    const int wm = w >> 1, wn = w & 1;
    const int lr = l & 15, lg = l >> 4;

    f32x4 acc[4][2];
    #pragma unroll
    for (int fm = 0; fm < 4; ++fm)
        #pragma unroll
        for (int fn = 0; fn < 2; ++fn) acc[fm][fn] = (f32x4)0.f;

    for (int k0 = 0; k0 < K; k0 += 64) {
        __syncthreads();
        #pragma unroll
        for (int i = 0; i < 4; ++i) {
            int flat = i * 256 + t;
            int m = flat >> 3, c = flat & 7;
            size_t gidx = (size_t)(m0 + m) * lda + k0 + c * 8;
            int lidx = m * 64 + ((c ^ (m & 7)) << 3);
            *(ushort8*)&sAh[lidx] = *(const ushort8*)&Ah[gidx];
            *(ushort8*)&sAl[lidx] = *(const ushort8*)&Al[gidx];
        }
        #pragma unroll
        for (int i = 0; i < 2; ++i) {
            int flat = i * 256 + t;
            int n = flat >> 3, c = flat & 7;
            size_t gidx = (size_t)(n0 + n) * ldb + k0 + c * 8;
            int lidx = n * 64 + ((c ^ (n & 7)) << 3);
            *(ushort8*)&sBh[lidx] = *(const ushort8*)&BTh[gidx];
            *(ushort8*)&sBl[lidx] = *(const ushort8*)&BTl[gidx];
        }
        __syncthreads();

        #pragma unroll
        for (int kk = 0; kk < 2; ++kk) {
            const int c = kk * 4 + lg;
            bf16x8 afh[4], afl[4];
            #pragma unroll
            for (int fm = 0; fm < 4; ++fm) {
                int m = wm * 64 + fm * 16 + lr;
                int lidx = m * 64 + ((c ^ (m & 7)) << 3);
                afh[fm] = *(bf16x8*)&sAh[lidx];
                afl[fm] = *(bf16x8*)&sAl[lidx];
            }
            bf16x8 bh[2], bl[2];
            #pragma unroll
            for (int fn = 0; fn < 2; ++fn) {
                int n = wn * 32 + fn * 16 + lr;
                int lidx = n * 64 + ((c ^ (n & 7)) << 3);
                bh[fn] = *(bf16x8*)&sBh[lidx];
                bl[fn] = *(bf16x8*)&sBl[lidx];
            }
            #pragma unroll
            for (int fm = 0; fm < 4; ++fm)
                #pragma unroll
                for (int fn = 0; fn < 2; ++fn) {
                    acc[fm][fn] = __builtin_amdgcn_mfma_f32_16x16x32_bf16(afh[fm], bh[fn], acc[fm][fn], 0, 0, 0);
                    acc[fm][fn] = __builtin_amdgcn_mfma_f32_16x16x32_bf16(afh[fm], bl[fn], acc[fm][fn], 0, 0, 0);
                    acc[fm][fn] = __builtin_amdgcn_mfma_f32_16x16x32_bf16(afl[fm], bh[fn], acc[fm][fn], 0, 0, 0);
                }
        }
    }

    #pragma unroll
    for (int fm = 0; fm < 4; ++fm)
        #pragma unroll
        for (int fn = 0; fn < 2; ++fn) {
            const int n = n0 + wn * 32 + fn * 16 + lr;
            #pragma unroll
            for (int r = 0; r < 4; ++r) {
                const int m = m0 + wm * 64 + fm * 16 + lg * 4 + r;
                C[(size_t)m * ldc + n] = acc[fm][fn][r];
            }
        }
}

// ----- MFMA out GEMM: x += ctx@Wa + h@Wff (single bf16, 2-pass K) ----------
// BM=64 x BN=256, grid (2, NROWS/64). 4 waves, each 64x64 output.
__global__ __launch_bounds__(256, 2) void mfma_out_k(
    const unsigned short* __restrict__ A1,
    const unsigned short* __restrict__ B1,
    const unsigned short* __restrict__ A2,
    const unsigned short* __restrict__ B2,
    float* __restrict__ X)
{
    __shared__ unsigned short sA[64 * 64];
    __shared__ unsigned short sB[256 * 64];

    const int n0 = blockIdx.x << 8;
    const int m0 = blockIdx.y << 6;
    const int t  = threadIdx.x;
    const int l  = t & 63;
    const int w  = t >> 6;
    const int lr = l & 15, lg = l >> 4;

    f32x4 acc[4][4];
    #pragma unroll
    for (int fm = 0; fm < 4; ++fm)
        #pragma unroll
        for (int fn = 0; fn < 4; ++fn) acc[fm][fn] = (f32x4)0.f;

    #pragma unroll
    for (int pass = 0; pass < 2; ++pass) {
        const unsigned short* pA = pass ? A2 : A1;
        const unsigned short* pB = pass ? B2 : B1;
        const int lda = pass ? FFIN : DIMM;
        const int KK  = pass ? FFIN : DIMM;

        for (int k0 = 0; k0 < KK; k0 += 64) {
            __syncthreads();
            // A: 64 rows x 8 chunks = 512
            #pragma unroll
            for (int i = 0; i < 2; ++i) {
                int flat = i * 256 + t;
                int m = flat >> 3, c = flat & 7;
                size_t gidx = (size_t)(m0 + m) * lda + k0 + c * 8;
                int lidx = m * 64 + ((c ^ (m & 7)) << 3);
                *(ushort8*)&sA[lidx] = *(const ushort8*)&pA[gidx];
            }
            // B: 256 rows x 8 chunks = 2048
            #pragma unroll
            for (int i = 0; i < 8; ++i) {
                int flat = i * 256 + t;
                int n = flat >> 3, c = flat & 7;
                size_t gidx = (size_t)(n0 + n) * KK + k0 + c * 8;
                int lidx = n * 64 + ((c ^ (n & 7)) << 3);
                *(ushort8*)&sB[lidx] = *(const ushort8*)&pB[gidx];
            }
            __syncthreads();

            #pragma unroll
            for (int kk = 0; kk < 2; ++kk) {
                const int c = kk * 4 + lg;
                bf16x8 af[4];
                #pragma unroll
                for (int fm = 0; fm < 4; ++fm) {
                    int m = fm * 16 + lr;
                    int lidx = m * 64 + ((c ^ (m & 7)) << 3);
                    af[fm] = *(bf16x8*)&sA[lidx];
                }
                bf16x8 bf[4];
                #pragma unroll
                for (int fn = 0; fn < 4; ++fn) {
                    int n = w * 64 + fn * 16 + lr;
                    int lidx = n * 64 + ((c ^ (n & 7)) << 3);
                    bf[fn] = *(bf16x8*)&sB[lidx];
                }
                #pragma unroll
                for (int fm = 0; fm < 4; ++fm)
                    #pragma unroll
                    for (int fn = 0; fn < 4; ++fn)
                        acc[fm][fn] = __builtin_amdgcn_mfma_f32_16x16x32_bf16(af[fm], bf[fn], acc[fm][fn], 0, 0, 0);
            }
        }
    }

    #pragma unroll
    for (int fm = 0; fm < 4; ++fm)
        #pragma unroll
        for (int fn = 0; fn < 4; ++fn) {
            const int n = n0 + w * 64 + fn * 16 + lr;
            #pragma unroll
            for (int r = 0; r < 4; ++r) {
                const int m = m0 + fm * 16 + lg * 4 + r;
                X[(size_t)m * DIMM + n] += acc[fm][fn][r];
            }
        }
}

// --- MFMA dual GEMM: h = silu(A@Wg)*(A@Wx), all single bf16 -> bf16 --------
__global__ __launch_bounds__(256, 2) void mfma_dual_silu_k(
    const unsigned short* __restrict__ Ah,
    const unsigned short* __restrict__ WTh,
    unsigned short* __restrict__ Hh)
{
    __shared__ unsigned short sA[128 * 64];
    __shared__ unsigned short sBx[64 * 64];
    __shared__ unsigned short sBg[64 * 64];

    const int n0 = blockIdx.x << 6;
    const int m0 = blockIdx.y << 7;
    const int t  = threadIdx.x;
    const int l  = t & 63;
    const int w  = t >> 6;
    const int wm = w >> 1, wn = w & 1;
    const int lr = l & 15, lg = l >> 4;

    f32x4 accX[4][2], accG[4][2];
    #pragma unroll
    for (int fm = 0; fm < 4; ++fm)
        #pragma unroll
        for (int fn = 0; fn < 2; ++fn) {
            accX[fm][fn] = (f32x4)0.f;
            accG[fm][fn] = (f32x4)0.f;
        }

    for (int k0 = 0; k0 < DIMM; k0 += 64) {
        __syncthreads();
        #pragma unroll
        for (int i = 0; i < 4; ++i) {
            int flat = i * 256 + t;
            int m = flat >> 3, c = flat & 7;
            size_t gidx = (size_t)(m0 + m) * DIMM + k0 + c * 8;
            int lidx = m * 64 + ((c ^ (m & 7)) << 3);
            *(ushort8*)&sA[lidx] = *(const ushort8*)&Ah[gidx];
        }
        #pragma unroll
        for (int i = 0; i < 2; ++i) {
            int flat = i * 256 + t;
            int n = flat >> 3, c = flat & 7;
            size_t gx = (size_t)(n0 + n) * DIMM + k0 + c * 8;
            size_t gg = (size_t)(2048 + n0 + n) * DIMM + k0 + c * 8;
            int lidx = n * 64 + ((c ^ (n & 7)) << 3);
            *(ushort8*)&sBx[lidx] = *(const ushort8*)&WTh[gx];
            *(ushort8*)&sBg[lidx] = *(const ushort8*)&WTh[gg];
        }
        __syncthreads();

        #pragma unroll
        for (int kk = 0; kk < 2; ++kk) {
            const int c = kk * 4 + lg;
            bf16x8 af[4];
            #pragma unroll
            for (int fm = 0; fm < 4; ++fm) {
                int m = wm * 64 + fm * 16 + lr;
                int lidx = m * 64 + ((c ^ (m & 7)) << 3);
                af[fm] = *(bf16x8*)&sA[lidx];
            }
            bf16x8 bx[2], bg[2];
            #pragma unroll
            for (int fn = 0; fn < 2; ++fn) {
                int n = wn * 32 + fn * 16 + lr;
                int lidx = n * 64 + ((c ^ (n & 7)) << 3);
                bx[fn] = *(bf16x8*)&sBx[lidx];
                bg[fn] = *(bf16x8*)&sBg[lidx];
            }
            #pragma unroll
            for (int fm = 0; fm < 4; ++fm)
                #pragma unroll
                for (int fn = 0; fn < 2; ++fn) {
                    accX[fm][fn] = __builtin_amdgcn_mfma_f32_16x16x32_bf16(af[fm], bx[fn], accX[fm][fn], 0, 0, 0);
                    accG[fm][fn] = __builtin_amdgcn_mfma_f32_16x16x32_bf16(af[fm], bg[fn], accG[fm][fn], 0, 0, 0);
                }
        }
    }

    #pragma unroll
    for (int fm = 0; fm < 4; ++fm)
        #pragma unroll
        for (int fn = 0; fn < 2; ++fn) {
            const int n = n0 + wn * 32 + fn * 16 + lr;
            #pragma unroll
            for (int r = 0; r < 4; ++r) {
                const int m = m0 + wm * 64 + fm * 16 + lg * 4 + r;
                float gv = accG[fm][fn][r];
                float xv = accX[fm][fn][r];
                float sig = 1.0f / (1.0f + __expf(-gv));
                float hv = gv * sig * xv;
                float hf;
                Hh[(size_t)m * FFIN + n] = bfhi(hv, &hf);
            }
        }
}

// ------------------- attention: MFMA flash (per b,h,64 q-rows) -------------
// Masked-tile skip: trip count ceil(VL/64), uniform per block (VL per batch).
__global__ __launch_bounds__(256) void attn_mfma_k(
    const unsigned short* __restrict__ qh, const unsigned short* __restrict__ ql,
    const unsigned short* __restrict__ kh, const unsigned short* __restrict__ kl,
    const unsigned short* __restrict__ vT,
    unsigned short* __restrict__ ctxh,
    const int* __restrict__ vl)
{
    __shared__ unsigned short sKh[64 * 64];
    __shared__ unsigned short sKl[64 * 64];
    __shared__ unsigned short sVT[64 * 64];
    __shared__ unsigned short sP[64 * 64];

    const int i0 = blockIdx.x << 6;
    const int h  = blockIdx.y;
    const int b  = blockIdx.z;
    const int t  = threadIdx.x;
    const int l  = t & 63;
    const int w  = t >> 6;
    const int lr = l & 15, lg = l >> 4;
    const int VL = vl[b];
    const int ntiles = (VL + 63) >> 6;   // fully-masked tiles contribute 0

    bf16x8 qfh[2], qfl[2];
    {
        size_t base = (((size_t)(b * 8 + h) * 512) + i0 + w * 16 + lr) * 64 + lg * 8;
        qfh[0] = *(const bf16x8*)&qh[base];
        qfh[1] = *(const bf16x8*)&qh[base + 32];
        qfl[0] = *(const bf16x8*)&ql[base];
        qfl[1] = *(const bf16x8*)&ql[base + 32];
    }

    float mrow[4], lrow[4];
    f32x4 oacc[4];
    #pragma unroll
    for (int r = 0; r < 4; ++r) { mrow[r] = -3.0e38f; lrow[r] = 0.f; }
    #pragma unroll
    for (int nb = 0; nb < 4; ++nb) oacc[nb] = (f32x4)0.f;

    for (int jt = 0; jt < ntiles; ++jt) {
        const int j0 = jt << 6;
        __syncthreads();
        #pragma unroll
        for (int i = 0; i < 2; ++i) {
            int flat = i * 256 + t;
            int m = flat >> 3, c = flat & 7;
            int lidx = m * 64 + ((c ^ (m & 7)) << 3);
            size_t kg = ((size_t)b * 512 + j0 + m) * 64 + c * 8;
            *(ushort8*)&sKh[lidx] = *(const ushort8*)&kh[kg];
            *(ushort8*)&sKl[lidx] = *(const ushort8*)&kl[kg];
            size_t vg = ((size_t)b * 64 + m) * 512 + j0 + c * 8;
            *(ushort8*)&sVT[lidx] = *(const ushort8*)&vT[vg];
        }
        __syncthreads();

        f32x4 accS[4];
        #pragma unroll
        for (int nb = 0; nb < 4; ++nb) accS[nb] = (f32x4)0.f;
        #pragma unroll
        for (int ks = 0; ks < 2; ++ks) {
            const int c = ks * 4 + lg;
            #pragma unroll
            for (int nb = 0; nb < 4; ++nb) {
                int n = nb * 16 + lr;
                int lidx = n * 64 + ((c ^ (n & 7)) << 3);
                bf16x8 kfh = *(bf16x8*)&sKh[lidx];
                bf16x8 kfl = *(bf16x8*)&sKl[lidx];
                accS[nb] = __builtin_amdgcn_mfma_f32_16x16x32_bf16(qfh[ks], kfh, accS[nb], 0, 0, 0);
                accS[nb] = __builtin_amdgcn_mfma_f32_16x16x32_bf16(qfh[ks], kfl, accS[nb], 0, 0, 0);
                accS[nb] = __builtin_amdgcn_mfma_f32_16x16x32_bf16(qfl[ks], kfh, accS[nb], 0, 0, 0);
            }
        }

        #pragma unroll
        for (int nb = 0; nb < 4; ++nb) {
            if (j0 + nb * 16 + lr >= VL) {
                #pragma unroll
                for (int r = 0; r < 4; ++r) accS[nb][r] = -3.0e38f;
            }
        }

        #pragma unroll
        for (int r = 0; r < 4; ++r) {
            float rm = fmaxf(fmaxf(accS[0][r], accS[1][r]), fmaxf(accS[2][r], accS[3][r]));
            #pragma unroll
            for (int off = 8; off; off >>= 1) rm = fmaxf(rm, __shfl_xor(rm, off));
            float nm = fmaxf(mrow[r], rm);
            float scl = __expf(mrow[r] - nm);
            mrow[r] = nm;
            float ps = 0.f;
            #pragma unroll
            for (int nb = 0; nb < 4; ++nb) {
                float p = __expf(accS[nb][r] - nm);
                accS[nb][r] = p;
                ps += p;
            }
            lrow[r] = lrow[r] * scl + ps;
            #pragma unroll
            for (int nb = 0; nb < 4; ++nb) oacc[nb][r] *= scl;
        }

        #pragma unroll
        for (int nb = 0; nb < 4; ++nb) {
            int cc = nb * 2 + (lr >> 3);
            #pragma unroll
            for (int r = 0; r < 4; ++r) {
                int q = w * 16 + lg * 4 + r;
                int lidx = q * 64 + ((cc ^ (q & 7)) << 3) + (lr & 7);
                float hf2;
                sP[lidx] = bfhi(accS[nb][r], &hf2);
            }
        }

        #pragma unroll
        for (int ks = 0; ks < 2; ++ks) {
            const int c = ks * 4 + lg;
            int qrow = w * 16 + lr;
            int plidx = qrow * 64 + ((c ^ (qrow & 7)) << 3);
            bf16x8 pf = *(bf16x8*)&sP[plidx];
            #pragma unroll
            for (int nb = 0; nb < 4; ++nb) {
                int n = nb * 16 + lr;
                int lidx = n * 64 + ((c ^ (n & 7)) << 3);
                bf16x8 vf = *(bf16x8*)&sVT[lidx];
                oacc[nb] = __builtin_amdgcn_mfma_f32_16x16x32_bf16(pf, vf, oacc[nb], 0, 0, 0);
            }
        }
    }

    #pragma unroll
    for (int r = 0; r < 4; ++r) {
        float lt = lrow[r];
        #pragma unroll
        for (int off = 8; off; off >>= 1) lt += __shfl_xor(lt, off);
        float inv = 1.0f / lt;
        const int row = (b << 9) + i0 + w * 16 + lg * 4 + r;
        const size_t base = (size_t)row * DIMM + h * 64;
        #pragma unroll
        for (int nb = 0; nb < 4; ++nb) {
            float v = oacc[nb][r] * inv;
            float hf;
            ctxh[base + nb * 16 + lr] = bfhi(v, &hf);
        }
    }
}

// ------------------------------ pool ---------------------------------------
__global__ __launch_bounds__(512) void pool_part_k(const float* __restrict__ x,
                                                   float* __restrict__ psum,
                                                   float* __restrict__ pmax)
{
    const int seg = blockIdx.x;
    const int b   = blockIdx.y;
    const int d   = threadIdx.x;
    const float* xb = x + ((size_t)(b << 9) + (seg << 6)) * DIMM;
    float s = 0.f, m = -3.0e38f;
    for (int i = 0; i < 64; ++i) {
        float v = xb[(size_t)i * DIMM + d];
        s += v;
        m = fmaxf(m, v);
    }
    psum[((size_t)b * 8 + seg) * DIMM + d] = s;
    pmax[((size_t)b * 8 + seg) * DIMM + d] = m;
}

__global__ __launch_bounds__(512) void pool_comb_k(const float* __restrict__ psum,
                                                   const float* __restrict__ pmax,
                                                   float* __restrict__ out)
{
    const int b = blockIdx.x;
    const int d = threadIdx.x;
    float s = 0.f, m = -3.0e38f;
    #pragma unroll
    for (int seg = 0; seg < 8; ++seg) {
        s += psum[((size_t)b * 8 + seg) * DIMM + d];
        m = fmaxf(m, pmax[((size_t)b * 8 + seg) * DIMM + d]);
    }
    out[b * 1024 + d] = s * (1.0f / 512.0f);
    out[b * 1024 + 512 + d] = m;
}

// ---------------------------------------------------------------------------
extern "C" void kernel_launch(void* const* d_in, const int* in_sizes, int n_in,
                              void* d_out, int out_size, void* d_ws, size_t ws_size,
                              hipStream_t stream)
{
    const int*   page_in        = (const int*)d_in[0];
    const int*   item_in        = (const int*)d_in[1];
    const int*   item_meta_in   = (const int*)d_in[2];
    const int*   vl_in          = (const int*)d_in[3];
    const int*   page_meta_in   = (const int*)d_in[4];
    const float* pwide          = (const float*)d_in[5];
    const float* iwide          = (const float*)d_in[6];
    const float* page_emb       = (const float*)d_in[7];
    const float* page_meta_emb  = (const float*)d_in[8];
    const float* item_emb       = (const float*)d_in[9];
    const float* item_meta_emb  = (const float*)d_in[10];
    const float* item_pre_emb   = (const float*)d_in[11];
    const float* pW             = (const float*)d_in[12];
    const float* pb             = (const float*)d_in[13];
    const float* pg             = (const float*)d_in[14];
    const float* pbeta          = (const float*)d_in[15];
    const float* iW             = (const float*)d_in[16];
    const float* ib             = (const float*)d_in[17];
    const float* ig             = (const float*)d_in[18];
    const float* ibeta          = (const float*)d_in[19];
    const float* norm_g         = (const float*)d_in[20];
    const float* fused_W        = (const float*)d_in[21];
    const float* attn_out_W     = (const float*)d_in[22];
    const float* ff_out_W       = (const float*)d_in[23];
    float* out = (float*)d_out;

    float* ws  = (float*)d_ws;
    float* x    = ws;                                      // 16384*512 f32
    unsigned short* xnh = (unsigned short*)(x + (size_t)NROWS * DIMM);
    unsigned short* xnl = xnh + (size_t)NROWS * DIMM;
    float* qkv = (float*)(xnl + (size_t)NROWS * DIMM);     // 16384*640 f32
    unsigned short* hh   = (unsigned short*)(qkv + (size_t)NROWS * QKVC);
    unsigned short* ctxh = hh + (size_t)NROWS * FFIN;
    float* psum = (float*)(ctxh + (size_t)NROWS * DIMM);
    float* pmax = psum + (size_t)NBATCH * 8 * DIMM;
    unsigned short* WqTh = (unsigned short*)(pmax + (size_t)NBATCH * 8 * DIMM);
    unsigned short* WqTl = WqTh + (size_t)QKVC * DIMM;     // 640x512
    unsigned short* WdTh = WqTl + (size_t)QKVC * DIMM;     // 4096x512 (hi only)
    unsigned short* WaTh = WdTh + (size_t)4096 * DIMM;     // 512x512 (hi only)
    unsigned short* WfTh = WaTh + (size_t)DIMM * DIMM;     // 512x2048 (hi only)
    unsigned short* khb  = WfTh + (size_t)DIMM * FFIN;     // 32x512x64
    unsigned short* klb  = khb + (size_t)NBATCH * SEQ * 64;
    unsigned short* vTb  = klb + (size_t)NBATCH * SEQ * 64; // 32x64x512
    float* cost = (float*)(vTb + (size_t)NBATCH * 64 * SEQ); // 512x32
    float* sint = cost + 512 * 32;
    // q hi/lo alias xnh/xnl (xn dead after dual-silu; rope runs after it)
    unsigned short* qhb = xnh;
    unsigned short* qlb = xnl;

    build_x_k<<<NROWS, 512, 0, stream>>>(
        page_in, item_in, item_meta_in, page_meta_in, pwide, iwide,
        page_emb, page_meta_emb, item_emb, item_meta_emb, item_pre_emb,
        pW, pb, pg, pbeta, iW, ib, ig, ibeta, x);

    trig_k<<<64, 256, 0, stream>>>(cost, sint);

    for (int l = 0; l < 4; ++l) {
        const float* Wf  = fused_W    + (size_t)l * DIMM * NFUSED;
        const float* Wa  = attn_out_W + (size_t)l * DIMM * DIMM;
        const float* Wff = ff_out_W   + (size_t)l * FFIN * DIMM;
        const float* g   = norm_g     + (size_t)l * DIMM;

        ln_k<<<NROWS, 256, 0, stream>>>(x, xnh, xnl, g);

        wconv_k<true><<<dim3(QKVC / 64, DIMM / 64), 256, 0, stream>>>(
            Wf, NFUSED, 0, WqTh, WqTl, DIMM);
        wconv_k<false><<<dim3(4096 / 64, DIMM / 64), 256, 0, stream>>>(
            Wf, NFUSED, 640, WdTh, nullptr, DIMM);
        wconv_k<false><<<dim3(DIMM / 64, DIMM / 64), 256, 0, stream>>>(
            Wa, DIMM, 0, WaTh, nullptr, DIMM);
        wconv_k<false><<<dim3(DIMM / 64, FFIN / 64), 256, 0, stream>>>(
            Wff, DIMM, 0, WfTh, nullptr, FFIN);

        mfma_gemm_k<<<dim3(QKVC / 64, NROWS / 128), 256, 0, stream>>>(
            xnh, xnl, DIMM, WqTh, WqTl, DIMM, DIMM, qkv, QKVC);

        mfma_dual_silu_k<<<dim3(FFIN / 64, NROWS / 128), 256, 0, stream>>>(
            xnh, WdTh, hh);

        // xn dead now; rope writes q hi/lo into its space
        rope_split_k<<<NROWS / 4, 256, 0, stream>>>(
            qkv, cost, sint, qhb, qlb, khb, klb, vTb);

        attn_mfma_k<<<dim3(SEQ / 64, NHEAD, NBATCH), 256, 0, stream>>>(
            qhb, qlb, khb, klb, vTb, ctxh, vl_in);

        mfma_out_k<<<dim3(2, NROWS / 64), 256, 0, stream>>>(
            ctxh, WaTh, hh, WfTh, x);
    }

    pool_part_k<<<dim3(8, NBATCH), 512, 0, stream>>>(x, psum, pmax);
    pool_comb_k<<<NBATCH, 512, 0, stream>>>(psum, pmax, out);
}